// Round 6
// baseline (941.725 us; speedup 1.0000x reference)
//
#include <hip/hip_runtime.h>
#include <math.h>

#define T_STEPS 4
#define NN 20000
#define EE 160000
#define IND 64
#define DD 128
#define G3 384     // 3*D (GRU gates)
#define QS 512     // q|k|v|skip fused width

typedef __bf16 bf16x8 __attribute__((ext_vector_type(8)));
typedef float floatx4 __attribute__((ext_vector_type(4)));

// ---------------------------------------------------------------------------
// fp32 -> bf16 split (RNE): x ~= hi + lo, |x-(hi+lo)| <~ 2^-18 |x|
// ---------------------------------------------------------------------------
__device__ inline unsigned short f2bf(float x) {
  unsigned u = __float_as_uint(x);
  unsigned r = (u + 0x7fffu + ((u >> 16) & 1u)) >> 16;
  return (unsigned short)r;
}
__device__ inline float bf2f(unsigned short h) {
  return __uint_as_float((unsigned)h << 16);
}
__device__ inline void bfsplit(float x, unsigned short& hi, unsigned short& lo) {
  hi = f2bf(x);
  lo = f2bf(x - bf2f(hi));
}
// load 16 consecutive bf16 -> fp32 (32B, two dwordx4)
__device__ inline void ld16bf(const unsigned short* p, float* f) {
  const uint4 u0 = *(const uint4*)p;
  const uint4 u1 = *(const uint4*)(p + 8);
  f[0] = __uint_as_float(u0.x << 16);  f[1] = __uint_as_float(u0.x & 0xffff0000u);
  f[2] = __uint_as_float(u0.y << 16);  f[3] = __uint_as_float(u0.y & 0xffff0000u);
  f[4] = __uint_as_float(u0.z << 16);  f[5] = __uint_as_float(u0.z & 0xffff0000u);
  f[6] = __uint_as_float(u0.w << 16);  f[7] = __uint_as_float(u0.w & 0xffff0000u);
  f[8]  = __uint_as_float(u1.x << 16); f[9]  = __uint_as_float(u1.x & 0xffff0000u);
  f[10] = __uint_as_float(u1.y << 16); f[11] = __uint_as_float(u1.y & 0xffff0000u);
  f[12] = __uint_as_float(u1.z << 16); f[13] = __uint_as_float(u1.z & 0xffff0000u);
  f[14] = __uint_as_float(u1.w << 16); f[15] = __uint_as_float(u1.w & 0xffff0000u);
}

// ---------------------------------------------------------------------------
// Split-bf16 MFMA GEMM: C[M,N] = (Ahi+Alo)[M,K] x B + bias.
// obf16=0 -> fp32 C ; obf16=1 -> bf16 Cb. Wave: 64 rows x 128 cols
// (12 MFMA per 2 B-frag loads). M%32==0 required; M%64==32 handled via has2.
// ---------------------------------------------------------------------------
__global__ __launch_bounds__(256) void gemm_mfma(
    const unsigned short* __restrict__ Ahi, const unsigned short* __restrict__ Alo,
    const unsigned short* __restrict__ Bp, const float* __restrict__ bias,
    float* __restrict__ C, unsigned short* __restrict__ Cb,
    int M, int N, int K, int obf16)
{
  const int wave = (blockIdx.x * 256 + threadIdx.x) >> 6;
  const int lane = threadIdx.x & 63;
  const int ngroups = N >> 7;          // N/128
  const int mtiles = (M + 63) >> 6;    // 64 rows per wave
  if (wave >= mtiles * ngroups) return;
  const int mw = wave / ngroups;
  const int ng = wave - mw * ngroups;
  const int r = lane & 15, quad = lane >> 4;
  const int ktiles = K >> 5;
  const int m0 = mw * 64;
  const bool has2 = (m0 + 32) < M;     // second 32-row half present (uniform)
  const size_t rowA = (size_t)(m0 + r) * K + quad * 8;
  const size_t rowB = rowA + (size_t)16 * K;
  const size_t rowC = has2 ? rowA + (size_t)32 * K : rowA;  // clamp when absent
  const size_t rowD = has2 ? rowA + (size_t)48 * K : rowA;
  floatx4 acc[4][8];
#pragma unroll
  for (int m = 0; m < 4; ++m)
#pragma unroll
    for (int nt = 0; nt < 8; ++nt) acc[m][nt] = (floatx4){0.f, 0.f, 0.f, 0.f};
  const int n0t = ng * 8;
  for (int kt = 0; kt < ktiles; ++kt) {
    bf16x8 a0h = *(const bf16x8*)(Ahi + rowA + kt * 32);
    bf16x8 a0l = *(const bf16x8*)(Alo + rowA + kt * 32);
    bf16x8 a1h = *(const bf16x8*)(Ahi + rowB + kt * 32);
    bf16x8 a1l = *(const bf16x8*)(Alo + rowB + kt * 32);
    bf16x8 a2h = *(const bf16x8*)(Ahi + rowC + kt * 32);
    bf16x8 a2l = *(const bf16x8*)(Alo + rowC + kt * 32);
    bf16x8 a3h = *(const bf16x8*)(Ahi + rowD + kt * 32);
    bf16x8 a3l = *(const bf16x8*)(Alo + rowD + kt * 32);
#pragma unroll
    for (int nt = 0; nt < 8; ++nt) {
      const unsigned short* bp =
          Bp + ((size_t)((n0t + nt) * ktiles + kt)) * 1024 + lane * 8;
      bf16x8 bhi = *(const bf16x8*)bp;
      bf16x8 blo = *(const bf16x8*)(bp + 512);
      acc[0][nt] = __builtin_amdgcn_mfma_f32_16x16x32_bf16(a0h, bhi, acc[0][nt], 0, 0, 0);
      acc[0][nt] = __builtin_amdgcn_mfma_f32_16x16x32_bf16(a0h, blo, acc[0][nt], 0, 0, 0);
      acc[0][nt] = __builtin_amdgcn_mfma_f32_16x16x32_bf16(a0l, bhi, acc[0][nt], 0, 0, 0);
      acc[1][nt] = __builtin_amdgcn_mfma_f32_16x16x32_bf16(a1h, bhi, acc[1][nt], 0, 0, 0);
      acc[1][nt] = __builtin_amdgcn_mfma_f32_16x16x32_bf16(a1h, blo, acc[1][nt], 0, 0, 0);
      acc[1][nt] = __builtin_amdgcn_mfma_f32_16x16x32_bf16(a1l, bhi, acc[1][nt], 0, 0, 0);
      if (has2) {
        acc[2][nt] = __builtin_amdgcn_mfma_f32_16x16x32_bf16(a2h, bhi, acc[2][nt], 0, 0, 0);
        acc[2][nt] = __builtin_amdgcn_mfma_f32_16x16x32_bf16(a2h, blo, acc[2][nt], 0, 0, 0);
        acc[2][nt] = __builtin_amdgcn_mfma_f32_16x16x32_bf16(a2l, bhi, acc[2][nt], 0, 0, 0);
        acc[3][nt] = __builtin_amdgcn_mfma_f32_16x16x32_bf16(a3h, bhi, acc[3][nt], 0, 0, 0);
        acc[3][nt] = __builtin_amdgcn_mfma_f32_16x16x32_bf16(a3h, blo, acc[3][nt], 0, 0, 0);
        acc[3][nt] = __builtin_amdgcn_mfma_f32_16x16x32_bf16(a3l, bhi, acc[3][nt], 0, 0, 0);
      }
    }
  }
  const int mmax = has2 ? 4 : 2;
  for (int m = 0; m < mmax; ++m) {
    const int crow0 = m0 + m * 16 + quad * 4;
#pragma unroll
    for (int nt = 0; nt < 8; ++nt) {
      const int col = ng * 128 + nt * 16 + r;
      const float b = bias[col];
      if (obf16) {
#pragma unroll
        for (int i = 0; i < 4; ++i)
          Cb[(size_t)(crow0 + i) * N + col] = f2bf(acc[m][nt][i] + b);
      } else {
#pragma unroll
        for (int i = 0; i < 4; ++i)
          C[(size_t)(crow0 + i) * N + col] = acc[m][nt][i] + b;
      }
    }
  }
}

// ---------------------------------------------------------------------------
// Weight packing into MFMA fragment order (hi/lo split) + fused conv bias
// ---------------------------------------------------------------------------
#define BIH_PAIRS 24576    // (384/16)*(64/32)*512
#define BHH_PAIRS 49152    // 24*4*512
#define WCAT_PAIRS 131072  // 2*32*4*512
#define BCAT_N 1024

__global__ void pack_weights(
    const float* __restrict__ Wih, const float* __restrict__ Whh,
    const float* __restrict__ Wq, const float* __restrict__ Wk,
    const float* __restrict__ Wv, const float* __restrict__ Ws,
    const float* __restrict__ bq, const float* __restrict__ bk,
    const float* __restrict__ bv, const float* __restrict__ bs,
    unsigned short* __restrict__ BihP, unsigned short* __restrict__ BhhP,
    unsigned short* __restrict__ WcatP, float* __restrict__ bcat)
{
  int gid = blockIdx.x * 256 + threadIdx.x;
  if (gid < BIH_PAIRS) {  // K=64, N=384, ktiles=2
    int tile = gid >> 9, lj = gid & 511, lane = lj >> 3, j = lj & 7;
    int k_tile = tile & 1, n_tile = tile >> 1;
    int n = n_tile * 16 + (lane & 15);
    int k = k_tile * 32 + (lane >> 4) * 8 + j;
    unsigned short hi, lo;
    bfsplit(Wih[n * IND + k], hi, lo);   // B[k][n] = Wih^T
    BihP[tile * 1024 + lane * 8 + j] = hi;
    BihP[tile * 1024 + 512 + lane * 8 + j] = lo;
    return;
  }
  gid -= BIH_PAIRS;
  if (gid < BHH_PAIRS) {  // K=128, N=384, ktiles=4
    int tile = gid >> 9, lj = gid & 511, lane = lj >> 3, j = lj & 7;
    int k_tile = tile & 3, n_tile = tile >> 2;
    int n = n_tile * 16 + (lane & 15);
    int k = k_tile * 32 + (lane >> 4) * 8 + j;
    unsigned short hi, lo;
    bfsplit(Whh[n * DD + k], hi, lo);
    BhhP[tile * 1024 + lane * 8 + j] = hi;
    BhhP[tile * 1024 + 512 + lane * 8 + j] = lo;
    return;
  }
  gid -= BHH_PAIRS;
  if (gid < WCAT_PAIRS) {  // per layer: K=128, N=512, ktiles=4
    int l = gid >> 16, rem = gid & 65535;
    int tile = rem >> 9, lj = rem & 511, lane = lj >> 3, j = lj & 7;
    int k_tile = tile & 3, n_tile = tile >> 2;
    int n = n_tile * 16 + (lane & 15);
    int k = k_tile * 32 + (lane >> 4) * 8 + j;
    const float* W = (n < 128) ? Wq : (n < 256) ? Wk : (n < 384) ? Wv : Ws;
    unsigned short hi, lo;
    bfsplit(W[l * DD * DD + k * DD + (n & 127)], hi, lo);
    size_t base = (size_t)l * 131072 + tile * 1024;
    WcatP[base + lane * 8 + j] = hi;
    WcatP[base + 512 + lane * 8 + j] = lo;
    return;
  }
  gid -= WCAT_PAIRS;
  if (gid < BCAT_N) {
    int l = gid >> 9, n = gid & 511;
    const float* b = (n < 128) ? bq : (n < 256) ? bk : (n < 384) ? bv : bs;
    bcat[gid] = b[l * DD + (n & 127)];
  }
}

// ---------------------------------------------------------------------------
__global__ void xsplit(const float* __restrict__ x,
                       unsigned short* __restrict__ xhi,
                       unsigned short* __restrict__ xlo)
{
  int i = blockIdx.x * 256 + threadIdx.x;   // exact T*NN*IND grid
  unsigned short hi, lo;
  bfsplit(x[i], hi, lo);
  xhi[i] = hi; xlo[i] = lo;
}

// ---------------------------------------------------------------------------
// CSR build (by destination), per timestep; parallel 3-phase scan
// ---------------------------------------------------------------------------
#define SCHUNK 1024
#define NCHUNK 20          // ceil(20000/1024)

__global__ void csr_count(const int* __restrict__ ei, int* __restrict__ deg)
{
  int gid = blockIdx.x * 256 + threadIdx.x;
  if (gid >= T_STEPS * EE) return;
  int t = gid / EE, e = gid % EE;
  int dst = ei[(size_t)t * 2 * EE + EE + e];
  atomicAdd(&deg[t * NN + dst], 1);
}

__global__ void scan1(const int* __restrict__ deg, int* __restrict__ part)
{
  const int b = blockIdx.x;              // 0..T*NCHUNK-1
  const int t = b / NCHUNK, c = b % NCHUNK;
  const int tid = threadIdx.x;
  __shared__ int s[256];
  int base = c * SCHUNK + tid * 4;
  int sum = 0;
#pragma unroll
  for (int u = 0; u < 4; ++u) {
    int i = base + u;
    if (i < NN) sum += deg[t * NN + i];
  }
  s[tid] = sum;
  __syncthreads();
  for (int o = 128; o > 0; o >>= 1) {
    if (tid < o) s[tid] += s[tid + o];
    __syncthreads();
  }
  if (tid == 0) part[b] = s[0];
}

__global__ void scan2(int* __restrict__ part, int* __restrict__ offs)
{
  const int tid = threadIdx.x;
  __shared__ int s[T_STEPS * NCHUNK];
  if (tid < T_STEPS * NCHUNK) s[tid] = part[tid];
  __syncthreads();
  if (tid == 0) {
    for (int t = 0; t < T_STEPS; ++t) {
      int run = 0;
      for (int c = 0; c < NCHUNK; ++c) {
        int v = s[t * NCHUNK + c];
        s[t * NCHUNK + c] = run;
        run += v;
      }
      offs[t * (NN + 1) + NN] = run;
    }
  }
  __syncthreads();
  if (tid < T_STEPS * NCHUNK) part[tid] = s[tid];
}

__global__ void scan3(const int* __restrict__ deg, const int* __restrict__ part,
                      int* __restrict__ offs, int* __restrict__ cur)
{
  const int b = blockIdx.x;
  const int t = b / NCHUNK, c = b % NCHUNK;
  const int tid = threadIdx.x;
  __shared__ int s[256];
  int base = c * SCHUNK + tid * 4;
  int v[4]; int sum = 0;
#pragma unroll
  for (int u = 0; u < 4; ++u) {
    int i = base + u;
    v[u] = (i < NN) ? deg[t * NN + i] : 0;
    sum += v[u];
  }
  s[tid] = sum;
  __syncthreads();
  for (int o = 1; o < 256; o <<= 1) {
    int x = (tid >= o) ? s[tid - o] : 0;
    __syncthreads();
    s[tid] += x;
    __syncthreads();
  }
  int excl = part[b] + s[tid] - sum;
#pragma unroll
  for (int u = 0; u < 4; ++u) {
    int i = base + u;
    if (i < NN) {
      offs[t * (NN + 1) + i] = excl;
      cur[t * NN + i] = excl;
    }
    excl += v[u];
  }
}

// packed CSR entry: .x = src node, .y = edge_attr bits (one 8B store per edge)
__global__ void csr_fill(const int* __restrict__ ei, const float* __restrict__ ea,
                         int* __restrict__ cur, int2* __restrict__ cse)
{
  int gid = blockIdx.x * 256 + threadIdx.x;
  if (gid >= T_STEPS * EE) return;
  int t = gid / EE, e = gid % EE;
  int src = ei[(size_t)t * 2 * EE + e];
  int dst = ei[(size_t)t * 2 * EE + EE + e];
  int slot = atomicAdd(&cur[t * NN + dst], 1);
  cse[(size_t)t * EE + slot] = make_int2(src, __float_as_int(ea[(size_t)t * EE + e]));
}

// ---------------------------------------------------------------------------
// GRU gate fusion. t0: gh == b_hh exactly (h0=0), h_prev=0.
// ---------------------------------------------------------------------------
__global__ __launch_bounds__(256) void gru_gate(
    const float* __restrict__ gi, const float* __restrict__ gh,
    const float* __restrict__ b_hh, int t0,
    const unsigned short* __restrict__ phi, const unsigned short* __restrict__ plo,
    unsigned short* __restrict__ hhi_t, unsigned short* __restrict__ hlo_t)
{
  int idx = blockIdx.x * 256 + threadIdx.x;   // exact NN*DD grid
  int n = idx >> 7, d = idx & 127;
  size_t gb = (size_t)n * G3 + d;
  float ir = gi[gb], iz = gi[gb + DD], inn = gi[gb + 2 * DD];
  float hr, hz, hn, hp;
  if (t0) {
    hr = b_hh[d]; hz = b_hh[DD + d]; hn = b_hh[2 * DD + d]; hp = 0.f;
  } else {
    hr = gh[gb]; hz = gh[gb + DD]; hn = gh[gb + 2 * DD];
    hp = bf2f(phi[idx]) + bf2f(plo[idx]);
  }
  float r = 1.f / (1.f + __expf(-(ir + hr)));
  float z = 1.f / (1.f + __expf(-(iz + hz)));
  float nv = tanhf(inn + r * hn);
  float hnew = (1.f - z) * nv + z * hp;
  unsigned short hi, lo;
  bfsplit(hnew, hi, lo);
  hhi_t[idx] = hi; hlo_t[idx] = lo;
}

// ---------------------------------------------------------------------------
// Fused TransformerConv (d=128), all T via blockIdx.y. qkvb is bf16 [T][NN][512].
// One wave per dst node; lane = (eslot 0..7) x (feature-group 0..7, 16 floats).
// No-max softmax (|alpha| is O(1) by weight-scale bounds; exp safe to |a|<80).
// Edge-feature factored: agg = (S ex*v + (S ex*a)*We)/l. All cross-lane
// reductions deferred to the epilogue except the 3-shuffle q.k dot.
// ---------------------------------------------------------------------------
__global__ __launch_bounds__(256) void attn_conv(
    const unsigned short* __restrict__ qkvb,  // [T][NN][512] bf16
    const int* __restrict__ offs4,    // [T][NN+1]
    const int2* __restrict__ cse4,    // [T][E]
    const float* __restrict__ We,     // [128]
    unsigned short* __restrict__ hhi4, unsigned short* __restrict__ hlo4)
{
  const int t = blockIdx.y;
  const unsigned short* qk = qkvb + (size_t)t * NN * QS;
  const int* offs = offs4 + (size_t)t * (NN + 1);
  const int2* cse = cse4 + (size_t)t * EE;
  const int wv = (blockIdx.x * 256 + threadIdx.x) >> 6;
  const int lane = threadIdx.x & 63;
  if (wv >= NN) return;
  const int fg = lane & 7, es = lane >> 3;
  const int f0 = fg * 16;
  const float scale = 0.08838834764831845f;   // 1/sqrt(128)

  float qf[16], wf[16];
  ld16bf(qk + (size_t)wv * QS + f0, qf);
#pragma unroll
  for (int j = 0; j < 16; j += 4)
    *(float4*)&wf[j] = *(const float4*)&We[f0 + j];
  float qwe = 0.f;
#pragma unroll
  for (int j = 0; j < 16; ++j) qwe = fmaf(qf[j], wf[j], qwe);
  qwe += __shfl_xor(qwe, 1); qwe += __shfl_xor(qwe, 2); qwe += __shfl_xor(qwe, 4);

  const int e0 = offs[wv], e1 = offs[wv + 1];
  float l_lane = 0.f, sA_lane = 0.f;
  float acc[16];
#pragma unroll
  for (int i = 0; i < 16; ++i) acc[i] = 0.f;

  for (int base = e0; base < e1; base += 8) {
    const int eidx = base + es;
    const bool valid = eidx < e1;
    int2 se = valid ? cse[eidx] : make_int2(0, 0);
    const int s = se.x;
    const float a = __int_as_float(se.y);
    float kf[16];
    ld16bf(qk + (size_t)s * QS + 128 + f0, kf);
    float p = 0.f;
#pragma unroll
    for (int j = 0; j < 16; ++j) p = fmaf(qf[j], kf[j], p);
    p += __shfl_xor(p, 1); p += __shfl_xor(p, 2); p += __shfl_xor(p, 4);
    const float ex = valid ? __expf((p + a * qwe) * scale) : 0.f;
    l_lane += ex;
    sA_lane = fmaf(ex, a, sA_lane);
    float vf[16];
    ld16bf(qk + (size_t)s * QS + 256 + f0, vf);
#pragma unroll
    for (int j = 0; j < 16; ++j)
      acc[j] = fmaf(ex, vf[j], acc[j]);
  }
  // epilogue reductions over the 8 edge-slots
  l_lane += __shfl_xor(l_lane, 8); l_lane += __shfl_xor(l_lane, 16); l_lane += __shfl_xor(l_lane, 32);
  sA_lane += __shfl_xor(sA_lane, 8); sA_lane += __shfl_xor(sA_lane, 16); sA_lane += __shfl_xor(sA_lane, 32);
#pragma unroll
  for (int i = 0; i < 16; ++i) {
    acc[i] += __shfl_xor(acc[i], 8);
    acc[i] += __shfl_xor(acc[i], 16);
    acc[i] += __shfl_xor(acc[i], 32);
  }
  if (es != 0) return;
  const float inv = 1.f / (l_lane + 1e-16f);
  const float sAi = sA_lane * inv;
  float sf[16];
  ld16bf(qk + (size_t)wv * QS + 384 + f0, sf);
  unsigned hp[8], lp[8];
#pragma unroll
  for (int j = 0; j < 8; ++j) {
    float oa = fmaf(acc[2 * j], inv, fmaf(sAi, wf[2 * j], sf[2 * j]));
    float ob = fmaf(acc[2 * j + 1], inv, fmaf(sAi, wf[2 * j + 1], sf[2 * j + 1]));
    oa = (oa > 0.f) ? oa : 0.01f * oa;    // leaky_relu
    ob = (ob > 0.f) ? ob : 0.01f * ob;
    unsigned short ha, la, hb, lb;
    bfsplit(oa, ha, la); bfsplit(ob, hb, lb);
    hp[j] = ((unsigned)hb << 16) | ha;
    lp[j] = ((unsigned)lb << 16) | la;
  }
  unsigned short* hdst = hhi4 + ((size_t)t * NN + wv) * DD + f0;
  unsigned short* ldst = hlo4 + ((size_t)t * NN + wv) * DD + f0;
  *(uint4*)(hdst + 0) = make_uint4(hp[0], hp[1], hp[2], hp[3]);
  *(uint4*)(hdst + 8) = make_uint4(hp[4], hp[5], hp[6], hp[7]);
  *(uint4*)(ldst + 0) = make_uint4(lp[0], lp[1], lp[2], lp[3]);
  *(uint4*)(ldst + 8) = make_uint4(lp[4], lp[5], lp[6], lp[7]);
}

// ---------------------------------------------------------------------------
// mean over T from bf16 hi/lo split (hi+lo ~= fp32); 2 elems per thread
// ---------------------------------------------------------------------------
__global__ void mean_k(const unsigned short* __restrict__ hhi,
                       const unsigned short* __restrict__ hlo,
                       float* __restrict__ hm)
{
  int i = blockIdx.x * 256 + threadIdx.x;   // exact NN*DD/2 grid
  float vx = 0.f, vy = 0.f;
#pragma unroll
  for (int t = 0; t < T_STEPS; ++t) {
    unsigned h = *(const unsigned*)&hhi[(size_t)t * NN * DD + 2 * i];
    unsigned l = *(const unsigned*)&hlo[(size_t)t * NN * DD + 2 * i];
    vx += __uint_as_float(h << 16) + __uint_as_float(l << 16);
    vy += __uint_as_float(h & 0xffff0000u) + __uint_as_float(l & 0xffff0000u);
  }
  *(float2*)&hm[2 * i] = make_float2(0.25f * vx, 0.25f * vy);
}

// ---------------------------------------------------------------------------
__global__ __launch_bounds__(256) void out_proj(
    const float* __restrict__ h,
    const float* __restrict__ Wq, const float* __restrict__ Wk,
    const float* __restrict__ Wv, const float* __restrict__ Ws,
    const float* __restrict__ bq, const float* __restrict__ bk,
    const float* __restrict__ bv, const float* __restrict__ bs,
    float* __restrict__ q1, float* __restrict__ k1,
    float* __restrict__ v1, float* __restrict__ s1)
{
  const int wv = (blockIdx.x * 256 + threadIdx.x) >> 6;
  const int lane = threadIdx.x & 63;
  if (wv >= NN) return;
  float2 h2 = *(const float2*)&h[(size_t)wv * DD + 2 * lane];
  float pq = h2.x * Wq[2 * lane] + h2.y * Wq[2 * lane + 1];
  float pk = h2.x * Wk[2 * lane] + h2.y * Wk[2 * lane + 1];
  float pv = h2.x * Wv[2 * lane] + h2.y * Wv[2 * lane + 1];
  float ps = h2.x * Ws[2 * lane] + h2.y * Ws[2 * lane + 1];
#pragma unroll
  for (int o = 1; o < 64; o <<= 1) {
    pq += __shfl_xor(pq, o); pk += __shfl_xor(pk, o);
    pv += __shfl_xor(pv, o); ps += __shfl_xor(ps, o);
  }
  if (lane == 0) {
    q1[wv] = pq + bq[0]; k1[wv] = pk + bk[0];
    v1[wv] = pv + bv[0]; s1[wv] = ps + bs[0];
  }
}

__global__ void out_attn(
    const float* __restrict__ q1, const float* __restrict__ k1,
    const float* __restrict__ v1, const float* __restrict__ s1,
    const int* __restrict__ offs, const int2* __restrict__ cse,
    const float* __restrict__ We, float* __restrict__ out)
{
  int n = blockIdx.x * 256 + threadIdx.x;
  if (n >= NN) return;
  const float we = We[0];
  const float q = q1[n];
  const int e0 = offs[n], e1 = offs[n + 1];
  float m = -INFINITY;
  for (int e = e0; e < e1; ++e) {
    int2 se = cse[e];
    float al = q * (k1[se.x] + __int_as_float(se.y) * we);
    m = fmaxf(m, al);
  }
  float l = 0.f, acc = 0.f;
  for (int e = e0; e < e1; ++e) {
    int2 se = cse[e];
    float ca = __int_as_float(se.y);
    float al = q * (k1[se.x] + ca * we);
    float ex = __expf(al - m);
    l += ex;
    acc += ex * (v1[se.x] + ca * we);
  }
  out[n] = acc / (l + 1e-16f) + s1[n];
}

// ---------------------------------------------------------------------------
extern "C" void kernel_launch(void* const* d_in, const int* in_sizes, int n_in,
                              void* d_out, int out_size, void* d_ws, size_t ws_size,
                              hipStream_t stream)
{
  const float* x_seq = (const float*)d_in[0];
  const int*   ei    = (const int*)  d_in[1];
  const float* ea    = (const float*)d_in[2];
  const float* W_ih  = (const float*)d_in[3];
  const float* W_hh  = (const float*)d_in[4];
  const float* b_ih  = (const float*)d_in[5];
  const float* b_hh  = (const float*)d_in[6];
  const float* cWq   = (const float*)d_in[7];
  const float* cbq   = (const float*)d_in[8];
  const float* cWk   = (const float*)d_in[9];
  const float* cbk   = (const float*)d_in[10];
  const float* cWv   = (const float*)d_in[11];
  const float* cbv   = (const float*)d_in[12];
  const float* cWe   = (const float*)d_in[13];
  const float* cWs   = (const float*)d_in[14];
  const float* cbs   = (const float*)d_in[15];
  const float* oWq   = (const float*)d_in[16];
  const float* obq   = (const float*)d_in[17];
  const float* oWk   = (const float*)d_in[18];
  const float* obk   = (const float*)d_in[19];
  const float* oWv   = (const float*)d_in[20];
  const float* obv   = (const float*)d_in[21];
  const float* oWe   = (const float*)d_in[22];
  const float* oWs   = (const float*)d_in[23];
  const float* obs   = (const float*)d_in[24];
  float* out = (float*)d_out;

  char* ws = (char*)d_ws;
  size_t off = 0;
  auto alloc = [&](size_t bytes) -> char* {
    char* p = ws + off;
    off += (bytes + 255) & ~(size_t)255;
    return p;
  };
  // ---- total ~171 MB (round-4/5 proven; round-3's 289 MB aborted) ----
  unsigned short* BihP  = (unsigned short*)alloc((size_t)2 * BIH_PAIRS * 2);
  unsigned short* BhhP  = (unsigned short*)alloc((size_t)2 * BHH_PAIRS * 2);
  unsigned short* WcatP = (unsigned short*)alloc((size_t)2 * WCAT_PAIRS * 2);
  float* fbcat = (float*)alloc((size_t)BCAT_N * 4);
  unsigned short* xhi   = (unsigned short*)alloc((size_t)T_STEPS * NN * IND * 2);
  unsigned short* xlo   = (unsigned short*)alloc((size_t)T_STEPS * NN * IND * 2);
  unsigned short* hallhi = (unsigned short*)alloc((size_t)T_STEPS * NN * DD * 2);
  unsigned short* halllo = (unsigned short*)alloc((size_t)T_STEPS * NN * DD * 2);
  float* fH    = (float*)alloc((size_t)NN * DD * 4);          // h_mean
  int*   iDeg  = (int*)  alloc((size_t)T_STEPS * NN * 4);     // zero-init
  int*   iCur  = (int*)  alloc((size_t)T_STEPS * NN * 4);
  int*   iOffs = (int*)  alloc((size_t)T_STEPS * (NN + 1) * 4);
  int*   iPart = (int*)  alloc((size_t)T_STEPS * NCHUNK * 4);
  int2*  iSE   = (int2*) alloc((size_t)T_STEPS * EE * 8);
  float* fQ1   = (float*)alloc((size_t)NN * 4);
  float* fK1   = (float*)alloc((size_t)NN * 4);
  float* fV1   = (float*)alloc((size_t)NN * 4);
  float* fS1   = (float*)alloc((size_t)NN * 4);
  // union: GRU uses gi2 [2NN*G3 fp32] + gh [NN*G3 fp32] = 92.2 MB;
  //        conv uses qkvb [4NN*512 bf16] = 81.9 MB
  size_t uniOff = off;
  float* fGi2  = (float*)(ws + uniOff);
  float* fGh   = (float*)(ws + uniOff + (size_t)2 * NN * G3 * 4);
  unsigned short* qkvb = (unsigned short*)(ws + uniOff);
  (void)ws_size; (void)in_sizes; (void)n_in; (void)out_size;

  auto gemm = [&](const unsigned short* Ahi, const unsigned short* Alo,
                  const unsigned short* Bp, const float* bias, float* C,
                  unsigned short* Cb, int M, int N, int K, int obf16) {
    int waves = ((M + 63) >> 6) * (N >> 7);
    gemm_mfma<<<(waves + 3) / 4, 256, 0, stream>>>(Ahi, Alo, Bp, bias, C, Cb,
                                                   M, N, K, obf16);
  };

  // weights + activation split + CSR
  pack_weights<<<(BIH_PAIRS + BHH_PAIRS + WCAT_PAIRS + BCAT_N + 255) / 256, 256, 0,
                 stream>>>(W_ih, W_hh, cWq, cWk, cWv, cWs, cbq, cbk, cbv, cbs,
                           BihP, BhhP, WcatP, fbcat);
  xsplit<<<(T_STEPS * NN * IND) / 256, 256, 0, stream>>>(x_seq, xhi, xlo);
  hipMemsetAsync(iDeg, 0, (size_t)T_STEPS * NN * 4, stream);
  csr_count<<<(T_STEPS * EE) / 256, 256, 0, stream>>>(ei, iDeg);
  scan1<<<T_STEPS * NCHUNK, 256, 0, stream>>>(iDeg, iPart);
  scan2<<<1, 128, 0, stream>>>(iPart, iOffs);
  scan3<<<T_STEPS * NCHUNK, 256, 0, stream>>>(iDeg, iPart, iOffs, iCur);
  csr_fill<<<(T_STEPS * EE) / 256, 256, 0, stream>>>(ei, ea, iCur, iSE);

  // GRU over time: gi batched in pairs of t, gh sequential (t=0 skipped)
  for (int tp = 0; tp < 2; ++tp) {
    gemm(xhi + (size_t)tp * 2 * NN * IND, xlo + (size_t)tp * 2 * NN * IND,
         BihP, b_ih, fGi2, nullptr, 2 * NN, G3, IND, 0);
    for (int k = 0; k < 2; ++k) {
      const int t = tp * 2 + k;
      const unsigned short* phi = hallhi + (size_t)(t - 1) * NN * DD;  // unused t=0
      const unsigned short* plo = halllo + (size_t)(t - 1) * NN * DD;
      if (t > 0) gemm(phi, plo, BhhP, b_hh, fGh, nullptr, NN, G3, DD, 0);
      gru_gate<<<(NN * DD) / 256, 256, 0, stream>>>(
          fGi2 + (size_t)k * NN * G3, fGh, b_hh, (t == 0) ? 1 : 0,
          (t == 0) ? hallhi : phi, (t == 0) ? halllo : plo,
          hallhi + (size_t)t * NN * DD, halllo + (size_t)t * NN * DD);
    }
  }

  // stacked TransformerConv layers, full T batch, bf16 qkvb
  for (int l = 0; l < 2; ++l) {
    gemm(hallhi, halllo, WcatP + (size_t)l * 131072, fbcat + (size_t)l * QS,
         nullptr, qkvb, T_STEPS * NN, QS, DD, 1);
    dim3 ag((NN * 64) / 256, T_STEPS);
    attn_conv<<<ag, 256, 0, stream>>>(qkvb, iOffs, iSE, cWe + l * DD,
                                      hallhi, halllo);
  }

  // mean over T (reconstruct fp32 from hi+lo)
  mean_k<<<(NN * DD / 2) / 256, 256, 0, stream>>>(hallhi, halllo, fH);

  // output conv (d=1) on t=3 graph
  out_proj<<<(NN * 64) / 256, 256, 0, stream>>>(
      fH, oWq, oWk, oWv, oWs, obq, obk, obv, obs, fQ1, fK1, fV1, fS1);
  out_attn<<<(NN + 255) / 256, 256, 0, stream>>>(
      fQ1, fK1, fV1, fS1, iOffs + 3 * (NN + 1), iSE + (size_t)3 * EE, oWe, out);
}

// Round 7
// 623.797 us; speedup vs baseline: 1.5097x; 1.5097x over previous
//
#include <hip/hip_runtime.h>
#include <math.h>

#define T_STEPS 4
#define NN 20000
#define EE 160000
#define IND 64
#define DD 128
#define G3 384     // 3*D (GRU gates)
#define QS 512     // q|k|v|skip fused width

typedef __bf16 bf16x8 __attribute__((ext_vector_type(8)));
typedef float floatx4 __attribute__((ext_vector_type(4)));

// ---------------------------------------------------------------------------
// fp32 -> bf16 split (RNE): x ~= hi + lo, |x-(hi+lo)| <~ 2^-18 |x|
// ---------------------------------------------------------------------------
__device__ inline unsigned short f2bf(float x) {
  unsigned u = __float_as_uint(x);
  unsigned r = (u + 0x7fffu + ((u >> 16) & 1u)) >> 16;
  return (unsigned short)r;
}
__device__ inline float bf2f(unsigned short h) {
  return __uint_as_float((unsigned)h << 16);
}
__device__ inline void bfsplit(float x, unsigned short& hi, unsigned short& lo) {
  hi = f2bf(x);
  lo = f2bf(x - bf2f(hi));
}
// load 16 consecutive bf16 -> fp32 (32B, two dwordx4)
__device__ inline void ld16bf(const unsigned short* p, float* f) {
  const uint4 u0 = *(const uint4*)p;
  const uint4 u1 = *(const uint4*)(p + 8);
  f[0] = __uint_as_float(u0.x << 16);  f[1] = __uint_as_float(u0.x & 0xffff0000u);
  f[2] = __uint_as_float(u0.y << 16);  f[3] = __uint_as_float(u0.y & 0xffff0000u);
  f[4] = __uint_as_float(u0.z << 16);  f[5] = __uint_as_float(u0.z & 0xffff0000u);
  f[6] = __uint_as_float(u0.w << 16);  f[7] = __uint_as_float(u0.w & 0xffff0000u);
  f[8]  = __uint_as_float(u1.x << 16); f[9]  = __uint_as_float(u1.x & 0xffff0000u);
  f[10] = __uint_as_float(u1.y << 16); f[11] = __uint_as_float(u1.y & 0xffff0000u);
  f[12] = __uint_as_float(u1.z << 16); f[13] = __uint_as_float(u1.z & 0xffff0000u);
  f[14] = __uint_as_float(u1.w << 16); f[15] = __uint_as_float(u1.w & 0xffff0000u);
}

// ---------------------------------------------------------------------------
// Split-bf16 MFMA GEMM: C[M,N] = (Ahi+Alo)[M,K] x B + bias.
// obf16=0 -> fp32 C ; obf16=1 -> bf16 Cb. Wave: 32 rows x 128 cols.
// ROUND-5 PROVEN VERSION — 64-row tile (r6) spilled accumulators to scratch
// (WRITE_SIZE 634 MB vs 82 MB logical, 180 µs/dispatch). Do not enlarge
// without -Rpass-analysis VGPR check.
// ---------------------------------------------------------------------------
__global__ __launch_bounds__(256) void gemm_mfma(
    const unsigned short* __restrict__ Ahi, const unsigned short* __restrict__ Alo,
    const unsigned short* __restrict__ Bp, const float* __restrict__ bias,
    float* __restrict__ C, unsigned short* __restrict__ Cb,
    int M, int N, int K, int obf16)
{
  const int wave = (blockIdx.x * 256 + threadIdx.x) >> 6;
  const int lane = threadIdx.x & 63;
  const int ngroups = N >> 7;          // N/128
  const int mtiles = M >> 5;           // 32 rows per wave
  if (wave >= mtiles * ngroups) return;
  const int mw = wave / ngroups;
  const int ng = wave - mw * ngroups;
  const int r = lane & 15, quad = lane >> 4;
  const int ktiles = K >> 5;
  const unsigned short* a0h = Ahi + (size_t)(mw * 32 + r) * K + quad * 8;
  const unsigned short* a0l = Alo + (size_t)(mw * 32 + r) * K + quad * 8;
  const unsigned short* a1h = a0h + (size_t)16 * K;
  const unsigned short* a1l = a0l + (size_t)16 * K;
  floatx4 acc[2][8];
#pragma unroll
  for (int m = 0; m < 2; ++m)
#pragma unroll
    for (int nt = 0; nt < 8; ++nt) acc[m][nt] = (floatx4){0.f, 0.f, 0.f, 0.f};
  const int n0t = ng * 8;
  for (int kt = 0; kt < ktiles; ++kt) {
    bf16x8 a0hi = *(const bf16x8*)(a0h + kt * 32);
    bf16x8 a0lo = *(const bf16x8*)(a0l + kt * 32);
    bf16x8 a1hi = *(const bf16x8*)(a1h + kt * 32);
    bf16x8 a1lo = *(const bf16x8*)(a1l + kt * 32);
#pragma unroll
    for (int nt = 0; nt < 8; ++nt) {
      const unsigned short* bp =
          Bp + ((size_t)((n0t + nt) * ktiles + kt)) * 1024 + lane * 8;
      bf16x8 bhi = *(const bf16x8*)bp;
      bf16x8 blo = *(const bf16x8*)(bp + 512);
      acc[0][nt] = __builtin_amdgcn_mfma_f32_16x16x32_bf16(a0hi, bhi, acc[0][nt], 0, 0, 0);
      acc[0][nt] = __builtin_amdgcn_mfma_f32_16x16x32_bf16(a0hi, blo, acc[0][nt], 0, 0, 0);
      acc[0][nt] = __builtin_amdgcn_mfma_f32_16x16x32_bf16(a0lo, bhi, acc[0][nt], 0, 0, 0);
      acc[1][nt] = __builtin_amdgcn_mfma_f32_16x16x32_bf16(a1hi, bhi, acc[1][nt], 0, 0, 0);
      acc[1][nt] = __builtin_amdgcn_mfma_f32_16x16x32_bf16(a1hi, blo, acc[1][nt], 0, 0, 0);
      acc[1][nt] = __builtin_amdgcn_mfma_f32_16x16x32_bf16(a1lo, bhi, acc[1][nt], 0, 0, 0);
    }
  }
#pragma unroll
  for (int m = 0; m < 2; ++m) {
    const int crow0 = mw * 32 + m * 16 + quad * 4;
#pragma unroll
    for (int nt = 0; nt < 8; ++nt) {
      const int col = ng * 128 + nt * 16 + r;
      const float b = bias[col];
      if (obf16) {
#pragma unroll
        for (int i = 0; i < 4; ++i)
          Cb[(size_t)(crow0 + i) * N + col] = f2bf(acc[m][nt][i] + b);
      } else {
#pragma unroll
        for (int i = 0; i < 4; ++i)
          C[(size_t)(crow0 + i) * N + col] = acc[m][nt][i] + b;
      }
    }
  }
}

// ---------------------------------------------------------------------------
// Weight packing into MFMA fragment order (hi/lo split) + fused conv bias
// ---------------------------------------------------------------------------
#define BIH_PAIRS 24576    // (384/16)*(64/32)*512
#define BHH_PAIRS 49152    // 24*4*512
#define WCAT_PAIRS 131072  // 2*32*4*512
#define BCAT_N 1024

__global__ void pack_weights(
    const float* __restrict__ Wih, const float* __restrict__ Whh,
    const float* __restrict__ Wq, const float* __restrict__ Wk,
    const float* __restrict__ Wv, const float* __restrict__ Ws,
    const float* __restrict__ bq, const float* __restrict__ bk,
    const float* __restrict__ bv, const float* __restrict__ bs,
    unsigned short* __restrict__ BihP, unsigned short* __restrict__ BhhP,
    unsigned short* __restrict__ WcatP, float* __restrict__ bcat)
{
  int gid = blockIdx.x * 256 + threadIdx.x;
  if (gid < BIH_PAIRS) {  // K=64, N=384, ktiles=2
    int tile = gid >> 9, lj = gid & 511, lane = lj >> 3, j = lj & 7;
    int k_tile = tile & 1, n_tile = tile >> 1;
    int n = n_tile * 16 + (lane & 15);
    int k = k_tile * 32 + (lane >> 4) * 8 + j;
    unsigned short hi, lo;
    bfsplit(Wih[n * IND + k], hi, lo);   // B[k][n] = Wih^T
    BihP[tile * 1024 + lane * 8 + j] = hi;
    BihP[tile * 1024 + 512 + lane * 8 + j] = lo;
    return;
  }
  gid -= BIH_PAIRS;
  if (gid < BHH_PAIRS) {  // K=128, N=384, ktiles=4
    int tile = gid >> 9, lj = gid & 511, lane = lj >> 3, j = lj & 7;
    int k_tile = tile & 3, n_tile = tile >> 2;
    int n = n_tile * 16 + (lane & 15);
    int k = k_tile * 32 + (lane >> 4) * 8 + j;
    unsigned short hi, lo;
    bfsplit(Whh[n * DD + k], hi, lo);
    BhhP[tile * 1024 + lane * 8 + j] = hi;
    BhhP[tile * 1024 + 512 + lane * 8 + j] = lo;
    return;
  }
  gid -= BHH_PAIRS;
  if (gid < WCAT_PAIRS) {  // per layer: K=128, N=512, ktiles=4
    int l = gid >> 16, rem = gid & 65535;
    int tile = rem >> 9, lj = rem & 511, lane = lj >> 3, j = lj & 7;
    int k_tile = tile & 3, n_tile = tile >> 2;
    int n = n_tile * 16 + (lane & 15);
    int k = k_tile * 32 + (lane >> 4) * 8 + j;
    const float* W = (n < 128) ? Wq : (n < 256) ? Wk : (n < 384) ? Wv : Ws;
    unsigned short hi, lo;
    bfsplit(W[l * DD * DD + k * DD + (n & 127)], hi, lo);
    size_t base = (size_t)l * 131072 + tile * 1024;
    WcatP[base + lane * 8 + j] = hi;
    WcatP[base + 512 + lane * 8 + j] = lo;
    return;
  }
  gid -= WCAT_PAIRS;
  if (gid < BCAT_N) {
    int l = gid >> 9, n = gid & 511;
    const float* b = (n < 128) ? bq : (n < 256) ? bk : (n < 384) ? bv : bs;
    bcat[gid] = b[l * DD + (n & 127)];
  }
}

// ---------------------------------------------------------------------------
__global__ void xsplit(const float* __restrict__ x,
                       unsigned short* __restrict__ xhi,
                       unsigned short* __restrict__ xlo)
{
  int i = blockIdx.x * 256 + threadIdx.x;   // exact T*NN*IND grid
  unsigned short hi, lo;
  bfsplit(x[i], hi, lo);
  xhi[i] = hi; xlo[i] = lo;
}

// ---------------------------------------------------------------------------
// CSR build (by destination), per timestep; parallel 3-phase scan
// ---------------------------------------------------------------------------
#define SCHUNK 1024
#define NCHUNK 20          // ceil(20000/1024)

__global__ void csr_count(const int* __restrict__ ei, int* __restrict__ deg)
{
  int gid = blockIdx.x * 256 + threadIdx.x;
  if (gid >= T_STEPS * EE) return;
  int t = gid / EE, e = gid % EE;
  int dst = ei[(size_t)t * 2 * EE + EE + e];
  atomicAdd(&deg[t * NN + dst], 1);
}

__global__ void scan1(const int* __restrict__ deg, int* __restrict__ part)
{
  const int b = blockIdx.x;              // 0..T*NCHUNK-1
  const int t = b / NCHUNK, c = b % NCHUNK;
  const int tid = threadIdx.x;
  __shared__ int s[256];
  int base = c * SCHUNK + tid * 4;
  int sum = 0;
#pragma unroll
  for (int u = 0; u < 4; ++u) {
    int i = base + u;
    if (i < NN) sum += deg[t * NN + i];
  }
  s[tid] = sum;
  __syncthreads();
  for (int o = 128; o > 0; o >>= 1) {
    if (tid < o) s[tid] += s[tid + o];
    __syncthreads();
  }
  if (tid == 0) part[b] = s[0];
}

__global__ void scan2(int* __restrict__ part, int* __restrict__ offs)
{
  const int tid = threadIdx.x;
  __shared__ int s[T_STEPS * NCHUNK];
  if (tid < T_STEPS * NCHUNK) s[tid] = part[tid];
  __syncthreads();
  if (tid == 0) {
    for (int t = 0; t < T_STEPS; ++t) {
      int run = 0;
      for (int c = 0; c < NCHUNK; ++c) {
        int v = s[t * NCHUNK + c];
        s[t * NCHUNK + c] = run;
        run += v;
      }
      offs[t * (NN + 1) + NN] = run;
    }
  }
  __syncthreads();
  if (tid < T_STEPS * NCHUNK) part[tid] = s[tid];
}

__global__ void scan3(const int* __restrict__ deg, const int* __restrict__ part,
                      int* __restrict__ offs, int* __restrict__ cur)
{
  const int b = blockIdx.x;
  const int t = b / NCHUNK, c = b % NCHUNK;
  const int tid = threadIdx.x;
  __shared__ int s[256];
  int base = c * SCHUNK + tid * 4;
  int v[4]; int sum = 0;
#pragma unroll
  for (int u = 0; u < 4; ++u) {
    int i = base + u;
    v[u] = (i < NN) ? deg[t * NN + i] : 0;
    sum += v[u];
  }
  s[tid] = sum;
  __syncthreads();
  for (int o = 1; o < 256; o <<= 1) {
    int x = (tid >= o) ? s[tid - o] : 0;
    __syncthreads();
    s[tid] += x;
    __syncthreads();
  }
  int excl = part[b] + s[tid] - sum;
#pragma unroll
  for (int u = 0; u < 4; ++u) {
    int i = base + u;
    if (i < NN) {
      offs[t * (NN + 1) + i] = excl;
      cur[t * NN + i] = excl;
    }
    excl += v[u];
  }
}

// packed CSR entry: .x = src node, .y = edge_attr bits (one 8B store per edge)
__global__ void csr_fill(const int* __restrict__ ei, const float* __restrict__ ea,
                         int* __restrict__ cur, int2* __restrict__ cse)
{
  int gid = blockIdx.x * 256 + threadIdx.x;
  if (gid >= T_STEPS * EE) return;
  int t = gid / EE, e = gid % EE;
  int src = ei[(size_t)t * 2 * EE + e];
  int dst = ei[(size_t)t * 2 * EE + EE + e];
  int slot = atomicAdd(&cur[t * NN + dst], 1);
  cse[(size_t)t * EE + slot] = make_int2(src, __float_as_int(ea[(size_t)t * EE + e]));
}

// ---------------------------------------------------------------------------
// GRU gate fusion. t0: gh == b_hh exactly (h0=0), h_prev=0.
// ---------------------------------------------------------------------------
__global__ __launch_bounds__(256) void gru_gate(
    const float* __restrict__ gi, const float* __restrict__ gh,
    const float* __restrict__ b_hh, int t0,
    const unsigned short* __restrict__ phi, const unsigned short* __restrict__ plo,
    unsigned short* __restrict__ hhi_t, unsigned short* __restrict__ hlo_t)
{
  int idx = blockIdx.x * 256 + threadIdx.x;   // exact NN*DD grid
  int n = idx >> 7, d = idx & 127;
  size_t gb = (size_t)n * G3 + d;
  float ir = gi[gb], iz = gi[gb + DD], inn = gi[gb + 2 * DD];
  float hr, hz, hn, hp;
  if (t0) {
    hr = b_hh[d]; hz = b_hh[DD + d]; hn = b_hh[2 * DD + d]; hp = 0.f;
  } else {
    hr = gh[gb]; hz = gh[gb + DD]; hn = gh[gb + 2 * DD];
    hp = bf2f(phi[idx]) + bf2f(plo[idx]);
  }
  float r = 1.f / (1.f + __expf(-(ir + hr)));
  float z = 1.f / (1.f + __expf(-(iz + hz)));
  float nv = tanhf(inn + r * hn);
  float hnew = (1.f - z) * nv + z * hp;
  unsigned short hi, lo;
  bfsplit(hnew, hi, lo);
  hhi_t[idx] = hi; hlo_t[idx] = lo;
}

// ---------------------------------------------------------------------------
// Fused TransformerConv (d=128), all T via blockIdx.y. qkvb is bf16 [T][NN][512].
// One wave per dst node; lane = (eslot 0..7) x (feature-group 0..7, 16 floats).
// No-max softmax (|alpha| is O(1) by weight-scale bounds; exp safe to |a|<80).
// Edge-feature factored: agg = (S ex*v + (S ex*a)*We)/l. All cross-lane
// reductions deferred to the epilogue except the 3-shuffle q.k dot.
// ---------------------------------------------------------------------------
__global__ __launch_bounds__(256) void attn_conv(
    const unsigned short* __restrict__ qkvb,  // [T][NN][512] bf16
    const int* __restrict__ offs4,    // [T][NN+1]
    const int2* __restrict__ cse4,    // [T][E]
    const float* __restrict__ We,     // [128]
    unsigned short* __restrict__ hhi4, unsigned short* __restrict__ hlo4)
{
  const int t = blockIdx.y;
  const unsigned short* qk = qkvb + (size_t)t * NN * QS;
  const int* offs = offs4 + (size_t)t * (NN + 1);
  const int2* cse = cse4 + (size_t)t * EE;
  const int wv = (blockIdx.x * 256 + threadIdx.x) >> 6;
  const int lane = threadIdx.x & 63;
  if (wv >= NN) return;
  const int fg = lane & 7, es = lane >> 3;
  const int f0 = fg * 16;
  const float scale = 0.08838834764831845f;   // 1/sqrt(128)

  float qf[16], wf[16];
  ld16bf(qk + (size_t)wv * QS + f0, qf);
#pragma unroll
  for (int j = 0; j < 16; j += 4)
    *(float4*)&wf[j] = *(const float4*)&We[f0 + j];
  float qwe = 0.f;
#pragma unroll
  for (int j = 0; j < 16; ++j) qwe = fmaf(qf[j], wf[j], qwe);
  qwe += __shfl_xor(qwe, 1); qwe += __shfl_xor(qwe, 2); qwe += __shfl_xor(qwe, 4);

  const int e0 = offs[wv], e1 = offs[wv + 1];
  float l_lane = 0.f, sA_lane = 0.f;
  float acc[16];
#pragma unroll
  for (int i = 0; i < 16; ++i) acc[i] = 0.f;

  for (int base = e0; base < e1; base += 8) {
    const int eidx = base + es;
    const bool valid = eidx < e1;
    int2 se = valid ? cse[eidx] : make_int2(0, 0);
    const int s = se.x;
    const float a = __int_as_float(se.y);
    float kf[16];
    ld16bf(qk + (size_t)s * QS + 128 + f0, kf);
    float p = 0.f;
#pragma unroll
    for (int j = 0; j < 16; ++j) p = fmaf(qf[j], kf[j], p);
    p += __shfl_xor(p, 1); p += __shfl_xor(p, 2); p += __shfl_xor(p, 4);
    const float ex = valid ? __expf((p + a * qwe) * scale) : 0.f;
    l_lane += ex;
    sA_lane = fmaf(ex, a, sA_lane);
    float vf[16];
    ld16bf(qk + (size_t)s * QS + 256 + f0, vf);
#pragma unroll
    for (int j = 0; j < 16; ++j)
      acc[j] = fmaf(ex, vf[j], acc[j]);
  }
  // epilogue reductions over the 8 edge-slots
  l_lane += __shfl_xor(l_lane, 8); l_lane += __shfl_xor(l_lane, 16); l_lane += __shfl_xor(l_lane, 32);
  sA_lane += __shfl_xor(sA_lane, 8); sA_lane += __shfl_xor(sA_lane, 16); sA_lane += __shfl_xor(sA_lane, 32);
#pragma unroll
  for (int i = 0; i < 16; ++i) {
    acc[i] += __shfl_xor(acc[i], 8);
    acc[i] += __shfl_xor(acc[i], 16);
    acc[i] += __shfl_xor(acc[i], 32);
  }
  if (es != 0) return;
  const float inv = 1.f / (l_lane + 1e-16f);
  const float sAi = sA_lane * inv;
  float sf[16];
  ld16bf(qk + (size_t)wv * QS + 384 + f0, sf);
  unsigned hp[8], lp[8];
#pragma unroll
  for (int j = 0; j < 8; ++j) {
    float oa = fmaf(acc[2 * j], inv, fmaf(sAi, wf[2 * j], sf[2 * j]));
    float ob = fmaf(acc[2 * j + 1], inv, fmaf(sAi, wf[2 * j + 1], sf[2 * j + 1]));
    oa = (oa > 0.f) ? oa : 0.01f * oa;    // leaky_relu
    ob = (ob > 0.f) ? ob : 0.01f * ob;
    unsigned short ha, la, hb, lb;
    bfsplit(oa, ha, la); bfsplit(ob, hb, lb);
    hp[j] = ((unsigned)hb << 16) | ha;
    lp[j] = ((unsigned)lb << 16) | la;
  }
  unsigned short* hdst = hhi4 + ((size_t)t * NN + wv) * DD + f0;
  unsigned short* ldst = hlo4 + ((size_t)t * NN + wv) * DD + f0;
  *(uint4*)(hdst + 0) = make_uint4(hp[0], hp[1], hp[2], hp[3]);
  *(uint4*)(hdst + 8) = make_uint4(hp[4], hp[5], hp[6], hp[7]);
  *(uint4*)(ldst + 0) = make_uint4(lp[0], lp[1], lp[2], lp[3]);
  *(uint4*)(ldst + 8) = make_uint4(lp[4], lp[5], lp[6], lp[7]);
}

// ---------------------------------------------------------------------------
// mean over T from bf16 hi/lo split (hi+lo ~= fp32); 2 elems per thread
// ---------------------------------------------------------------------------
__global__ void mean_k(const unsigned short* __restrict__ hhi,
                       const unsigned short* __restrict__ hlo,
                       float* __restrict__ hm)
{
  int i = blockIdx.x * 256 + threadIdx.x;   // exact NN*DD/2 grid
  float vx = 0.f, vy = 0.f;
#pragma unroll
  for (int t = 0; t < T_STEPS; ++t) {
    unsigned h = *(const unsigned*)&hhi[(size_t)t * NN * DD + 2 * i];
    unsigned l = *(const unsigned*)&hlo[(size_t)t * NN * DD + 2 * i];
    vx += __uint_as_float(h << 16) + __uint_as_float(l << 16);
    vy += __uint_as_float(h & 0xffff0000u) + __uint_as_float(l & 0xffff0000u);
  }
  *(float2*)&hm[2 * i] = make_float2(0.25f * vx, 0.25f * vy);
}

// ---------------------------------------------------------------------------
__global__ __launch_bounds__(256) void out_proj(
    const float* __restrict__ h,
    const float* __restrict__ Wq, const float* __restrict__ Wk,
    const float* __restrict__ Wv, const float* __restrict__ Ws,
    const float* __restrict__ bq, const float* __restrict__ bk,
    const float* __restrict__ bv, const float* __restrict__ bs,
    float* __restrict__ q1, float* __restrict__ k1,
    float* __restrict__ v1, float* __restrict__ s1)
{
  const int wv = (blockIdx.x * 256 + threadIdx.x) >> 6;
  const int lane = threadIdx.x & 63;
  if (wv >= NN) return;
  float2 h2 = *(const float2*)&h[(size_t)wv * DD + 2 * lane];
  float pq = h2.x * Wq[2 * lane] + h2.y * Wq[2 * lane + 1];
  float pk = h2.x * Wk[2 * lane] + h2.y * Wk[2 * lane + 1];
  float pv = h2.x * Wv[2 * lane] + h2.y * Wv[2 * lane + 1];
  float ps = h2.x * Ws[2 * lane] + h2.y * Ws[2 * lane + 1];
#pragma unroll
  for (int o = 1; o < 64; o <<= 1) {
    pq += __shfl_xor(pq, o); pk += __shfl_xor(pk, o);
    pv += __shfl_xor(pv, o); ps += __shfl_xor(ps, o);
  }
  if (lane == 0) {
    q1[wv] = pq + bq[0]; k1[wv] = pk + bk[0];
    v1[wv] = pv + bv[0]; s1[wv] = ps + bs[0];
  }
}

__global__ void out_attn(
    const float* __restrict__ q1, const float* __restrict__ k1,
    const float* __restrict__ v1, const float* __restrict__ s1,
    const int* __restrict__ offs, const int2* __restrict__ cse,
    const float* __restrict__ We, float* __restrict__ out)
{
  int n = blockIdx.x * 256 + threadIdx.x;
  if (n >= NN) return;
  const float we = We[0];
  const float q = q1[n];
  const int e0 = offs[n], e1 = offs[n + 1];
  float m = -INFINITY;
  for (int e = e0; e < e1; ++e) {
    int2 se = cse[e];
    float al = q * (k1[se.x] + __int_as_float(se.y) * we);
    m = fmaxf(m, al);
  }
  float l = 0.f, acc = 0.f;
  for (int e = e0; e < e1; ++e) {
    int2 se = cse[e];
    float ca = __int_as_float(se.y);
    float al = q * (k1[se.x] + ca * we);
    float ex = __expf(al - m);
    l += ex;
    acc += ex * (v1[se.x] + ca * we);
  }
  out[n] = acc / (l + 1e-16f) + s1[n];
}

// ---------------------------------------------------------------------------
extern "C" void kernel_launch(void* const* d_in, const int* in_sizes, int n_in,
                              void* d_out, int out_size, void* d_ws, size_t ws_size,
                              hipStream_t stream)
{
  const float* x_seq = (const float*)d_in[0];
  const int*   ei    = (const int*)  d_in[1];
  const float* ea    = (const float*)d_in[2];
  const float* W_ih  = (const float*)d_in[3];
  const float* W_hh  = (const float*)d_in[4];
  const float* b_ih  = (const float*)d_in[5];
  const float* b_hh  = (const float*)d_in[6];
  const float* cWq   = (const float*)d_in[7];
  const float* cbq   = (const float*)d_in[8];
  const float* cWk   = (const float*)d_in[9];
  const float* cbk   = (const float*)d_in[10];
  const float* cWv   = (const float*)d_in[11];
  const float* cbv   = (const float*)d_in[12];
  const float* cWe   = (const float*)d_in[13];
  const float* cWs   = (const float*)d_in[14];
  const float* cbs   = (const float*)d_in[15];
  const float* oWq   = (const float*)d_in[16];
  const float* obq   = (const float*)d_in[17];
  const float* oWk   = (const float*)d_in[18];
  const float* obk   = (const float*)d_in[19];
  const float* oWv   = (const float*)d_in[20];
  const float* obv   = (const float*)d_in[21];
  const float* oWe   = (const float*)d_in[22];
  const float* oWs   = (const float*)d_in[23];
  const float* obs   = (const float*)d_in[24];
  float* out = (float*)d_out;

  char* ws = (char*)d_ws;
  size_t off = 0;
  auto alloc = [&](size_t bytes) -> char* {
    char* p = ws + off;
    off += (bytes + 255) & ~(size_t)255;
    return p;
  };
  // ---- total ~171 MB (round-4/5 proven; round-3's 289 MB aborted) ----
  unsigned short* BihP  = (unsigned short*)alloc((size_t)2 * BIH_PAIRS * 2);
  unsigned short* BhhP  = (unsigned short*)alloc((size_t)2 * BHH_PAIRS * 2);
  unsigned short* WcatP = (unsigned short*)alloc((size_t)2 * WCAT_PAIRS * 2);
  float* fbcat = (float*)alloc((size_t)BCAT_N * 4);
  unsigned short* xhi   = (unsigned short*)alloc((size_t)T_STEPS * NN * IND * 2);
  unsigned short* xlo   = (unsigned short*)alloc((size_t)T_STEPS * NN * IND * 2);
  unsigned short* hallhi = (unsigned short*)alloc((size_t)T_STEPS * NN * DD * 2);
  unsigned short* halllo = (unsigned short*)alloc((size_t)T_STEPS * NN * DD * 2);
  float* fH    = (float*)alloc((size_t)NN * DD * 4);          // h_mean
  int*   iDeg  = (int*)  alloc((size_t)T_STEPS * NN * 4);     // zero-init
  int*   iCur  = (int*)  alloc((size_t)T_STEPS * NN * 4);
  int*   iOffs = (int*)  alloc((size_t)T_STEPS * (NN + 1) * 4);
  int*   iPart = (int*)  alloc((size_t)T_STEPS * NCHUNK * 4);
  int2*  iSE   = (int2*) alloc((size_t)T_STEPS * EE * 8);
  float* fQ1   = (float*)alloc((size_t)NN * 4);
  float* fK1   = (float*)alloc((size_t)NN * 4);
  float* fV1   = (float*)alloc((size_t)NN * 4);
  float* fS1   = (float*)alloc((size_t)NN * 4);
  // union: GRU uses gi2 [2NN*G3 fp32] + gh [NN*G3 fp32] = 92.2 MB;
  //        conv uses qkvb [4NN*512 bf16] = 81.9 MB
  size_t uniOff = off;
  float* fGi2  = (float*)(ws + uniOff);
  float* fGh   = (float*)(ws + uniOff + (size_t)2 * NN * G3 * 4);
  unsigned short* qkvb = (unsigned short*)(ws + uniOff);
  (void)ws_size; (void)in_sizes; (void)n_in; (void)out_size;

  auto gemm = [&](const unsigned short* Ahi, const unsigned short* Alo,
                  const unsigned short* Bp, const float* bias, float* C,
                  unsigned short* Cb, int M, int N, int K, int obf16) {
    int waves = (M >> 5) * (N >> 7);
    gemm_mfma<<<(waves + 3) / 4, 256, 0, stream>>>(Ahi, Alo, Bp, bias, C, Cb,
                                                   M, N, K, obf16);
  };

  // weights + activation split + CSR
  pack_weights<<<(BIH_PAIRS + BHH_PAIRS + WCAT_PAIRS + BCAT_N + 255) / 256, 256, 0,
                 stream>>>(W_ih, W_hh, cWq, cWk, cWv, cWs, cbq, cbk, cbv, cbs,
                           BihP, BhhP, WcatP, fbcat);
  xsplit<<<(T_STEPS * NN * IND) / 256, 256, 0, stream>>>(x_seq, xhi, xlo);
  hipMemsetAsync(iDeg, 0, (size_t)T_STEPS * NN * 4, stream);
  csr_count<<<(T_STEPS * EE) / 256, 256, 0, stream>>>(ei, iDeg);
  scan1<<<T_STEPS * NCHUNK, 256, 0, stream>>>(iDeg, iPart);
  scan2<<<1, 128, 0, stream>>>(iPart, iOffs);
  scan3<<<T_STEPS * NCHUNK, 256, 0, stream>>>(iDeg, iPart, iOffs, iCur);
  csr_fill<<<(T_STEPS * EE) / 256, 256, 0, stream>>>(ei, ea, iCur, iSE);

  // GRU over time: gi batched in pairs of t, gh sequential (t=0 skipped)
  for (int tp = 0; tp < 2; ++tp) {
    gemm(xhi + (size_t)tp * 2 * NN * IND, xlo + (size_t)tp * 2 * NN * IND,
         BihP, b_ih, fGi2, nullptr, 2 * NN, G3, IND, 0);
    for (int k = 0; k < 2; ++k) {
      const int t = tp * 2 + k;
      const unsigned short* phi = hallhi + (size_t)(t - 1) * NN * DD;  // unused t=0
      const unsigned short* plo = halllo + (size_t)(t - 1) * NN * DD;
      if (t > 0) gemm(phi, plo, BhhP, b_hh, fGh, nullptr, NN, G3, DD, 0);
      gru_gate<<<(NN * DD) / 256, 256, 0, stream>>>(
          fGi2 + (size_t)k * NN * G3, fGh, b_hh, (t == 0) ? 1 : 0,
          (t == 0) ? hallhi : phi, (t == 0) ? halllo : plo,
          hallhi + (size_t)t * NN * DD, halllo + (size_t)t * NN * DD);
    }
  }

  // stacked TransformerConv layers, full T batch, bf16 qkvb
  for (int l = 0; l < 2; ++l) {
    gemm(hallhi, halllo, WcatP + (size_t)l * 131072, fbcat + (size_t)l * QS,
         nullptr, qkvb, T_STEPS * NN, QS, DD, 1);
    dim3 ag((NN * 64) / 256, T_STEPS);
    attn_conv<<<ag, 256, 0, stream>>>(qkvb, iOffs, iSE, cWe + l * DD,
                                      hallhi, halllo);
  }

  // mean over T (reconstruct fp32 from hi+lo)
  mean_k<<<(NN * DD / 2) / 256, 256, 0, stream>>>(hallhi, halllo, fH);

  // output conv (d=1) on t=3 graph
  out_proj<<<(NN * 64) / 256, 256, 0, stream>>>(
      fH, oWq, oWk, oWv, oWs, obq, obk, obv, obs, fQ1, fK1, fV1, fS1);
  out_attn<<<(NN + 255) / 256, 256, 0, stream>>>(
      fQ1, fK1, fV1, fS1, iOffs + 3 * (NN + 1), iSE + (size_t)3 * EE, oWe, out);
}

// Round 8
// 562.341 us; speedup vs baseline: 1.6747x; 1.1093x over previous
//
#include <hip/hip_runtime.h>
#include <math.h>

#define T_STEPS 4
#define NN 20000
#define EE 160000
#define IND 64
#define DD 128
#define G3 384     // 3*D (GRU gates)
#define QS 512     // q|k|v|skip fused width

typedef __bf16 bf16x8 __attribute__((ext_vector_type(8)));
typedef float floatx4 __attribute__((ext_vector_type(4)));

// ---------------------------------------------------------------------------
// fp32 -> bf16 split (RNE): x ~= hi + lo, |x-(hi+lo)| <~ 2^-18 |x|
// ---------------------------------------------------------------------------
__device__ inline unsigned short f2bf(float x) {
  unsigned u = __float_as_uint(x);
  unsigned r = (u + 0x7fffu + ((u >> 16) & 1u)) >> 16;
  return (unsigned short)r;
}
__device__ inline float bf2f(unsigned short h) {
  return __uint_as_float((unsigned)h << 16);
}
__device__ inline void bfsplit(float x, unsigned short& hi, unsigned short& lo) {
  hi = f2bf(x);
  lo = f2bf(x - bf2f(hi));
}
// load 16 consecutive bf16 -> fp32 (32B, two dwordx4)
__device__ inline void ld16bf(const unsigned short* p, float* f) {
  const uint4 u0 = *(const uint4*)p;
  const uint4 u1 = *(const uint4*)(p + 8);
  f[0] = __uint_as_float(u0.x << 16);  f[1] = __uint_as_float(u0.x & 0xffff0000u);
  f[2] = __uint_as_float(u0.y << 16);  f[3] = __uint_as_float(u0.y & 0xffff0000u);
  f[4] = __uint_as_float(u0.z << 16);  f[5] = __uint_as_float(u0.z & 0xffff0000u);
  f[6] = __uint_as_float(u0.w << 16);  f[7] = __uint_as_float(u0.w & 0xffff0000u);
  f[8]  = __uint_as_float(u1.x << 16); f[9]  = __uint_as_float(u1.x & 0xffff0000u);
  f[10] = __uint_as_float(u1.y << 16); f[11] = __uint_as_float(u1.y & 0xffff0000u);
  f[12] = __uint_as_float(u1.z << 16); f[13] = __uint_as_float(u1.z & 0xffff0000u);
  f[14] = __uint_as_float(u1.w << 16); f[15] = __uint_as_float(u1.w & 0xffff0000u);
}

// ---------------------------------------------------------------------------
// Split-bf16 MFMA GEMM: C = (Ahi+Alo) x (Bhi+Blo) + bias (3-MFMA terms).
// obf16=0 -> fp32 C ; obf16=1 -> bf16 Cb. Wave: 32 rows x 128 cols.
// ROUND-5 PROVEN — 64-row tile spilled (r6: WRITE 634 MB). Do not enlarge.
// ---------------------------------------------------------------------------
__global__ __launch_bounds__(256) void gemm_mfma(
    const unsigned short* __restrict__ Ahi, const unsigned short* __restrict__ Alo,
    const unsigned short* __restrict__ Bp, const float* __restrict__ bias,
    float* __restrict__ C, unsigned short* __restrict__ Cb,
    int M, int N, int K, int obf16)
{
  const int wave = (blockIdx.x * 256 + threadIdx.x) >> 6;
  const int lane = threadIdx.x & 63;
  const int ngroups = N >> 7;          // N/128
  const int mtiles = M >> 5;           // 32 rows per wave
  if (wave >= mtiles * ngroups) return;
  const int mw = wave / ngroups;
  const int ng = wave - mw * ngroups;
  const int r = lane & 15, quad = lane >> 4;
  const int ktiles = K >> 5;
  const unsigned short* a0h = Ahi + (size_t)(mw * 32 + r) * K + quad * 8;
  const unsigned short* a0l = Alo + (size_t)(mw * 32 + r) * K + quad * 8;
  const unsigned short* a1h = a0h + (size_t)16 * K;
  const unsigned short* a1l = a0l + (size_t)16 * K;
  floatx4 acc[2][8];
#pragma unroll
  for (int m = 0; m < 2; ++m)
#pragma unroll
    for (int nt = 0; nt < 8; ++nt) acc[m][nt] = (floatx4){0.f, 0.f, 0.f, 0.f};
  const int n0t = ng * 8;
  for (int kt = 0; kt < ktiles; ++kt) {
    bf16x8 a0hi = *(const bf16x8*)(a0h + kt * 32);
    bf16x8 a0lo = *(const bf16x8*)(a0l + kt * 32);
    bf16x8 a1hi = *(const bf16x8*)(a1h + kt * 32);
    bf16x8 a1lo = *(const bf16x8*)(a1l + kt * 32);
#pragma unroll
    for (int nt = 0; nt < 8; ++nt) {
      const unsigned short* bp =
          Bp + ((size_t)((n0t + nt) * ktiles + kt)) * 1024 + lane * 8;
      bf16x8 bhi = *(const bf16x8*)bp;
      bf16x8 blo = *(const bf16x8*)(bp + 512);
      acc[0][nt] = __builtin_amdgcn_mfma_f32_16x16x32_bf16(a0hi, bhi, acc[0][nt], 0, 0, 0);
      acc[0][nt] = __builtin_amdgcn_mfma_f32_16x16x32_bf16(a0hi, blo, acc[0][nt], 0, 0, 0);
      acc[0][nt] = __builtin_amdgcn_mfma_f32_16x16x32_bf16(a0lo, bhi, acc[0][nt], 0, 0, 0);
      acc[1][nt] = __builtin_amdgcn_mfma_f32_16x16x32_bf16(a1hi, bhi, acc[1][nt], 0, 0, 0);
      acc[1][nt] = __builtin_amdgcn_mfma_f32_16x16x32_bf16(a1hi, blo, acc[1][nt], 0, 0, 0);
      acc[1][nt] = __builtin_amdgcn_mfma_f32_16x16x32_bf16(a1lo, bhi, acc[1][nt], 0, 0, 0);
    }
  }
#pragma unroll
  for (int m = 0; m < 2; ++m) {
    const int crow0 = mw * 32 + m * 16 + quad * 4;
#pragma unroll
    for (int nt = 0; nt < 8; ++nt) {
      const int col = ng * 128 + nt * 16 + r;
      const float b = bias[col];
      if (obf16) {
#pragma unroll
        for (int i = 0; i < 4; ++i)
          Cb[(size_t)(crow0 + i) * N + col] = f2bf(acc[m][nt][i] + b);
      } else {
#pragma unroll
        for (int i = 0; i < 4; ++i)
          C[(size_t)(crow0 + i) * N + col] = acc[m][nt][i] + b;
      }
    }
  }
}

// ---------------------------------------------------------------------------
// Single-bf16-A MFMA GEMM: C = A x (Bhi+Blo) + bias, bf16 out (2 MFMA/tile).
// A is plain bf16 row-major [M][K]. Separate kernel: no runtime branch in
// K-loop (r6 spill lesson).
// ---------------------------------------------------------------------------
__global__ __launch_bounds__(256) void gemm_mfma_b1(
    const unsigned short* __restrict__ A,
    const unsigned short* __restrict__ Bp, const float* __restrict__ bias,
    unsigned short* __restrict__ Cb, int M, int N, int K)
{
  const int wave = (blockIdx.x * 256 + threadIdx.x) >> 6;
  const int lane = threadIdx.x & 63;
  const int ngroups = N >> 7;
  const int mtiles = M >> 5;
  if (wave >= mtiles * ngroups) return;
  const int mw = wave / ngroups;
  const int ng = wave - mw * ngroups;
  const int r = lane & 15, quad = lane >> 4;
  const int ktiles = K >> 5;
  const unsigned short* a0 = A + (size_t)(mw * 32 + r) * K + quad * 8;
  const unsigned short* a1 = a0 + (size_t)16 * K;
  floatx4 acc[2][8];
#pragma unroll
  for (int m = 0; m < 2; ++m)
#pragma unroll
    for (int nt = 0; nt < 8; ++nt) acc[m][nt] = (floatx4){0.f, 0.f, 0.f, 0.f};
  const int n0t = ng * 8;
  for (int kt = 0; kt < ktiles; ++kt) {
    bf16x8 af0 = *(const bf16x8*)(a0 + kt * 32);
    bf16x8 af1 = *(const bf16x8*)(a1 + kt * 32);
#pragma unroll
    for (int nt = 0; nt < 8; ++nt) {
      const unsigned short* bp =
          Bp + ((size_t)((n0t + nt) * ktiles + kt)) * 1024 + lane * 8;
      bf16x8 bhi = *(const bf16x8*)bp;
      bf16x8 blo = *(const bf16x8*)(bp + 512);
      acc[0][nt] = __builtin_amdgcn_mfma_f32_16x16x32_bf16(af0, bhi, acc[0][nt], 0, 0, 0);
      acc[0][nt] = __builtin_amdgcn_mfma_f32_16x16x32_bf16(af0, blo, acc[0][nt], 0, 0, 0);
      acc[1][nt] = __builtin_amdgcn_mfma_f32_16x16x32_bf16(af1, bhi, acc[1][nt], 0, 0, 0);
      acc[1][nt] = __builtin_amdgcn_mfma_f32_16x16x32_bf16(af1, blo, acc[1][nt], 0, 0, 0);
    }
  }
#pragma unroll
  for (int m = 0; m < 2; ++m) {
    const int crow0 = mw * 32 + m * 16 + quad * 4;
#pragma unroll
    for (int nt = 0; nt < 8; ++nt) {
      const int col = ng * 128 + nt * 16 + r;
      const float b = bias[col];
#pragma unroll
      for (int i = 0; i < 4; ++i)
        Cb[(size_t)(crow0 + i) * N + col] = f2bf(acc[m][nt][i] + b);
    }
  }
}

// ---------------------------------------------------------------------------
// Weight packing into MFMA fragment order (hi/lo split) + fused conv bias
// ---------------------------------------------------------------------------
#define BIH_PAIRS 24576    // (384/16)*(64/32)*512
#define BHH_PAIRS 49152    // 24*4*512
#define WCAT_PAIRS 131072  // 2*32*4*512
#define BCAT_N 1024

__global__ void pack_weights(
    const float* __restrict__ Wih, const float* __restrict__ Whh,
    const float* __restrict__ Wq, const float* __restrict__ Wk,
    const float* __restrict__ Wv, const float* __restrict__ Ws,
    const float* __restrict__ bq, const float* __restrict__ bk,
    const float* __restrict__ bv, const float* __restrict__ bs,
    unsigned short* __restrict__ BihP, unsigned short* __restrict__ BhhP,
    unsigned short* __restrict__ WcatP, float* __restrict__ bcat)
{
  int gid = blockIdx.x * 256 + threadIdx.x;
  if (gid < BIH_PAIRS) {  // K=64, N=384, ktiles=2
    int tile = gid >> 9, lj = gid & 511, lane = lj >> 3, j = lj & 7;
    int k_tile = tile & 1, n_tile = tile >> 1;
    int n = n_tile * 16 + (lane & 15);
    int k = k_tile * 32 + (lane >> 4) * 8 + j;
    unsigned short hi, lo;
    bfsplit(Wih[n * IND + k], hi, lo);   // B[k][n] = Wih^T
    BihP[tile * 1024 + lane * 8 + j] = hi;
    BihP[tile * 1024 + 512 + lane * 8 + j] = lo;
    return;
  }
  gid -= BIH_PAIRS;
  if (gid < BHH_PAIRS) {  // K=128, N=384, ktiles=4
    int tile = gid >> 9, lj = gid & 511, lane = lj >> 3, j = lj & 7;
    int k_tile = tile & 3, n_tile = tile >> 2;
    int n = n_tile * 16 + (lane & 15);
    int k = k_tile * 32 + (lane >> 4) * 8 + j;
    unsigned short hi, lo;
    bfsplit(Whh[n * DD + k], hi, lo);
    BhhP[tile * 1024 + lane * 8 + j] = hi;
    BhhP[tile * 1024 + 512 + lane * 8 + j] = lo;
    return;
  }
  gid -= BHH_PAIRS;
  if (gid < WCAT_PAIRS) {  // per layer: K=128, N=512, ktiles=4
    int l = gid >> 16, rem = gid & 65535;
    int tile = rem >> 9, lj = rem & 511, lane = lj >> 3, j = lj & 7;
    int k_tile = tile & 3, n_tile = tile >> 2;
    int n = n_tile * 16 + (lane & 15);
    int k = k_tile * 32 + (lane >> 4) * 8 + j;
    const float* W = (n < 128) ? Wq : (n < 256) ? Wk : (n < 384) ? Wv : Ws;
    unsigned short hi, lo;
    bfsplit(W[l * DD * DD + k * DD + (n & 127)], hi, lo);
    size_t base = (size_t)l * 131072 + tile * 1024;
    WcatP[base + lane * 8 + j] = hi;
    WcatP[base + 512 + lane * 8 + j] = lo;
    return;
  }
  gid -= WCAT_PAIRS;
  if (gid < BCAT_N) {
    int l = gid >> 9, n = gid & 511;
    const float* b = (n < 128) ? bq : (n < 256) ? bk : (n < 384) ? bv : bs;
    bcat[gid] = b[l * DD + (n & 127)];
  }
}

// ---------------------------------------------------------------------------
__global__ void xsplit(const float* __restrict__ x,
                       unsigned short* __restrict__ xhi,
                       unsigned short* __restrict__ xlo)
{
  int i = blockIdx.x * 256 + threadIdx.x;   // exact T*NN*IND grid
  unsigned short hi, lo;
  bfsplit(x[i], hi, lo);
  xhi[i] = hi; xlo[i] = lo;
}

// ---------------------------------------------------------------------------
// CSR build (by destination), per timestep; parallel 3-phase scan
// ---------------------------------------------------------------------------
#define SCHUNK 1024
#define NCHUNK 20          // ceil(20000/1024)

__global__ void csr_count(const int* __restrict__ ei, int* __restrict__ deg)
{
  int gid = blockIdx.x * 256 + threadIdx.x;
  if (gid >= T_STEPS * EE) return;
  int t = gid / EE, e = gid % EE;
  int dst = ei[(size_t)t * 2 * EE + EE + e];
  atomicAdd(&deg[t * NN + dst], 1);
}

__global__ void scan1(const int* __restrict__ deg, int* __restrict__ part)
{
  const int b = blockIdx.x;              // 0..T*NCHUNK-1
  const int t = b / NCHUNK, c = b % NCHUNK;
  const int tid = threadIdx.x;
  __shared__ int s[256];
  int base = c * SCHUNK + tid * 4;
  int sum = 0;
#pragma unroll
  for (int u = 0; u < 4; ++u) {
    int i = base + u;
    if (i < NN) sum += deg[t * NN + i];
  }
  s[tid] = sum;
  __syncthreads();
  for (int o = 128; o > 0; o >>= 1) {
    if (tid < o) s[tid] += s[tid + o];
    __syncthreads();
  }
  if (tid == 0) part[b] = s[0];
}

__global__ void scan2(int* __restrict__ part, int* __restrict__ offs)
{
  const int tid = threadIdx.x;
  __shared__ int s[T_STEPS * NCHUNK];
  if (tid < T_STEPS * NCHUNK) s[tid] = part[tid];
  __syncthreads();
  if (tid == 0) {
    for (int t = 0; t < T_STEPS; ++t) {
      int run = 0;
      for (int c = 0; c < NCHUNK; ++c) {
        int v = s[t * NCHUNK + c];
        s[t * NCHUNK + c] = run;
        run += v;
      }
      offs[t * (NN + 1) + NN] = run;
    }
  }
  __syncthreads();
  if (tid < T_STEPS * NCHUNK) part[tid] = s[tid];
}

__global__ void scan3(const int* __restrict__ deg, const int* __restrict__ part,
                      int* __restrict__ offs, int* __restrict__ cur)
{
  const int b = blockIdx.x;
  const int t = b / NCHUNK, c = b % NCHUNK;
  const int tid = threadIdx.x;
  __shared__ int s[256];
  int base = c * SCHUNK + tid * 4;
  int v[4]; int sum = 0;
#pragma unroll
  for (int u = 0; u < 4; ++u) {
    int i = base + u;
    v[u] = (i < NN) ? deg[t * NN + i] : 0;
    sum += v[u];
  }
  s[tid] = sum;
  __syncthreads();
  for (int o = 1; o < 256; o <<= 1) {
    int x = (tid >= o) ? s[tid - o] : 0;
    __syncthreads();
    s[tid] += x;
    __syncthreads();
  }
  int excl = part[b] + s[tid] - sum;
#pragma unroll
  for (int u = 0; u < 4; ++u) {
    int i = base + u;
    if (i < NN) {
      offs[t * (NN + 1) + i] = excl;
      cur[t * NN + i] = excl;
    }
    excl += v[u];
  }
}

// packed CSR entry: .x = src node, .y = edge_attr bits (one 8B store per edge)
__global__ void csr_fill(const int* __restrict__ ei, const float* __restrict__ ea,
                         int* __restrict__ cur, int2* __restrict__ cse)
{
  int gid = blockIdx.x * 256 + threadIdx.x;
  if (gid >= T_STEPS * EE) return;
  int t = gid / EE, e = gid % EE;
  int src = ei[(size_t)t * 2 * EE + e];
  int dst = ei[(size_t)t * 2 * EE + EE + e];
  int slot = atomicAdd(&cur[t * NN + dst], 1);
  cse[(size_t)t * EE + slot] = make_int2(src, __float_as_int(ea[(size_t)t * EE + e]));
}

// ---------------------------------------------------------------------------
// GRU gate fusion. t0: gh == b_hh exactly (h0=0), h_prev=0.
// ---------------------------------------------------------------------------
__global__ __launch_bounds__(256) void gru_gate(
    const float* __restrict__ gi, const float* __restrict__ gh,
    const float* __restrict__ b_hh, int t0,
    const unsigned short* __restrict__ phi, const unsigned short* __restrict__ plo,
    unsigned short* __restrict__ hhi_t, unsigned short* __restrict__ hlo_t)
{
  int idx = blockIdx.x * 256 + threadIdx.x;   // exact NN*DD grid
  int n = idx >> 7, d = idx & 127;
  size_t gb = (size_t)n * G3 + d;
  float ir = gi[gb], iz = gi[gb + DD], inn = gi[gb + 2 * DD];
  float hr, hz, hn, hp;
  if (t0) {
    hr = b_hh[d]; hz = b_hh[DD + d]; hn = b_hh[2 * DD + d]; hp = 0.f;
  } else {
    hr = gh[gb]; hz = gh[gb + DD]; hn = gh[gb + 2 * DD];
    hp = bf2f(phi[idx]) + bf2f(plo[idx]);
  }
  float r = 1.f / (1.f + __expf(-(ir + hr)));
  float z = 1.f / (1.f + __expf(-(iz + hz)));
  float nv = tanhf(inn + r * hn);
  float hnew = (1.f - z) * nv + z * hp;
  unsigned short hi, lo;
  bfsplit(hnew, hi, lo);
  hhi_t[idx] = hi; hlo_t[idx] = lo;
}

// ---------------------------------------------------------------------------
// Fused TransformerConv (d=128), all T via blockIdx.y. qkvb bf16 [T][NN][512].
// TWO nodes per wave: lane = half(1b) | es(2b) | fg(3b); per node 4 edge-slots
// x 8 feature-groups (16 floats each). No-max softmax + factored edge feature
// (r7-verified). Output: single bf16 [T][NN][128] (feeds gemm_mfma_b1 + mean).
// ---------------------------------------------------------------------------
__global__ __launch_bounds__(256) void attn_conv(
    const unsigned short* __restrict__ qkvb,  // [T][NN][512] bf16
    const int* __restrict__ offs4,    // [T][NN+1]
    const int2* __restrict__ cse4,    // [T][E]
    const float* __restrict__ We,     // [128]
    unsigned short* __restrict__ hob) // [T][NN][128] bf16 out
{
  const int t = blockIdx.y;
  const unsigned short* qk = qkvb + (size_t)t * NN * QS;
  const int* offs = offs4 + (size_t)t * (NN + 1);
  const int2* cse = cse4 + (size_t)t * EE;
  const int wave = (blockIdx.x * 256 + threadIdx.x) >> 6;   // NN/2 waves per t
  const int lane = threadIdx.x & 63;
  const int half = lane >> 5;
  const int es = (lane >> 3) & 3;      // 4 edge slots
  const int fg = lane & 7;             // 8 feature groups
  const int node = wave * 2 + half;    // exact: NN even, grid exact
  const int f0 = fg * 16;
  const float scale = 0.08838834764831845f;   // 1/sqrt(128)

  float qf[16], wf[16];
  ld16bf(qk + (size_t)node * QS + f0, qf);
#pragma unroll
  for (int j = 0; j < 16; j += 4)
    *(float4*)&wf[j] = *(const float4*)&We[f0 + j];
  float qwe = 0.f;
#pragma unroll
  for (int j = 0; j < 16; ++j) qwe = fmaf(qf[j], wf[j], qwe);
  qwe += __shfl_xor(qwe, 1); qwe += __shfl_xor(qwe, 2); qwe += __shfl_xor(qwe, 4);

  const int e0 = offs[node], e1 = offs[node + 1];
  float l_lane = 0.f, sA_lane = 0.f;
  float acc[16];
#pragma unroll
  for (int i = 0; i < 16; ++i) acc[i] = 0.f;

  for (int base = e0; base < e1; base += 4) {
    const int eidx = base + es;
    const bool valid = eidx < e1;
    int2 se = valid ? cse[eidx] : make_int2(0, 0);
    const int s = se.x;
    const float a = __int_as_float(se.y);
    float kf[16];
    ld16bf(qk + (size_t)s * QS + 128 + f0, kf);
    float p = 0.f;
#pragma unroll
    for (int j = 0; j < 16; ++j) p = fmaf(qf[j], kf[j], p);
    p += __shfl_xor(p, 1); p += __shfl_xor(p, 2); p += __shfl_xor(p, 4);
    const float ex = valid ? __expf((p + a * qwe) * scale) : 0.f;
    l_lane += ex;
    sA_lane = fmaf(ex, a, sA_lane);
    float vf[16];
    ld16bf(qk + (size_t)s * QS + 256 + f0, vf);
#pragma unroll
    for (int j = 0; j < 16; ++j)
      acc[j] = fmaf(ex, vf[j], acc[j]);
  }
  // reductions over the 4 edge-slots (xor 8,16 stay within the 32-lane half)
  l_lane += __shfl_xor(l_lane, 8);  l_lane += __shfl_xor(l_lane, 16);
  sA_lane += __shfl_xor(sA_lane, 8); sA_lane += __shfl_xor(sA_lane, 16);
#pragma unroll
  for (int i = 0; i < 16; ++i) {
    acc[i] += __shfl_xor(acc[i], 8);
    acc[i] += __shfl_xor(acc[i], 16);
  }
  if (es != 0) return;
  const float inv = 1.f / (l_lane + 1e-16f);
  const float sAi = sA_lane * inv;
  float sf[16];
  ld16bf(qk + (size_t)node * QS + 384 + f0, sf);
  unsigned op[8];
#pragma unroll
  for (int j = 0; j < 8; ++j) {
    float oa = fmaf(acc[2 * j], inv, fmaf(sAi, wf[2 * j], sf[2 * j]));
    float ob = fmaf(acc[2 * j + 1], inv, fmaf(sAi, wf[2 * j + 1], sf[2 * j + 1]));
    oa = (oa > 0.f) ? oa : 0.01f * oa;    // leaky_relu
    ob = (ob > 0.f) ? ob : 0.01f * ob;
    op[j] = ((unsigned)f2bf(ob) << 16) | f2bf(oa);
  }
  unsigned short* dst = hob + ((size_t)t * NN + node) * DD + f0;
  *(uint4*)(dst + 0) = make_uint4(op[0], op[1], op[2], op[3]);
  *(uint4*)(dst + 8) = make_uint4(op[4], op[5], op[6], op[7]);
}

// ---------------------------------------------------------------------------
// mean over T from single bf16; 2 elems per thread
// ---------------------------------------------------------------------------
__global__ void mean_k(const unsigned short* __restrict__ hb,
                       float* __restrict__ hm)
{
  int i = blockIdx.x * 256 + threadIdx.x;   // exact NN*DD/2 grid
  float vx = 0.f, vy = 0.f;
#pragma unroll
  for (int t = 0; t < T_STEPS; ++t) {
    unsigned h = *(const unsigned*)&hb[(size_t)t * NN * DD + 2 * i];
    vx += __uint_as_float(h << 16);
    vy += __uint_as_float(h & 0xffff0000u);
  }
  *(float2*)&hm[2 * i] = make_float2(0.25f * vx, 0.25f * vy);
}

// ---------------------------------------------------------------------------
__global__ __launch_bounds__(256) void out_proj(
    const float* __restrict__ h,
    const float* __restrict__ Wq, const float* __restrict__ Wk,
    const float* __restrict__ Wv, const float* __restrict__ Ws,
    const float* __restrict__ bq, const float* __restrict__ bk,
    const float* __restrict__ bv, const float* __restrict__ bs,
    float* __restrict__ q1, float* __restrict__ k1,
    float* __restrict__ v1, float* __restrict__ s1)
{
  const int wv = (blockIdx.x * 256 + threadIdx.x) >> 6;
  const int lane = threadIdx.x & 63;
  if (wv >= NN) return;
  float2 h2 = *(const float2*)&h[(size_t)wv * DD + 2 * lane];
  float pq = h2.x * Wq[2 * lane] + h2.y * Wq[2 * lane + 1];
  float pk = h2.x * Wk[2 * lane] + h2.y * Wk[2 * lane + 1];
  float pv = h2.x * Wv[2 * lane] + h2.y * Wv[2 * lane + 1];
  float ps = h2.x * Ws[2 * lane] + h2.y * Ws[2 * lane + 1];
#pragma unroll
  for (int o = 1; o < 64; o <<= 1) {
    pq += __shfl_xor(pq, o); pk += __shfl_xor(pk, o);
    pv += __shfl_xor(pv, o); ps += __shfl_xor(ps, o);
  }
  if (lane == 0) {
    q1[wv] = pq + bq[0]; k1[wv] = pk + bk[0];
    v1[wv] = pv + bv[0]; s1[wv] = ps + bs[0];
  }
}

__global__ void out_attn(
    const float* __restrict__ q1, const float* __restrict__ k1,
    const float* __restrict__ v1, const float* __restrict__ s1,
    const int* __restrict__ offs, const int2* __restrict__ cse,
    const float* __restrict__ We, float* __restrict__ out)
{
  int n = blockIdx.x * 256 + threadIdx.x;
  if (n >= NN) return;
  const float we = We[0];
  const float q = q1[n];
  const int e0 = offs[n], e1 = offs[n + 1];
  float m = -INFINITY;
  for (int e = e0; e < e1; ++e) {
    int2 se = cse[e];
    float al = q * (k1[se.x] + __int_as_float(se.y) * we);
    m = fmaxf(m, al);
  }
  float l = 0.f, acc = 0.f;
  for (int e = e0; e < e1; ++e) {
    int2 se = cse[e];
    float ca = __int_as_float(se.y);
    float al = q * (k1[se.x] + ca * we);
    float ex = __expf(al - m);
    l += ex;
    acc += ex * (v1[se.x] + ca * we);
  }
  out[n] = acc / (l + 1e-16f) + s1[n];
}

// ---------------------------------------------------------------------------
extern "C" void kernel_launch(void* const* d_in, const int* in_sizes, int n_in,
                              void* d_out, int out_size, void* d_ws, size_t ws_size,
                              hipStream_t stream)
{
  const float* x_seq = (const float*)d_in[0];
  const int*   ei    = (const int*)  d_in[1];
  const float* ea    = (const float*)d_in[2];
  const float* W_ih  = (const float*)d_in[3];
  const float* W_hh  = (const float*)d_in[4];
  const float* b_ih  = (const float*)d_in[5];
  const float* b_hh  = (const float*)d_in[6];
  const float* cWq   = (const float*)d_in[7];
  const float* cbq   = (const float*)d_in[8];
  const float* cWk   = (const float*)d_in[9];
  const float* cbk   = (const float*)d_in[10];
  const float* cWv   = (const float*)d_in[11];
  const float* cbv   = (const float*)d_in[12];
  const float* cWe   = (const float*)d_in[13];
  const float* cWs   = (const float*)d_in[14];
  const float* cbs   = (const float*)d_in[15];
  const float* oWq   = (const float*)d_in[16];
  const float* obq   = (const float*)d_in[17];
  const float* oWk   = (const float*)d_in[18];
  const float* obk   = (const float*)d_in[19];
  const float* oWv   = (const float*)d_in[20];
  const float* obv   = (const float*)d_in[21];
  const float* oWe   = (const float*)d_in[22];
  const float* oWs   = (const float*)d_in[23];
  const float* obs   = (const float*)d_in[24];
  float* out = (float*)d_out;

  char* ws = (char*)d_ws;
  size_t off = 0;
  auto alloc = [&](size_t bytes) -> char* {
    char* p = ws + off;
    off += (bytes + 255) & ~(size_t)255;
    return p;
  };
  // ---- total ~181 MB (<186 MB proven r2; r3's 289 MB aborted) ----
  unsigned short* BihP  = (unsigned short*)alloc((size_t)2 * BIH_PAIRS * 2);
  unsigned short* BhhP  = (unsigned short*)alloc((size_t)2 * BHH_PAIRS * 2);
  unsigned short* WcatP = (unsigned short*)alloc((size_t)2 * WCAT_PAIRS * 2);
  float* fbcat = (float*)alloc((size_t)BCAT_N * 4);
  unsigned short* xhi   = (unsigned short*)alloc((size_t)T_STEPS * NN * IND * 2);
  unsigned short* xlo   = (unsigned short*)alloc((size_t)T_STEPS * NN * IND * 2);
  unsigned short* hallhi = (unsigned short*)alloc((size_t)T_STEPS * NN * DD * 2);
  unsigned short* halllo = (unsigned short*)alloc((size_t)T_STEPS * NN * DD * 2);
  float* fH    = (float*)alloc((size_t)NN * DD * 4);          // h_mean
  int*   iDeg  = (int*)  alloc((size_t)T_STEPS * NN * 4);     // zero-init
  int*   iCur  = (int*)  alloc((size_t)T_STEPS * NN * 4);
  int*   iOffs = (int*)  alloc((size_t)T_STEPS * (NN + 1) * 4);
  int*   iPart = (int*)  alloc((size_t)T_STEPS * NCHUNK * 4);
  int2*  iSE   = (int2*) alloc((size_t)T_STEPS * EE * 8);
  float* fQ1   = (float*)alloc((size_t)NN * 4);
  float* fK1   = (float*)alloc((size_t)NN * 4);
  float* fV1   = (float*)alloc((size_t)NN * 4);
  float* fS1   = (float*)alloc((size_t)NN * 4);
  // union: GRU phase gi2 [2NN*G3 f32] + gh [NN*G3 f32] = 92.2 MB;
  //        conv phase qkvb [4NN*512 bf16] 81.9 MB + hob [4NN*128 bf16] 20.5 MB
  //        (hob overlaps gh region — gh dead after GRU phase)
  size_t uniOff = off;
  float* fGi2  = (float*)(ws + uniOff);
  float* fGh   = (float*)(ws + uniOff + (size_t)2 * NN * G3 * 4);
  unsigned short* qkvb = (unsigned short*)(ws + uniOff);
  unsigned short* hob  = (unsigned short*)(ws + uniOff + (size_t)T_STEPS * NN * QS * 2);
  (void)ws_size; (void)in_sizes; (void)n_in; (void)out_size;

  auto gemm = [&](const unsigned short* Ahi, const unsigned short* Alo,
                  const unsigned short* Bp, const float* bias, float* C,
                  unsigned short* Cb, int M, int N, int K, int obf16) {
    int waves = (M >> 5) * (N >> 7);
    gemm_mfma<<<(waves + 3) / 4, 256, 0, stream>>>(Ahi, Alo, Bp, bias, C, Cb,
                                                   M, N, K, obf16);
  };

  // weights + activation split + CSR
  pack_weights<<<(BIH_PAIRS + BHH_PAIRS + WCAT_PAIRS + BCAT_N + 255) / 256, 256, 0,
                 stream>>>(W_ih, W_hh, cWq, cWk, cWv, cWs, cbq, cbk, cbv, cbs,
                           BihP, BhhP, WcatP, fbcat);
  xsplit<<<(T_STEPS * NN * IND) / 256, 256, 0, stream>>>(x_seq, xhi, xlo);
  hipMemsetAsync(iDeg, 0, (size_t)T_STEPS * NN * 4, stream);
  csr_count<<<(T_STEPS * EE) / 256, 256, 0, stream>>>(ei, iDeg);
  scan1<<<T_STEPS * NCHUNK, 256, 0, stream>>>(iDeg, iPart);
  scan2<<<1, 128, 0, stream>>>(iPart, iOffs);
  scan3<<<T_STEPS * NCHUNK, 256, 0, stream>>>(iDeg, iPart, iOffs, iCur);
  csr_fill<<<(T_STEPS * EE) / 256, 256, 0, stream>>>(ei, ea, iCur, iSE);

  // GRU over time: gi batched in pairs of t, gh sequential (t=0 skipped)
  for (int tp = 0; tp < 2; ++tp) {
    gemm(xhi + (size_t)tp * 2 * NN * IND, xlo + (size_t)tp * 2 * NN * IND,
         BihP, b_ih, fGi2, nullptr, 2 * NN, G3, IND, 0);
    for (int k = 0; k < 2; ++k) {
      const int t = tp * 2 + k;
      const unsigned short* phi = hallhi + (size_t)(t - 1) * NN * DD;  // unused t=0
      const unsigned short* plo = halllo + (size_t)(t - 1) * NN * DD;
      if (t > 0) gemm(phi, plo, BhhP, b_hh, fGh, nullptr, NN, G3, DD, 0);
      gru_gate<<<(NN * DD) / 256, 256, 0, stream>>>(
          fGi2 + (size_t)k * NN * G3, fGh, b_hh, (t == 0) ? 1 : 0,
          (t == 0) ? hallhi : phi, (t == 0) ? halllo : plo,
          hallhi + (size_t)t * NN * DD, halllo + (size_t)t * NN * DD);
    }
  }

  // Layer 1: hi/lo A (GRU out) -> qkvb ; attn -> hob (bf16)
  gemm(hallhi, halllo, WcatP, fbcat, nullptr, qkvb, T_STEPS * NN, QS, DD, 1);
  {
    dim3 ag((NN / 2 * 64) / 256, T_STEPS);
    attn_conv<<<ag, 256, 0, stream>>>(qkvb, iOffs, iSE, cWe, hob);
  }
  // Layer 2: single-bf16 A (hob) -> qkvb (2-MFMA) ; attn -> hob (overwrite)
  {
    int waves = ((T_STEPS * NN) >> 5) * (QS >> 7);
    gemm_mfma_b1<<<(waves + 3) / 4, 256, 0, stream>>>(
        hob, WcatP + (size_t)131072, fbcat + QS, qkvb, T_STEPS * NN, QS, DD);
    dim3 ag((NN / 2 * 64) / 256, T_STEPS);
    attn_conv<<<ag, 256, 0, stream>>>(qkvb, iOffs, iSE, cWe + DD, hob);
  }

  // mean over T (bf16 -> fp32)
  mean_k<<<(NN * DD / 2) / 256, 256, 0, stream>>>(hob, fH);

  // output conv (d=1) on t=3 graph
  out_proj<<<(NN * 64) / 256, 256, 0, stream>>>(
      fH, oWq, oWk, oWv, oWs, obq, obk, obv, obs, fQ1, fK1, fV1, fS1);
  out_attn<<<(NN + 255) / 256, 256, 0, stream>>>(
      fQ1, fK1, fV1, fS1, iOffs + 3 * (NN + 1), iSE + (size_t)3 * EE, oWe, out);
}

// Round 9
// 547.337 us; speedup vs baseline: 1.7206x; 1.0274x over previous
//
#include <hip/hip_runtime.h>
#include <math.h>

#define T_STEPS 4
#define NN 20000
#define EE 160000
#define IND 64
#define DD 128
#define G3 384     // 3*D (GRU gates)
#define QS 512     // q|k|v|skip fused width

typedef __bf16 bf16x8 __attribute__((ext_vector_type(8)));
typedef float floatx4 __attribute__((ext_vector_type(4)));

// ---------------------------------------------------------------------------
// fp32 -> bf16 split (RNE): x ~= hi + lo, |x-(hi+lo)| <~ 2^-18 |x|
// ---------------------------------------------------------------------------
__device__ inline unsigned short f2bf(float x) {
  unsigned u = __float_as_uint(x);
  unsigned r = (u + 0x7fffu + ((u >> 16) & 1u)) >> 16;
  return (unsigned short)r;
}
__device__ inline float bf2f(unsigned short h) {
  return __uint_as_float((unsigned)h << 16);
}
__device__ inline void bfsplit(float x, unsigned short& hi, unsigned short& lo) {
  hi = f2bf(x);
  lo = f2bf(x - bf2f(hi));
}
// load 16 consecutive bf16 -> fp32 (32B, two dwordx4)
__device__ inline void ld16bf(const unsigned short* p, float* f) {
  const uint4 u0 = *(const uint4*)p;
  const uint4 u1 = *(const uint4*)(p + 8);
  f[0] = __uint_as_float(u0.x << 16);  f[1] = __uint_as_float(u0.x & 0xffff0000u);
  f[2] = __uint_as_float(u0.y << 16);  f[3] = __uint_as_float(u0.y & 0xffff0000u);
  f[4] = __uint_as_float(u0.z << 16);  f[5] = __uint_as_float(u0.z & 0xffff0000u);
  f[6] = __uint_as_float(u0.w << 16);  f[7] = __uint_as_float(u0.w & 0xffff0000u);
  f[8]  = __uint_as_float(u1.x << 16); f[9]  = __uint_as_float(u1.x & 0xffff0000u);
  f[10] = __uint_as_float(u1.y << 16); f[11] = __uint_as_float(u1.y & 0xffff0000u);
  f[12] = __uint_as_float(u1.z << 16); f[13] = __uint_as_float(u1.z & 0xffff0000u);
  f[14] = __uint_as_float(u1.w << 16); f[15] = __uint_as_float(u1.w & 0xffff0000u);
}

// ---------------------------------------------------------------------------
// Split-bf16 MFMA GEMM with LDS-staged B. Block = 512 threads (8 waves), all
// sharing one 128-col group (ng); B for that ng (contiguous 16KB*ktiles in
// pack layout, <=64KB) is block-staged to LDS once, then each wave computes a
// 32-row x 128-col tile reading B via ds_read_b128 (kills the per-wave L2
// latency serialization seen in r8: 64 µs @ MfmaUtil 19%).
// obf16=0 -> fp32 C ; obf16=1 -> bf16 Cb.
// ---------------------------------------------------------------------------
__global__ __launch_bounds__(512) void gemm_mfma(
    const unsigned short* __restrict__ Ahi, const unsigned short* __restrict__ Alo,
    const unsigned short* __restrict__ Bp, const float* __restrict__ bias,
    float* __restrict__ C, unsigned short* __restrict__ Cb,
    int M, int N, int K, int obf16)
{
  __shared__ unsigned short Bs[32768];   // 64 KB (max ktiles=4)
  const int ngroups = N >> 7;
  const int mtiles = M >> 5;
  const int ng = blockIdx.x % ngroups;
  const int mb = blockIdx.x / ngroups;
  const int ktiles = K >> 5;
  const int tid = threadIdx.x;
  // stage B for this ng (contiguous region in pack layout)
  const unsigned short* Bsrc = Bp + (size_t)ng * 8 * ktiles * 1024;
  const int nchunk = ktiles * 8 * 128;   // 16B chunks
  for (int i = tid; i < nchunk; i += 512)
    *(uint4*)&Bs[i * 8] = *(const uint4*)&Bsrc[i * 8];
  __syncthreads();
  const int w = tid >> 6;
  const int lane = tid & 63;
  const int mw = mb * 8 + w;
  if (mw >= mtiles) return;
  const int r = lane & 15, quad = lane >> 4;
  const unsigned short* a0h = Ahi + (size_t)(mw * 32 + r) * K + quad * 8;
  const unsigned short* a0l = Alo + (size_t)(mw * 32 + r) * K + quad * 8;
  const unsigned short* a1h = a0h + (size_t)16 * K;
  const unsigned short* a1l = a0l + (size_t)16 * K;
  floatx4 acc[2][8];
#pragma unroll
  for (int m = 0; m < 2; ++m)
#pragma unroll
    for (int nt = 0; nt < 8; ++nt) acc[m][nt] = (floatx4){0.f, 0.f, 0.f, 0.f};
  for (int kt = 0; kt < ktiles; ++kt) {
    bf16x8 a0hi = *(const bf16x8*)(a0h + kt * 32);
    bf16x8 a0lo = *(const bf16x8*)(a0l + kt * 32);
    bf16x8 a1hi = *(const bf16x8*)(a1h + kt * 32);
    bf16x8 a1lo = *(const bf16x8*)(a1l + kt * 32);
#pragma unroll
    for (int nt = 0; nt < 8; ++nt) {
      const unsigned short* bp = Bs + (nt * ktiles + kt) * 1024 + lane * 8;
      bf16x8 bhi = *(const bf16x8*)bp;
      bf16x8 blo = *(const bf16x8*)(bp + 512);
      acc[0][nt] = __builtin_amdgcn_mfma_f32_16x16x32_bf16(a0hi, bhi, acc[0][nt], 0, 0, 0);
      acc[0][nt] = __builtin_amdgcn_mfma_f32_16x16x32_bf16(a0hi, blo, acc[0][nt], 0, 0, 0);
      acc[0][nt] = __builtin_amdgcn_mfma_f32_16x16x32_bf16(a0lo, bhi, acc[0][nt], 0, 0, 0);
      acc[1][nt] = __builtin_amdgcn_mfma_f32_16x16x32_bf16(a1hi, bhi, acc[1][nt], 0, 0, 0);
      acc[1][nt] = __builtin_amdgcn_mfma_f32_16x16x32_bf16(a1hi, blo, acc[1][nt], 0, 0, 0);
      acc[1][nt] = __builtin_amdgcn_mfma_f32_16x16x32_bf16(a1lo, bhi, acc[1][nt], 0, 0, 0);
    }
  }
#pragma unroll
  for (int m = 0; m < 2; ++m) {
    const int crow0 = mw * 32 + m * 16 + quad * 4;
#pragma unroll
    for (int nt = 0; nt < 8; ++nt) {
      const int col = ng * 128 + nt * 16 + r;
      const float b = bias[col];
      if (obf16) {
#pragma unroll
        for (int i = 0; i < 4; ++i)
          Cb[(size_t)(crow0 + i) * N + col] = f2bf(acc[m][nt][i] + b);
      } else {
#pragma unroll
        for (int i = 0; i < 4; ++i)
          C[(size_t)(crow0 + i) * N + col] = acc[m][nt][i] + b;
      }
    }
  }
}

// ---------------------------------------------------------------------------
// Single-bf16-A MFMA GEMM, LDS-staged B (2 MFMA/tile). bf16 out.
// ---------------------------------------------------------------------------
__global__ __launch_bounds__(512) void gemm_mfma_b1(
    const unsigned short* __restrict__ A,
    const unsigned short* __restrict__ Bp, const float* __restrict__ bias,
    unsigned short* __restrict__ Cb, int M, int N, int K)
{
  __shared__ unsigned short Bs[32768];
  const int ngroups = N >> 7;
  const int mtiles = M >> 5;
  const int ng = blockIdx.x % ngroups;
  const int mb = blockIdx.x / ngroups;
  const int ktiles = K >> 5;
  const int tid = threadIdx.x;
  const unsigned short* Bsrc = Bp + (size_t)ng * 8 * ktiles * 1024;
  const int nchunk = ktiles * 8 * 128;
  for (int i = tid; i < nchunk; i += 512)
    *(uint4*)&Bs[i * 8] = *(const uint4*)&Bsrc[i * 8];
  __syncthreads();
  const int w = tid >> 6;
  const int lane = tid & 63;
  const int mw = mb * 8 + w;
  if (mw >= mtiles) return;
  const int r = lane & 15, quad = lane >> 4;
  const unsigned short* a0 = A + (size_t)(mw * 32 + r) * K + quad * 8;
  const unsigned short* a1 = a0 + (size_t)16 * K;
  floatx4 acc[2][8];
#pragma unroll
  for (int m = 0; m < 2; ++m)
#pragma unroll
    for (int nt = 0; nt < 8; ++nt) acc[m][nt] = (floatx4){0.f, 0.f, 0.f, 0.f};
  for (int kt = 0; kt < ktiles; ++kt) {
    bf16x8 af0 = *(const bf16x8*)(a0 + kt * 32);
    bf16x8 af1 = *(const bf16x8*)(a1 + kt * 32);
#pragma unroll
    for (int nt = 0; nt < 8; ++nt) {
      const unsigned short* bp = Bs + (nt * ktiles + kt) * 1024 + lane * 8;
      bf16x8 bhi = *(const bf16x8*)bp;
      bf16x8 blo = *(const bf16x8*)(bp + 512);
      acc[0][nt] = __builtin_amdgcn_mfma_f32_16x16x32_bf16(af0, bhi, acc[0][nt], 0, 0, 0);
      acc[0][nt] = __builtin_amdgcn_mfma_f32_16x16x32_bf16(af0, blo, acc[0][nt], 0, 0, 0);
      acc[1][nt] = __builtin_amdgcn_mfma_f32_16x16x32_bf16(af1, bhi, acc[1][nt], 0, 0, 0);
      acc[1][nt] = __builtin_amdgcn_mfma_f32_16x16x32_bf16(af1, blo, acc[1][nt], 0, 0, 0);
    }
  }
#pragma unroll
  for (int m = 0; m < 2; ++m) {
    const int crow0 = mw * 32 + m * 16 + quad * 4;
#pragma unroll
    for (int nt = 0; nt < 8; ++nt) {
      const int col = ng * 128 + nt * 16 + r;
      const float b = bias[col];
#pragma unroll
      for (int i = 0; i < 4; ++i)
        Cb[(size_t)(crow0 + i) * N + col] = f2bf(acc[m][nt][i] + b);
    }
  }
}

// ---------------------------------------------------------------------------
// Weight packing into MFMA fragment order (hi/lo split) + fused conv bias
// ---------------------------------------------------------------------------
#define BIH_PAIRS 24576    // (384/16)*(64/32)*512
#define BHH_PAIRS 49152    // 24*4*512
#define WCAT_PAIRS 131072  // 2*32*4*512
#define BCAT_N 1024

__global__ void pack_weights(
    const float* __restrict__ Wih, const float* __restrict__ Whh,
    const float* __restrict__ Wq, const float* __restrict__ Wk,
    const float* __restrict__ Wv, const float* __restrict__ Ws,
    const float* __restrict__ bq, const float* __restrict__ bk,
    const float* __restrict__ bv, const float* __restrict__ bs,
    unsigned short* __restrict__ BihP, unsigned short* __restrict__ BhhP,
    unsigned short* __restrict__ WcatP, float* __restrict__ bcat)
{
  int gid = blockIdx.x * 256 + threadIdx.x;
  if (gid < BIH_PAIRS) {  // K=64, N=384, ktiles=2
    int tile = gid >> 9, lj = gid & 511, lane = lj >> 3, j = lj & 7;
    int k_tile = tile & 1, n_tile = tile >> 1;
    int n = n_tile * 16 + (lane & 15);
    int k = k_tile * 32 + (lane >> 4) * 8 + j;
    unsigned short hi, lo;
    bfsplit(Wih[n * IND + k], hi, lo);   // B[k][n] = Wih^T
    BihP[tile * 1024 + lane * 8 + j] = hi;
    BihP[tile * 1024 + 512 + lane * 8 + j] = lo;
    return;
  }
  gid -= BIH_PAIRS;
  if (gid < BHH_PAIRS) {  // K=128, N=384, ktiles=4
    int tile = gid >> 9, lj = gid & 511, lane = lj >> 3, j = lj & 7;
    int k_tile = tile & 3, n_tile = tile >> 2;
    int n = n_tile * 16 + (lane & 15);
    int k = k_tile * 32 + (lane >> 4) * 8 + j;
    unsigned short hi, lo;
    bfsplit(Whh[n * DD + k], hi, lo);
    BhhP[tile * 1024 + lane * 8 + j] = hi;
    BhhP[tile * 1024 + 512 + lane * 8 + j] = lo;
    return;
  }
  gid -= BHH_PAIRS;
  if (gid < WCAT_PAIRS) {  // per layer: K=128, N=512, ktiles=4
    int l = gid >> 16, rem = gid & 65535;
    int tile = rem >> 9, lj = rem & 511, lane = lj >> 3, j = lj & 7;
    int k_tile = tile & 3, n_tile = tile >> 2;
    int n = n_tile * 16 + (lane & 15);
    int k = k_tile * 32 + (lane >> 4) * 8 + j;
    const float* W = (n < 128) ? Wq : (n < 256) ? Wk : (n < 384) ? Wv : Ws;
    unsigned short hi, lo;
    bfsplit(W[l * DD * DD + k * DD + (n & 127)], hi, lo);
    size_t base = (size_t)l * 131072 + tile * 1024;
    WcatP[base + lane * 8 + j] = hi;
    WcatP[base + 512 + lane * 8 + j] = lo;
    return;
  }
  gid -= WCAT_PAIRS;
  if (gid < BCAT_N) {
    int l = gid >> 9, n = gid & 511;
    const float* b = (n < 128) ? bq : (n < 256) ? bk : (n < 384) ? bv : bs;
    bcat[gid] = b[l * DD + (n & 127)];
  }
}

// ---------------------------------------------------------------------------
__global__ void xsplit(const float* __restrict__ x,
                       unsigned short* __restrict__ xhi,
                       unsigned short* __restrict__ xlo)
{
  int i = blockIdx.x * 256 + threadIdx.x;   // exact T*NN*IND grid
  unsigned short hi, lo;
  bfsplit(x[i], hi, lo);
  xhi[i] = hi; xlo[i] = lo;
}

// ---------------------------------------------------------------------------
// CSR build (by destination), per timestep; parallel 3-phase scan
// ---------------------------------------------------------------------------
#define SCHUNK 1024
#define NCHUNK 20          // ceil(20000/1024)

__global__ void csr_count(const int* __restrict__ ei, int* __restrict__ deg)
{
  int gid = blockIdx.x * 256 + threadIdx.x;
  if (gid >= T_STEPS * EE) return;
  int t = gid / EE, e = gid % EE;
  int dst = ei[(size_t)t * 2 * EE + EE + e];
  atomicAdd(&deg[t * NN + dst], 1);
}

__global__ void scan1(const int* __restrict__ deg, int* __restrict__ part)
{
  const int b = blockIdx.x;              // 0..T*NCHUNK-1
  const int t = b / NCHUNK, c = b % NCHUNK;
  const int tid = threadIdx.x;
  __shared__ int s[256];
  int base = c * SCHUNK + tid * 4;
  int sum = 0;
#pragma unroll
  for (int u = 0; u < 4; ++u) {
    int i = base + u;
    if (i < NN) sum += deg[t * NN + i];
  }
  s[tid] = sum;
  __syncthreads();
  for (int o = 128; o > 0; o >>= 1) {
    if (tid < o) s[tid] += s[tid + o];
    __syncthreads();
  }
  if (tid == 0) part[b] = s[0];
}

__global__ void scan2(int* __restrict__ part, int* __restrict__ offs)
{
  const int tid = threadIdx.x;
  __shared__ int s[T_STEPS * NCHUNK];
  if (tid < T_STEPS * NCHUNK) s[tid] = part[tid];
  __syncthreads();
  if (tid == 0) {
    for (int t = 0; t < T_STEPS; ++t) {
      int run = 0;
      for (int c = 0; c < NCHUNK; ++c) {
        int v = s[t * NCHUNK + c];
        s[t * NCHUNK + c] = run;
        run += v;
      }
      offs[t * (NN + 1) + NN] = run;
    }
  }
  __syncthreads();
  if (tid < T_STEPS * NCHUNK) part[tid] = s[tid];
}

__global__ void scan3(const int* __restrict__ deg, const int* __restrict__ part,
                      int* __restrict__ offs, int* __restrict__ cur)
{
  const int b = blockIdx.x;
  const int t = b / NCHUNK, c = b % NCHUNK;
  const int tid = threadIdx.x;
  __shared__ int s[256];
  int base = c * SCHUNK + tid * 4;
  int v[4]; int sum = 0;
#pragma unroll
  for (int u = 0; u < 4; ++u) {
    int i = base + u;
    v[u] = (i < NN) ? deg[t * NN + i] : 0;
    sum += v[u];
  }
  s[tid] = sum;
  __syncthreads();
  for (int o = 1; o < 256; o <<= 1) {
    int x = (tid >= o) ? s[tid - o] : 0;
    __syncthreads();
    s[tid] += x;
    __syncthreads();
  }
  int excl = part[b] + s[tid] - sum;
#pragma unroll
  for (int u = 0; u < 4; ++u) {
    int i = base + u;
    if (i < NN) {
      offs[t * (NN + 1) + i] = excl;
      cur[t * NN + i] = excl;
    }
    excl += v[u];
  }
}

// packed CSR entry: .x = src node, .y = edge_attr bits (one 8B store per edge)
__global__ void csr_fill(const int* __restrict__ ei, const float* __restrict__ ea,
                         int* __restrict__ cur, int2* __restrict__ cse)
{
  int gid = blockIdx.x * 256 + threadIdx.x;
  if (gid >= T_STEPS * EE) return;
  int t = gid / EE, e = gid % EE;
  int src = ei[(size_t)t * 2 * EE + e];
  int dst = ei[(size_t)t * 2 * EE + EE + e];
  int slot = atomicAdd(&cur[t * NN + dst], 1);
  cse[(size_t)t * EE + slot] = make_int2(src, __float_as_int(ea[(size_t)t * EE + e]));
}

// ---------------------------------------------------------------------------
// GRU gate fusion. t0: gh == b_hh exactly (h0=0), h_prev=0.
// ---------------------------------------------------------------------------
__global__ __launch_bounds__(256) void gru_gate(
    const float* __restrict__ gi, const float* __restrict__ gh,
    const float* __restrict__ b_hh, int t0,
    const unsigned short* __restrict__ phi, const unsigned short* __restrict__ plo,
    unsigned short* __restrict__ hhi_t, unsigned short* __restrict__ hlo_t)
{
  int idx = blockIdx.x * 256 + threadIdx.x;   // exact NN*DD grid
  int n = idx >> 7, d = idx & 127;
  size_t gb = (size_t)n * G3 + d;
  float ir = gi[gb], iz = gi[gb + DD], inn = gi[gb + 2 * DD];
  float hr, hz, hn, hp;
  if (t0) {
    hr = b_hh[d]; hz = b_hh[DD + d]; hn = b_hh[2 * DD + d]; hp = 0.f;
  } else {
    hr = gh[gb]; hz = gh[gb + DD]; hn = gh[gb + 2 * DD];
    hp = bf2f(phi[idx]) + bf2f(plo[idx]);
  }
  float r = 1.f / (1.f + __expf(-(ir + hr)));
  float z = 1.f / (1.f + __expf(-(iz + hz)));
  float nv = tanhf(inn + r * hn);
  float hnew = (1.f - z) * nv + z * hp;
  unsigned short hi, lo;
  bfsplit(hnew, hi, lo);
  hhi_t[idx] = hi; hlo_t[idx] = lo;
}

// ---------------------------------------------------------------------------
// Fused TransformerConv (d=128), all T via blockIdx.y. qkvb bf16 [T][NN][512].
// TWO nodes per wave: lane = half(1b) | es(2b) | fg(3b); per node 4 edge-slots
// x 8 feature-groups (16 floats each). No-max softmax + factored edge feature
// (r7-verified). Output: single bf16 [T][NN][128] (feeds gemm_mfma_b1 + mean).
// ---------------------------------------------------------------------------
__global__ __launch_bounds__(256) void attn_conv(
    const unsigned short* __restrict__ qkvb,  // [T][NN][512] bf16
    const int* __restrict__ offs4,    // [T][NN+1]
    const int2* __restrict__ cse4,    // [T][E]
    const float* __restrict__ We,     // [128]
    unsigned short* __restrict__ hob) // [T][NN][128] bf16 out
{
  const int t = blockIdx.y;
  const unsigned short* qk = qkvb + (size_t)t * NN * QS;
  const int* offs = offs4 + (size_t)t * (NN + 1);
  const int2* cse = cse4 + (size_t)t * EE;
  const int wave = (blockIdx.x * 256 + threadIdx.x) >> 6;   // NN/2 waves per t
  const int lane = threadIdx.x & 63;
  const int half = lane >> 5;
  const int es = (lane >> 3) & 3;      // 4 edge slots
  const int fg = lane & 7;             // 8 feature groups
  const int node = wave * 2 + half;    // exact: NN even, grid exact
  const int f0 = fg * 16;
  const float scale = 0.08838834764831845f;   // 1/sqrt(128)

  float qf[16], wf[16];
  ld16bf(qk + (size_t)node * QS + f0, qf);
#pragma unroll
  for (int j = 0; j < 16; j += 4)
    *(float4*)&wf[j] = *(const float4*)&We[f0 + j];
  float qwe = 0.f;
#pragma unroll
  for (int j = 0; j < 16; ++j) qwe = fmaf(qf[j], wf[j], qwe);
  qwe += __shfl_xor(qwe, 1); qwe += __shfl_xor(qwe, 2); qwe += __shfl_xor(qwe, 4);

  const int e0 = offs[node], e1 = offs[node + 1];
  float l_lane = 0.f, sA_lane = 0.f;
  float acc[16];
#pragma unroll
  for (int i = 0; i < 16; ++i) acc[i] = 0.f;

  for (int base = e0; base < e1; base += 4) {
    const int eidx = base + es;
    const bool valid = eidx < e1;
    int2 se = valid ? cse[eidx] : make_int2(0, 0);
    const int s = se.x;
    const float a = __int_as_float(se.y);
    float kf[16];
    ld16bf(qk + (size_t)s * QS + 128 + f0, kf);
    float p = 0.f;
#pragma unroll
    for (int j = 0; j < 16; ++j) p = fmaf(qf[j], kf[j], p);
    p += __shfl_xor(p, 1); p += __shfl_xor(p, 2); p += __shfl_xor(p, 4);
    const float ex = valid ? __expf((p + a * qwe) * scale) : 0.f;
    l_lane += ex;
    sA_lane = fmaf(ex, a, sA_lane);
    float vf[16];
    ld16bf(qk + (size_t)s * QS + 256 + f0, vf);
#pragma unroll
    for (int j = 0; j < 16; ++j)
      acc[j] = fmaf(ex, vf[j], acc[j]);
  }
  // reductions over the 4 edge-slots (xor 8,16 stay within the 32-lane half)
  l_lane += __shfl_xor(l_lane, 8);  l_lane += __shfl_xor(l_lane, 16);
  sA_lane += __shfl_xor(sA_lane, 8); sA_lane += __shfl_xor(sA_lane, 16);
#pragma unroll
  for (int i = 0; i < 16; ++i) {
    acc[i] += __shfl_xor(acc[i], 8);
    acc[i] += __shfl_xor(acc[i], 16);
  }
  if (es != 0) return;
  const float inv = 1.f / (l_lane + 1e-16f);
  const float sAi = sA_lane * inv;
  float sf[16];
  ld16bf(qk + (size_t)node * QS + 384 + f0, sf);
  unsigned op[8];
#pragma unroll
  for (int j = 0; j < 8; ++j) {
    float oa = fmaf(acc[2 * j], inv, fmaf(sAi, wf[2 * j], sf[2 * j]));
    float ob = fmaf(acc[2 * j + 1], inv, fmaf(sAi, wf[2 * j + 1], sf[2 * j + 1]));
    oa = (oa > 0.f) ? oa : 0.01f * oa;    // leaky_relu
    ob = (ob > 0.f) ? ob : 0.01f * ob;
    op[j] = ((unsigned)f2bf(ob) << 16) | f2bf(oa);
  }
  unsigned short* dst = hob + ((size_t)t * NN + node) * DD + f0;
  *(uint4*)(dst + 0) = make_uint4(op[0], op[1], op[2], op[3]);
  *(uint4*)(dst + 8) = make_uint4(op[4], op[5], op[6], op[7]);
}

// ---------------------------------------------------------------------------
// mean over T from single bf16; 2 elems per thread
// ---------------------------------------------------------------------------
__global__ void mean_k(const unsigned short* __restrict__ hb,
                       float* __restrict__ hm)
{
  int i = blockIdx.x * 256 + threadIdx.x;   // exact NN*DD/2 grid
  float vx = 0.f, vy = 0.f;
#pragma unroll
  for (int t = 0; t < T_STEPS; ++t) {
    unsigned h = *(const unsigned*)&hb[(size_t)t * NN * DD + 2 * i];
    vx += __uint_as_float(h << 16);
    vy += __uint_as_float(h & 0xffff0000u);
  }
  *(float2*)&hm[2 * i] = make_float2(0.25f * vx, 0.25f * vy);
}

// ---------------------------------------------------------------------------
__global__ __launch_bounds__(256) void out_proj(
    const float* __restrict__ h,
    const float* __restrict__ Wq, const float* __restrict__ Wk,
    const float* __restrict__ Wv, const float* __restrict__ Ws,
    const float* __restrict__ bq, const float* __restrict__ bk,
    const float* __restrict__ bv, const float* __restrict__ bs,
    float* __restrict__ q1, float* __restrict__ k1,
    float* __restrict__ v1, float* __restrict__ s1)
{
  const int wv = (blockIdx.x * 256 + threadIdx.x) >> 6;
  const int lane = threadIdx.x & 63;
  if (wv >= NN) return;
  float2 h2 = *(const float2*)&h[(size_t)wv * DD + 2 * lane];
  float pq = h2.x * Wq[2 * lane] + h2.y * Wq[2 * lane + 1];
  float pk = h2.x * Wk[2 * lane] + h2.y * Wk[2 * lane + 1];
  float pv = h2.x * Wv[2 * lane] + h2.y * Wv[2 * lane + 1];
  float ps = h2.x * Ws[2 * lane] + h2.y * Ws[2 * lane + 1];
#pragma unroll
  for (int o = 1; o < 64; o <<= 1) {
    pq += __shfl_xor(pq, o); pk += __shfl_xor(pk, o);
    pv += __shfl_xor(pv, o); ps += __shfl_xor(ps, o);
  }
  if (lane == 0) {
    q1[wv] = pq + bq[0]; k1[wv] = pk + bk[0];
    v1[wv] = pv + bv[0]; s1[wv] = ps + bs[0];
  }
}

__global__ void out_attn(
    const float* __restrict__ q1, const float* __restrict__ k1,
    const float* __restrict__ v1, const float* __restrict__ s1,
    const int* __restrict__ offs, const int2* __restrict__ cse,
    const float* __restrict__ We, float* __restrict__ out)
{
  int n = blockIdx.x * 256 + threadIdx.x;
  if (n >= NN) return;
  const float we = We[0];
  const float q = q1[n];
  const int e0 = offs[n], e1 = offs[n + 1];
  float m = -INFINITY;
  for (int e = e0; e < e1; ++e) {
    int2 se = cse[e];
    float al = q * (k1[se.x] + __int_as_float(se.y) * we);
    m = fmaxf(m, al);
  }
  float l = 0.f, acc = 0.f;
  for (int e = e0; e < e1; ++e) {
    int2 se = cse[e];
    float ca = __int_as_float(se.y);
    float al = q * (k1[se.x] + ca * we);
    float ex = __expf(al - m);
    l += ex;
    acc += ex * (v1[se.x] + ca * we);
  }
  out[n] = acc / (l + 1e-16f) + s1[n];
}

// ---------------------------------------------------------------------------
extern "C" void kernel_launch(void* const* d_in, const int* in_sizes, int n_in,
                              void* d_out, int out_size, void* d_ws, size_t ws_size,
                              hipStream_t stream)
{
  const float* x_seq = (const float*)d_in[0];
  const int*   ei    = (const int*)  d_in[1];
  const float* ea    = (const float*)d_in[2];
  const float* W_ih  = (const float*)d_in[3];
  const float* W_hh  = (const float*)d_in[4];
  const float* b_ih  = (const float*)d_in[5];
  const float* b_hh  = (const float*)d_in[6];
  const float* cWq   = (const float*)d_in[7];
  const float* cbq   = (const float*)d_in[8];
  const float* cWk   = (const float*)d_in[9];
  const float* cbk   = (const float*)d_in[10];
  const float* cWv   = (const float*)d_in[11];
  const float* cbv   = (const float*)d_in[12];
  const float* cWe   = (const float*)d_in[13];
  const float* cWs   = (const float*)d_in[14];
  const float* cbs   = (const float*)d_in[15];
  const float* oWq   = (const float*)d_in[16];
  const float* obq   = (const float*)d_in[17];
  const float* oWk   = (const float*)d_in[18];
  const float* obk   = (const float*)d_in[19];
  const float* oWv   = (const float*)d_in[20];
  const float* obv   = (const float*)d_in[21];
  const float* oWe   = (const float*)d_in[22];
  const float* oWs   = (const float*)d_in[23];
  const float* obs   = (const float*)d_in[24];
  float* out = (float*)d_out;

  char* ws = (char*)d_ws;
  size_t off = 0;
  auto alloc = [&](size_t bytes) -> char* {
    char* p = ws + off;
    off += (bytes + 255) & ~(size_t)255;
    return p;
  };
  // ---- total ~181 MB (<186 MB proven r2; r3's 289 MB aborted) ----
  unsigned short* BihP  = (unsigned short*)alloc((size_t)2 * BIH_PAIRS * 2);
  unsigned short* BhhP  = (unsigned short*)alloc((size_t)2 * BHH_PAIRS * 2);
  unsigned short* WcatP = (unsigned short*)alloc((size_t)2 * WCAT_PAIRS * 2);
  float* fbcat = (float*)alloc((size_t)BCAT_N * 4);
  unsigned short* xhi   = (unsigned short*)alloc((size_t)T_STEPS * NN * IND * 2);
  unsigned short* xlo   = (unsigned short*)alloc((size_t)T_STEPS * NN * IND * 2);
  unsigned short* hallhi = (unsigned short*)alloc((size_t)T_STEPS * NN * DD * 2);
  unsigned short* halllo = (unsigned short*)alloc((size_t)T_STEPS * NN * DD * 2);
  float* fH    = (float*)alloc((size_t)NN * DD * 4);          // h_mean
  int*   iDeg  = (int*)  alloc((size_t)T_STEPS * NN * 4);     // zero-init
  int*   iCur  = (int*)  alloc((size_t)T_STEPS * NN * 4);
  int*   iOffs = (int*)  alloc((size_t)T_STEPS * (NN + 1) * 4);
  int*   iPart = (int*)  alloc((size_t)T_STEPS * NCHUNK * 4);
  int2*  iSE   = (int2*) alloc((size_t)T_STEPS * EE * 8);
  float* fQ1   = (float*)alloc((size_t)NN * 4);
  float* fK1   = (float*)alloc((size_t)NN * 4);
  float* fV1   = (float*)alloc((size_t)NN * 4);
  float* fS1   = (float*)alloc((size_t)NN * 4);
  // union: GRU phase gi2 [2NN*G3 f32] + gh [NN*G3 f32] = 92.2 MB;
  //        conv phase qkvb [4NN*512 bf16] 81.9 MB + hob [4NN*128 bf16] 20.5 MB
  size_t uniOff = off;
  float* fGi2  = (float*)(ws + uniOff);
  float* fGh   = (float*)(ws + uniOff + (size_t)2 * NN * G3 * 4);
  unsigned short* qkvb = (unsigned short*)(ws + uniOff);
  unsigned short* hob  = (unsigned short*)(ws + uniOff + (size_t)T_STEPS * NN * QS * 2);
  (void)ws_size; (void)in_sizes; (void)n_in; (void)out_size;

  auto gemm = [&](const unsigned short* Ahi, const unsigned short* Alo,
                  const unsigned short* Bp, const float* bias, float* C,
                  unsigned short* Cb, int M, int N, int K, int obf16) {
    int blocks = (((M >> 5) + 7) >> 3) * (N >> 7);
    gemm_mfma<<<blocks, 512, 0, stream>>>(Ahi, Alo, Bp, bias, C, Cb,
                                          M, N, K, obf16);
  };

  // weights + activation split + CSR
  pack_weights<<<(BIH_PAIRS + BHH_PAIRS + WCAT_PAIRS + BCAT_N + 255) / 256, 256, 0,
                 stream>>>(W_ih, W_hh, cWq, cWk, cWv, cWs, cbq, cbk, cbv, cbs,
                           BihP, BhhP, WcatP, fbcat);
  xsplit<<<(T_STEPS * NN * IND) / 256, 256, 0, stream>>>(x_seq, xhi, xlo);
  hipMemsetAsync(iDeg, 0, (size_t)T_STEPS * NN * 4, stream);
  csr_count<<<(T_STEPS * EE) / 256, 256, 0, stream>>>(ei, iDeg);
  scan1<<<T_STEPS * NCHUNK, 256, 0, stream>>>(iDeg, iPart);
  scan2<<<1, 128, 0, stream>>>(iPart, iOffs);
  scan3<<<T_STEPS * NCHUNK, 256, 0, stream>>>(iDeg, iPart, iOffs, iCur);
  csr_fill<<<(T_STEPS * EE) / 256, 256, 0, stream>>>(ei, ea, iCur, iSE);

  // GRU over time: gi batched in pairs of t, gh sequential (t=0 skipped)
  for (int tp = 0; tp < 2; ++tp) {
    gemm(xhi + (size_t)tp * 2 * NN * IND, xlo + (size_t)tp * 2 * NN * IND,
         BihP, b_ih, fGi2, nullptr, 2 * NN, G3, IND, 0);
    for (int k = 0; k < 2; ++k) {
      const int t = tp * 2 + k;
      const unsigned short* phi = hallhi + (size_t)(t - 1) * NN * DD;  // unused t=0
      const unsigned short* plo = halllo + (size_t)(t - 1) * NN * DD;
      if (t > 0) gemm(phi, plo, BhhP, b_hh, fGh, nullptr, NN, G3, DD, 0);
      gru_gate<<<(NN * DD) / 256, 256, 0, stream>>>(
          fGi2 + (size_t)k * NN * G3, fGh, b_hh, (t == 0) ? 1 : 0,
          (t == 0) ? hallhi : phi, (t == 0) ? halllo : plo,
          hallhi + (size_t)t * NN * DD, halllo + (size_t)t * NN * DD);
    }
  }

  // Layer 1: hi/lo A (GRU out) -> qkvb ; attn -> hob (bf16)
  gemm(hallhi, halllo, WcatP, fbcat, nullptr, qkvb, T_STEPS * NN, QS, DD, 1);
  {
    dim3 ag((NN / 2 * 64) / 256, T_STEPS);
    attn_conv<<<ag, 256, 0, stream>>>(qkvb, iOffs, iSE, cWe, hob);
  }
  // Layer 2: single-bf16 A (hob) -> qkvb (2-MFMA) ; attn -> hob (overwrite)
  {
    int blocks = ((((T_STEPS * NN) >> 5) + 7) >> 3) * (QS >> 7);
    gemm_mfma_b1<<<blocks, 512, 0, stream>>>(
        hob, WcatP + (size_t)131072, fbcat + QS, qkvb, T_STEPS * NN, QS, DD);
    dim3 ag((NN / 2 * 64) / 256, T_STEPS);
    attn_conv<<<ag, 256, 0, stream>>>(qkvb, iOffs, iSE, cWe + DD, hob);
  }

  // mean over T (bf16 -> fp32)
  mean_k<<<(NN * DD / 2) / 256, 256, 0, stream>>>(hob, fH);

  // output conv (d=1) on t=3 graph
  out_proj<<<(NN * 64) / 256, 256, 0, stream>>>(
      fH, oWq, oWk, oWv, oWs, obq, obk, obv, obs, fQ1, fK1, fV1, fS1);
  out_attn<<<(NN + 255) / 256, 256, 0, stream>>>(
      fQ1, fK1, fV1, fS1, iOffs + 3 * (NN + 1), iSE + (size_t)3 * EE, oWe, out);
}

// Round 10
// 544.618 us; speedup vs baseline: 1.7291x; 1.0050x over previous
//
#include <hip/hip_runtime.h>
#include <math.h>

#define T_STEPS 4
#define NN 20000
#define EE 160000
#define IND 64
#define DD 128
#define G3 384     // 3*D (GRU gates)
#define QS 512     // q|k|v|skip fused width

typedef __bf16 bf16x8 __attribute__((ext_vector_type(8)));
typedef _Float16 f16x8 __attribute__((ext_vector_type(8)));
typedef _Float16 half2v __attribute__((ext_vector_type(2)));
typedef float floatx4 __attribute__((ext_vector_type(4)));

// ---------------------------------------------------------------------------
// fp32 -> bf16 split (RNE) and fp16 helpers
// ---------------------------------------------------------------------------
__device__ inline unsigned short f2bf(float x) {
  unsigned u = __float_as_uint(x);
  unsigned r = (u + 0x7fffu + ((u >> 16) & 1u)) >> 16;
  return (unsigned short)r;
}
__device__ inline float bf2f(unsigned short h) {
  return __uint_as_float((unsigned)h << 16);
}
__device__ inline void bfsplit(float x, unsigned short& hi, unsigned short& lo) {
  hi = f2bf(x);
  lo = f2bf(x - bf2f(hi));
}
__device__ inline unsigned short f2h_bits(float x) {
  union { _Float16 h; unsigned short s; } u;
  u.h = (_Float16)x;   // v_cvt_f16_f32 (RNE)
  return u.s;
}
__device__ inline half2v shfl_xor_h2(half2v v, int m) {
  union { half2v h; int i; } u; u.h = v;
  u.i = __shfl_xor(u.i, m);
  return u.h;
}

// ---------------------------------------------------------------------------
// Split-bf16 MFMA GEMM with LDS-staged B (r9 proven). of16=0 -> fp32 C;
// of16=1 -> fp16 Cb. Block=512thr (8 waves) sharing one 128-col group.
// 32-row wave tile; DO NOT enlarge (r6: 64-row tile spilled accumulators).
// ---------------------------------------------------------------------------
__global__ __launch_bounds__(512) void gemm_mfma(
    const unsigned short* __restrict__ Ahi, const unsigned short* __restrict__ Alo,
    const unsigned short* __restrict__ Bp, const float* __restrict__ bias,
    float* __restrict__ C, unsigned short* __restrict__ Cb,
    int M, int N, int K, int of16)
{
  __shared__ unsigned short Bs[32768];   // 64 KB (max ktiles=4)
  const int ngroups = N >> 7;
  const int mtiles = M >> 5;
  const int ng = blockIdx.x % ngroups;
  const int mb = blockIdx.x / ngroups;
  const int ktiles = K >> 5;
  const int tid = threadIdx.x;
  const unsigned short* Bsrc = Bp + (size_t)ng * 8 * ktiles * 1024;
  const int nchunk = ktiles * 8 * 128;   // 16B chunks
  for (int i = tid; i < nchunk; i += 512)
    *(uint4*)&Bs[i * 8] = *(const uint4*)&Bsrc[i * 8];
  __syncthreads();
  const int w = tid >> 6;
  const int lane = tid & 63;
  const int mw = mb * 8 + w;
  if (mw >= mtiles) return;
  const int r = lane & 15, quad = lane >> 4;
  const unsigned short* a0h = Ahi + (size_t)(mw * 32 + r) * K + quad * 8;
  const unsigned short* a0l = Alo + (size_t)(mw * 32 + r) * K + quad * 8;
  const unsigned short* a1h = a0h + (size_t)16 * K;
  const unsigned short* a1l = a0l + (size_t)16 * K;
  floatx4 acc[2][8];
#pragma unroll
  for (int m = 0; m < 2; ++m)
#pragma unroll
    for (int nt = 0; nt < 8; ++nt) acc[m][nt] = (floatx4){0.f, 0.f, 0.f, 0.f};
  for (int kt = 0; kt < ktiles; ++kt) {
    bf16x8 a0hi = *(const bf16x8*)(a0h + kt * 32);
    bf16x8 a0lo = *(const bf16x8*)(a0l + kt * 32);
    bf16x8 a1hi = *(const bf16x8*)(a1h + kt * 32);
    bf16x8 a1lo = *(const bf16x8*)(a1l + kt * 32);
#pragma unroll
    for (int nt = 0; nt < 8; ++nt) {
      const unsigned short* bp = Bs + (nt * ktiles + kt) * 1024 + lane * 8;
      bf16x8 bhi = *(const bf16x8*)bp;
      bf16x8 blo = *(const bf16x8*)(bp + 512);
      acc[0][nt] = __builtin_amdgcn_mfma_f32_16x16x32_bf16(a0hi, bhi, acc[0][nt], 0, 0, 0);
      acc[0][nt] = __builtin_amdgcn_mfma_f32_16x16x32_bf16(a0hi, blo, acc[0][nt], 0, 0, 0);
      acc[0][nt] = __builtin_amdgcn_mfma_f32_16x16x32_bf16(a0lo, bhi, acc[0][nt], 0, 0, 0);
      acc[1][nt] = __builtin_amdgcn_mfma_f32_16x16x32_bf16(a1hi, bhi, acc[1][nt], 0, 0, 0);
      acc[1][nt] = __builtin_amdgcn_mfma_f32_16x16x32_bf16(a1hi, blo, acc[1][nt], 0, 0, 0);
      acc[1][nt] = __builtin_amdgcn_mfma_f32_16x16x32_bf16(a1lo, bhi, acc[1][nt], 0, 0, 0);
    }
  }
#pragma unroll
  for (int m = 0; m < 2; ++m) {
    const int crow0 = mw * 32 + m * 16 + quad * 4;
#pragma unroll
    for (int nt = 0; nt < 8; ++nt) {
      const int col = ng * 128 + nt * 16 + r;
      const float b = bias[col];
      if (of16) {
#pragma unroll
        for (int i = 0; i < 4; ++i)
          Cb[(size_t)(crow0 + i) * N + col] = f2h_bits(acc[m][nt][i] + b);
      } else {
#pragma unroll
        for (int i = 0; i < 4; ++i)
          C[(size_t)(crow0 + i) * N + col] = acc[m][nt][i] + b;
      }
    }
  }
}

// ---------------------------------------------------------------------------
// Single-f16-A MFMA GEMM, LDS-staged B (2 MFMA/tile), f16 B hi/lo, fp16 out.
// ---------------------------------------------------------------------------
__global__ __launch_bounds__(512) void gemm_mfma_b1(
    const unsigned short* __restrict__ A,
    const unsigned short* __restrict__ Bp, const float* __restrict__ bias,
    unsigned short* __restrict__ Cb, int M, int N, int K)
{
  __shared__ unsigned short Bs[32768];
  const int ngroups = N >> 7;
  const int mtiles = M >> 5;
  const int ng = blockIdx.x % ngroups;
  const int mb = blockIdx.x / ngroups;
  const int ktiles = K >> 5;
  const int tid = threadIdx.x;
  const unsigned short* Bsrc = Bp + (size_t)ng * 8 * ktiles * 1024;
  const int nchunk = ktiles * 8 * 128;
  for (int i = tid; i < nchunk; i += 512)
    *(uint4*)&Bs[i * 8] = *(const uint4*)&Bsrc[i * 8];
  __syncthreads();
  const int w = tid >> 6;
  const int lane = tid & 63;
  const int mw = mb * 8 + w;
  if (mw >= mtiles) return;
  const int r = lane & 15, quad = lane >> 4;
  const unsigned short* a0 = A + (size_t)(mw * 32 + r) * K + quad * 8;
  const unsigned short* a1 = a0 + (size_t)16 * K;
  floatx4 acc[2][8];
#pragma unroll
  for (int m = 0; m < 2; ++m)
#pragma unroll
    for (int nt = 0; nt < 8; ++nt) acc[m][nt] = (floatx4){0.f, 0.f, 0.f, 0.f};
  for (int kt = 0; kt < ktiles; ++kt) {
    f16x8 af0 = *(const f16x8*)(a0 + kt * 32);
    f16x8 af1 = *(const f16x8*)(a1 + kt * 32);
#pragma unroll
    for (int nt = 0; nt < 8; ++nt) {
      const unsigned short* bp = Bs + (nt * ktiles + kt) * 1024 + lane * 8;
      f16x8 bhi = *(const f16x8*)bp;
      f16x8 blo = *(const f16x8*)(bp + 512);
      acc[0][nt] = __builtin_amdgcn_mfma_f32_16x16x32_f16(af0, bhi, acc[0][nt], 0, 0, 0);
      acc[0][nt] = __builtin_amdgcn_mfma_f32_16x16x32_f16(af0, blo, acc[0][nt], 0, 0, 0);
      acc[1][nt] = __builtin_amdgcn_mfma_f32_16x16x32_f16(af1, bhi, acc[1][nt], 0, 0, 0);
      acc[1][nt] = __builtin_amdgcn_mfma_f32_16x16x32_f16(af1, blo, acc[1][nt], 0, 0, 0);
    }
  }
#pragma unroll
  for (int m = 0; m < 2; ++m) {
    const int crow0 = mw * 32 + m * 16 + quad * 4;
#pragma unroll
    for (int nt = 0; nt < 8; ++nt) {
      const int col = ng * 128 + nt * 16 + r;
      const float b = bias[col];
#pragma unroll
      for (int i = 0; i < 4; ++i)
        Cb[(size_t)(crow0 + i) * N + col] = f2h_bits(acc[m][nt][i] + b);
    }
  }
}

// ---------------------------------------------------------------------------
// Weight packing. GRU + conv layer0: bf16 hi/lo. Conv layer1: f16 hi/lo
// (feeds the f16 MFMA of gemm_mfma_b1). + fused conv bias.
// ---------------------------------------------------------------------------
#define BIH_PAIRS 24576    // (384/16)*(64/32)*512
#define BHH_PAIRS 49152    // 24*4*512
#define WCAT_PAIRS 131072  // 2*32*4*512
#define BCAT_N 1024

__global__ void pack_weights(
    const float* __restrict__ Wih, const float* __restrict__ Whh,
    const float* __restrict__ Wq, const float* __restrict__ Wk,
    const float* __restrict__ Wv, const float* __restrict__ Ws,
    const float* __restrict__ bq, const float* __restrict__ bk,
    const float* __restrict__ bv, const float* __restrict__ bs,
    unsigned short* __restrict__ BihP, unsigned short* __restrict__ BhhP,
    unsigned short* __restrict__ WcatP, float* __restrict__ bcat)
{
  int gid = blockIdx.x * 256 + threadIdx.x;
  if (gid < BIH_PAIRS) {  // K=64, N=384, ktiles=2
    int tile = gid >> 9, lj = gid & 511, lane = lj >> 3, j = lj & 7;
    int k_tile = tile & 1, n_tile = tile >> 1;
    int n = n_tile * 16 + (lane & 15);
    int k = k_tile * 32 + (lane >> 4) * 8 + j;
    unsigned short hi, lo;
    bfsplit(Wih[n * IND + k], hi, lo);   // B[k][n] = Wih^T
    BihP[tile * 1024 + lane * 8 + j] = hi;
    BihP[tile * 1024 + 512 + lane * 8 + j] = lo;
    return;
  }
  gid -= BIH_PAIRS;
  if (gid < BHH_PAIRS) {  // K=128, N=384, ktiles=4
    int tile = gid >> 9, lj = gid & 511, lane = lj >> 3, j = lj & 7;
    int k_tile = tile & 3, n_tile = tile >> 2;
    int n = n_tile * 16 + (lane & 15);
    int k = k_tile * 32 + (lane >> 4) * 8 + j;
    unsigned short hi, lo;
    bfsplit(Whh[n * DD + k], hi, lo);
    BhhP[tile * 1024 + lane * 8 + j] = hi;
    BhhP[tile * 1024 + 512 + lane * 8 + j] = lo;
    return;
  }
  gid -= BHH_PAIRS;
  if (gid < WCAT_PAIRS) {  // per layer: K=128, N=512, ktiles=4
    int l = gid >> 16, rem = gid & 65535;
    int tile = rem >> 9, lj = rem & 511, lane = lj >> 3, j = lj & 7;
    int k_tile = tile & 3, n_tile = tile >> 2;
    int n = n_tile * 16 + (lane & 15);
    int k = k_tile * 32 + (lane >> 4) * 8 + j;
    const float* W = (n < 128) ? Wq : (n < 256) ? Wk : (n < 384) ? Wv : Ws;
    float x = W[l * DD * DD + k * DD + (n & 127)];
    size_t base = (size_t)l * 131072 + tile * 1024;
    if (l == 0) {
      unsigned short hi, lo;
      bfsplit(x, hi, lo);
      WcatP[base + lane * 8 + j] = hi;
      WcatP[base + 512 + lane * 8 + j] = lo;
    } else {
      union { _Float16 h; unsigned short s; } uh, ul;
      uh.h = (_Float16)x;
      ul.h = (_Float16)(x - (float)uh.h);
      WcatP[base + lane * 8 + j] = uh.s;
      WcatP[base + 512 + lane * 8 + j] = ul.s;
    }
    return;
  }
  gid -= WCAT_PAIRS;
  if (gid < BCAT_N) {
    int l = gid >> 9, n = gid & 511;
    const float* b = (n < 128) ? bq : (n < 256) ? bk : (n < 384) ? bv : bs;
    bcat[gid] = b[l * DD + (n & 127)];
  }
}

// ---------------------------------------------------------------------------
__global__ void xsplit(const float* __restrict__ x,
                       unsigned short* __restrict__ xhi,
                       unsigned short* __restrict__ xlo)
{
  int i = blockIdx.x * 256 + threadIdx.x;   // exact T*NN*IND grid
  unsigned short hi, lo;
  bfsplit(x[i], hi, lo);
  xhi[i] = hi; xlo[i] = lo;
}

// ---------------------------------------------------------------------------
// CSR build (by destination), per timestep; parallel 3-phase scan
// ---------------------------------------------------------------------------
#define SCHUNK 1024
#define NCHUNK 20          // ceil(20000/1024)

__global__ void csr_count(const int* __restrict__ ei, int* __restrict__ deg)
{
  int gid = blockIdx.x * 256 + threadIdx.x;
  if (gid >= T_STEPS * EE) return;
  int t = gid / EE, e = gid % EE;
  int dst = ei[(size_t)t * 2 * EE + EE + e];
  atomicAdd(&deg[t * NN + dst], 1);
}

__global__ void scan1(const int* __restrict__ deg, int* __restrict__ part)
{
  const int b = blockIdx.x;              // 0..T*NCHUNK-1
  const int t = b / NCHUNK, c = b % NCHUNK;
  const int tid = threadIdx.x;
  __shared__ int s[256];
  int base = c * SCHUNK + tid * 4;
  int sum = 0;
#pragma unroll
  for (int u = 0; u < 4; ++u) {
    int i = base + u;
    if (i < NN) sum += deg[t * NN + i];
  }
  s[tid] = sum;
  __syncthreads();
  for (int o = 128; o > 0; o >>= 1) {
    if (tid < o) s[tid] += s[tid + o];
    __syncthreads();
  }
  if (tid == 0) part[b] = s[0];
}

__global__ void scan2(int* __restrict__ part, int* __restrict__ offs)
{
  const int tid = threadIdx.x;
  __shared__ int s[T_STEPS * NCHUNK];
  if (tid < T_STEPS * NCHUNK) s[tid] = part[tid];
  __syncthreads();
  if (tid == 0) {
    for (int t = 0; t < T_STEPS; ++t) {
      int run = 0;
      for (int c = 0; c < NCHUNK; ++c) {
        int v = s[t * NCHUNK + c];
        s[t * NCHUNK + c] = run;
        run += v;
      }
      offs[t * (NN + 1) + NN] = run;
    }
  }
  __syncthreads();
  if (tid < T_STEPS * NCHUNK) part[tid] = s[tid];
}

__global__ void scan3(const int* __restrict__ deg, const int* __restrict__ part,
                      int* __restrict__ offs, int* __restrict__ cur)
{
  const int b = blockIdx.x;
  const int t = b / NCHUNK, c = b % NCHUNK;
  const int tid = threadIdx.x;
  __shared__ int s[256];
  int base = c * SCHUNK + tid * 4;
  int v[4]; int sum = 0;
#pragma unroll
  for (int u = 0; u < 4; ++u) {
    int i = base + u;
    v[u] = (i < NN) ? deg[t * NN + i] : 0;
    sum += v[u];
  }
  s[tid] = sum;
  __syncthreads();
  for (int o = 1; o < 256; o <<= 1) {
    int x = (tid >= o) ? s[tid - o] : 0;
    __syncthreads();
    s[tid] += x;
    __syncthreads();
  }
  int excl = part[b] + s[tid] - sum;
#pragma unroll
  for (int u = 0; u < 4; ++u) {
    int i = base + u;
    if (i < NN) {
      offs[t * (NN + 1) + i] = excl;
      cur[t * NN + i] = excl;
    }
    excl += v[u];
  }
}

// packed CSR entry: .x = src node, .y = edge_attr bits (one 8B store per edge)
__global__ void csr_fill(const int* __restrict__ ei, const float* __restrict__ ea,
                         int* __restrict__ cur, int2* __restrict__ cse)
{
  int gid = blockIdx.x * 256 + threadIdx.x;
  if (gid >= T_STEPS * EE) return;
  int t = gid / EE, e = gid % EE;
  int src = ei[(size_t)t * 2 * EE + e];
  int dst = ei[(size_t)t * 2 * EE + EE + e];
  int slot = atomicAdd(&cur[t * NN + dst], 1);
  cse[(size_t)t * EE + slot] = make_int2(src, __float_as_int(ea[(size_t)t * EE + e]));
}

// ---------------------------------------------------------------------------
// GRU gate fusion. t0: gh == b_hh exactly (h0=0), h_prev=0.
// ---------------------------------------------------------------------------
__global__ __launch_bounds__(256) void gru_gate(
    const float* __restrict__ gi, const float* __restrict__ gh,
    const float* __restrict__ b_hh, int t0,
    const unsigned short* __restrict__ phi, const unsigned short* __restrict__ plo,
    unsigned short* __restrict__ hhi_t, unsigned short* __restrict__ hlo_t)
{
  int idx = blockIdx.x * 256 + threadIdx.x;   // exact NN*DD grid
  int n = idx >> 7, d = idx & 127;
  size_t gb = (size_t)n * G3 + d;
  float ir = gi[gb], iz = gi[gb + DD], inn = gi[gb + 2 * DD];
  float hr, hz, hn, hp;
  if (t0) {
    hr = b_hh[d]; hz = b_hh[DD + d]; hn = b_hh[2 * DD + d]; hp = 0.f;
  } else {
    hr = gh[gb]; hz = gh[gb + DD]; hn = gh[gb + 2 * DD];
    hp = bf2f(phi[idx]) + bf2f(plo[idx]);
  }
  float r = 1.f / (1.f + __expf(-(ir + hr)));
  float z = 1.f / (1.f + __expf(-(iz + hz)));
  float nv = tanhf(inn + r * hn);
  float hnew = (1.f - z) * nv + z * hp;
  unsigned short hi, lo;
  bfsplit(hnew, hi, lo);
  hhi_t[idx] = hi; hlo_t[idx] = lo;
}

// ---------------------------------------------------------------------------
// Fused TransformerConv (d=128), fp16 qkv, packed math.
// 1D grid 10000 blocks, XCD-aware swizzle: t = (bid&7)>>1 so each XCD
// (heuristic bid%8) gathers only one timestep's k/v (10.2 MB working set
// vs 41 MB -> better per-XCD L2 hit).
// TWO nodes per wave: lane = half(1b)|es(2b)|fg(3b); 4 edge-slots x 8
// feature-groups (16 fp16 each). No-max softmax + factored edge feature
// (r7-verified). q.k via v_dot2_f32_f16, v-accum via v_pk_fma_f16.
// ---------------------------------------------------------------------------
__global__ __launch_bounds__(256) void attn_conv(
    const unsigned short* __restrict__ qkvh,  // [T][NN][512] fp16
    const int* __restrict__ offs4,    // [T][NN+1]
    const int2* __restrict__ cse4,    // [T][E]
    const float* __restrict__ We,     // [128] fp32
    unsigned short* __restrict__ hoh) // [T][NN][128] fp16 out
{
  const int bid = blockIdx.x;
  const int xc = bid & 7, jb = bid >> 3;
  const int t = xc >> 1;
  const int blk = jb * 2 + (xc & 1);          // 0..2499 within t
  const unsigned short* qk = qkvh + (size_t)t * NN * QS;
  const int* offs = offs4 + (size_t)t * (NN + 1);
  const int2* cse = cse4 + (size_t)t * EE;
  const int lane = threadIdx.x & 63;
  const int w = threadIdx.x >> 6;             // 4 waves/block
  const int hlf = lane >> 5;
  const int es = (lane >> 3) & 3;             // 4 edge slots
  const int fg = lane & 7;                    // 8 feature groups
  const int node = blk * 8 + w * 2 + hlf;     // exact 20000 per t
  const int f0 = fg * 16;
  const float scale = 0.08838834764831845f;   // 1/sqrt(128)

  union U16 { uint4 u[2]; half2v h[8]; };
  U16 q;
  {
    const uint4* p = (const uint4*)(qk + (size_t)node * QS + f0);
    q.u[0] = p[0]; q.u[1] = p[1];
  }
  // We -> half2 pairs (for the q.We dot)
  half2v we2[8];
  {
    const float4* wp = (const float4*)&We[f0];
    float4 w0 = wp[0], w1 = wp[1], w2 = wp[2], w3 = wp[3];
    we2[0] = (half2v){(_Float16)w0.x, (_Float16)w0.y};
    we2[1] = (half2v){(_Float16)w0.z, (_Float16)w0.w};
    we2[2] = (half2v){(_Float16)w1.x, (_Float16)w1.y};
    we2[3] = (half2v){(_Float16)w1.z, (_Float16)w1.w};
    we2[4] = (half2v){(_Float16)w2.x, (_Float16)w2.y};
    we2[5] = (half2v){(_Float16)w2.z, (_Float16)w2.w};
    we2[6] = (half2v){(_Float16)w3.x, (_Float16)w3.y};
    we2[7] = (half2v){(_Float16)w3.z, (_Float16)w3.w};
  }
  float qwe = 0.f;
#pragma unroll
  for (int j = 0; j < 8; ++j) {
#if __has_builtin(__builtin_amdgcn_fdot2)
    qwe = __builtin_amdgcn_fdot2(q.h[j], we2[j], qwe, false);
#else
    qwe = fmaf((float)q.h[j].x, (float)we2[j].x, qwe);
    qwe = fmaf((float)q.h[j].y, (float)we2[j].y, qwe);
#endif
  }
  qwe += __shfl_xor(qwe, 1); qwe += __shfl_xor(qwe, 2); qwe += __shfl_xor(qwe, 4);

  const int e0 = offs[node], e1 = offs[node + 1];
  float l_lane = 0.f, sA_lane = 0.f;
  half2v acc2[8];
#pragma unroll
  for (int i = 0; i < 8; ++i) acc2[i] = (half2v){(_Float16)0.f, (_Float16)0.f};

  for (int base = e0; base < e1; base += 4) {
    const int eidx = base + es;
    const bool valid = eidx < e1;
    int2 se = valid ? cse[eidx] : make_int2(0, 0);
    const float a = __int_as_float(se.y);
    U16 kf;
    {
      const uint4* p = (const uint4*)(qk + (size_t)se.x * QS + 128 + f0);
      kf.u[0] = p[0]; kf.u[1] = p[1];
    }
    float p = 0.f;
#pragma unroll
    for (int j = 0; j < 8; ++j) {
#if __has_builtin(__builtin_amdgcn_fdot2)
      p = __builtin_amdgcn_fdot2(q.h[j], kf.h[j], p, false);
#else
      p = fmaf((float)q.h[j].x, (float)kf.h[j].x, p);
      p = fmaf((float)q.h[j].y, (float)kf.h[j].y, p);
#endif
    }
    p += __shfl_xor(p, 1); p += __shfl_xor(p, 2); p += __shfl_xor(p, 4);
    const float ex = valid ? __expf((p + a * qwe) * scale) : 0.f;
    l_lane += ex;
    sA_lane = fmaf(ex, a, sA_lane);
    const _Float16 exh = (_Float16)ex;
    const half2v ex2 = (half2v){exh, exh};
    U16 vf;
    {
      const uint4* p2 = (const uint4*)(qk + (size_t)se.x * QS + 256 + f0);
      vf.u[0] = p2[0]; vf.u[1] = p2[1];
    }
#pragma unroll
    for (int j = 0; j < 8; ++j)
      acc2[j] = ex2 * vf.h[j] + acc2[j];   // v_pk_fma_f16
  }
  // reductions over the 4 edge-slots (xor 8,16 stay within the 32-lane half)
  l_lane += __shfl_xor(l_lane, 8);  l_lane += __shfl_xor(l_lane, 16);
  sA_lane += __shfl_xor(sA_lane, 8); sA_lane += __shfl_xor(sA_lane, 16);
#pragma unroll
  for (int i = 0; i < 8; ++i) {
    acc2[i] = acc2[i] + shfl_xor_h2(acc2[i], 8);
    acc2[i] = acc2[i] + shfl_xor_h2(acc2[i], 16);
  }
  if (es != 0) return;
  const float inv = 1.f / (l_lane + 1e-16f);
  const float sAi = sA_lane * inv;
  U16 sk;
  {
    const uint4* p = (const uint4*)(qk + (size_t)node * QS + 384 + f0);
    sk.u[0] = p[0]; sk.u[1] = p[1];
  }
  float wf[16];
  {
    const float4* wp = (const float4*)&We[f0];
#pragma unroll
    for (int j = 0; j < 4; ++j) *(float4*)&wf[4 * j] = wp[j];
  }
  U16 outp;
#pragma unroll
  for (int j = 0; j < 8; ++j) {
    float oa = fmaf((float)acc2[j].x, inv, fmaf(sAi, wf[2 * j],     (float)sk.h[j].x));
    float ob = fmaf((float)acc2[j].y, inv, fmaf(sAi, wf[2 * j + 1], (float)sk.h[j].y));
    oa = (oa > 0.f) ? oa : 0.01f * oa;    // leaky_relu
    ob = (ob > 0.f) ? ob : 0.01f * ob;
    outp.h[j] = (half2v){(_Float16)oa, (_Float16)ob};
  }
  unsigned short* dst = hoh + ((size_t)t * NN + node) * DD + f0;
  *(uint4*)(dst + 0) = outp.u[0];
  *(uint4*)(dst + 8) = outp.u[1];
}

// ---------------------------------------------------------------------------
// mean over T from fp16; 2 elems per thread
// ---------------------------------------------------------------------------
__global__ void mean_k(const unsigned short* __restrict__ hb,
                       float* __restrict__ hm)
{
  int i = blockIdx.x * 256 + threadIdx.x;   // exact NN*DD/2 grid
  float vx = 0.f, vy = 0.f;
#pragma unroll
  for (int t = 0; t < T_STEPS; ++t) {
    union { unsigned u; half2v h; } c;
    c.u = *(const unsigned*)&hb[(size_t)t * NN * DD + 2 * i];
    vx += (float)c.h.x;
    vy += (float)c.h.y;
  }
  *(float2*)&hm[2 * i] = make_float2(0.25f * vx, 0.25f * vy);
}

// ---------------------------------------------------------------------------
__global__ __launch_bounds__(256) void out_proj(
    const float* __restrict__ h,
    const float* __restrict__ Wq, const float* __restrict__ Wk,
    const float* __restrict__ Wv, const float* __restrict__ Ws,
    const float* __restrict__ bq, const float* __restrict__ bk,
    const float* __restrict__ bv, const float* __restrict__ bs,
    float* __restrict__ q1, float* __restrict__ k1,
    float* __restrict__ v1, float* __restrict__ s1)
{
  const int wv = (blockIdx.x * 256 + threadIdx.x) >> 6;
  const int lane = threadIdx.x & 63;
  if (wv >= NN) return;
  float2 h2 = *(const float2*)&h[(size_t)wv * DD + 2 * lane];
  float pq = h2.x * Wq[2 * lane] + h2.y * Wq[2 * lane + 1];
  float pk = h2.x * Wk[2 * lane] + h2.y * Wk[2 * lane + 1];
  float pv = h2.x * Wv[2 * lane] + h2.y * Wv[2 * lane + 1];
  float ps = h2.x * Ws[2 * lane] + h2.y * Ws[2 * lane + 1];
#pragma unroll
  for (int o = 1; o < 64; o <<= 1) {
    pq += __shfl_xor(pq, o); pk += __shfl_xor(pk, o);
    pv += __shfl_xor(pv, o); ps += __shfl_xor(ps, o);
  }
  if (lane == 0) {
    q1[wv] = pq + bq[0]; k1[wv] = pk + bk[0];
    v1[wv] = pv + bv[0]; s1[wv] = ps + bs[0];
  }
}

__global__ void out_attn(
    const float* __restrict__ q1, const float* __restrict__ k1,
    const float* __restrict__ v1, const float* __restrict__ s1,
    const int* __restrict__ offs, const int2* __restrict__ cse,
    const float* __restrict__ We, float* __restrict__ out)
{
  int n = blockIdx.x * 256 + threadIdx.x;
  if (n >= NN) return;
  const float we = We[0];
  const float q = q1[n];
  const int e0 = offs[n], e1 = offs[n + 1];
  float m = -INFINITY;
  for (int e = e0; e < e1; ++e) {
    int2 se = cse[e];
    float al = q * (k1[se.x] + __int_as_float(se.y) * we);
    m = fmaxf(m, al);
  }
  float l = 0.f, acc = 0.f;
  for (int e = e0; e < e1; ++e) {
    int2 se = cse[e];
    float ca = __int_as_float(se.y);
    float al = q * (k1[se.x] + ca * we);
    float ex = __expf(al - m);
    l += ex;
    acc += ex * (v1[se.x] + ca * we);
  }
  out[n] = acc / (l + 1e-16f) + s1[n];
}

// ---------------------------------------------------------------------------
extern "C" void kernel_launch(void* const* d_in, const int* in_sizes, int n_in,
                              void* d_out, int out_size, void* d_ws, size_t ws_size,
                              hipStream_t stream)
{
  const float* x_seq = (const float*)d_in[0];
  const int*   ei    = (const int*)  d_in[1];
  const float* ea    = (const float*)d_in[2];
  const float* W_ih  = (const float*)d_in[3];
  const float* W_hh  = (const float*)d_in[4];
  const float* b_ih  = (const float*)d_in[5];
  const float* b_hh  = (const float*)d_in[6];
  const float* cWq   = (const float*)d_in[7];
  const float* cbq   = (const float*)d_in[8];
  const float* cWk   = (const float*)d_in[9];
  const float* cbk   = (const float*)d_in[10];
  const float* cWv   = (const float*)d_in[11];
  const float* cbv   = (const float*)d_in[12];
  const float* cWe   = (const float*)d_in[13];
  const float* cWs   = (const float*)d_in[14];
  const float* cbs   = (const float*)d_in[15];
  const float* oWq   = (const float*)d_in[16];
  const float* obq   = (const float*)d_in[17];
  const float* oWk   = (const float*)d_in[18];
  const float* obk   = (const float*)d_in[19];
  const float* oWv   = (const float*)d_in[20];
  const float* obv   = (const float*)d_in[21];
  const float* oWe   = (const float*)d_in[22];
  const float* oWs   = (const float*)d_in[23];
  const float* obs   = (const float*)d_in[24];
  float* out = (float*)d_out;

  char* ws = (char*)d_ws;
  size_t off = 0;
  auto alloc = [&](size_t bytes) -> char* {
    char* p = ws + off;
    off += (bytes + 255) & ~(size_t)255;
    return p;
  };
  // ---- total ~181 MB (<186 MB proven r2; r3's 289 MB aborted) ----
  unsigned short* BihP  = (unsigned short*)alloc((size_t)2 * BIH_PAIRS * 2);
  unsigned short* BhhP  = (unsigned short*)alloc((size_t)2 * BHH_PAIRS * 2);
  unsigned short* WcatP = (unsigned short*)alloc((size_t)2 * WCAT_PAIRS * 2);
  float* fbcat = (float*)alloc((size_t)BCAT_N * 4);
  unsigned short* xhi   = (unsigned short*)alloc((size_t)T_STEPS * NN * IND * 2);
  unsigned short* xlo   = (unsigned short*)alloc((size_t)T_STEPS * NN * IND * 2);
  unsigned short* hallhi = (unsigned short*)alloc((size_t)T_STEPS * NN * DD * 2);
  unsigned short* halllo = (unsigned short*)alloc((size_t)T_STEPS * NN * DD * 2);
  float* fH    = (float*)alloc((size_t)NN * DD * 4);          // h_mean
  int*   iDeg  = (int*)  alloc((size_t)T_STEPS * NN * 4);     // zero-init
  int*   iCur  = (int*)  alloc((size_t)T_STEPS * NN * 4);
  int*   iOffs = (int*)  alloc((size_t)T_STEPS * (NN + 1) * 4);
  int*   iPart = (int*)  alloc((size_t)T_STEPS * NCHUNK * 4);
  int2*  iSE   = (int2*) alloc((size_t)T_STEPS * EE * 8);
  float* fQ1   = (float*)alloc((size_t)NN * 4);
  float* fK1   = (float*)alloc((size_t)NN * 4);
  float* fV1   = (float*)alloc((size_t)NN * 4);
  float* fS1   = (float*)alloc((size_t)NN * 4);
  // union: GRU phase gi2 [2NN*G3 f32] + gh [NN*G3 f32] = 92.2 MB;
  //        conv phase qkvh [4NN*512 fp16] 81.9 MB + hoh [4NN*128 fp16] 20.5 MB
  size_t uniOff = off;
  float* fGi2  = (float*)(ws + uniOff);
  float* fGh   = (float*)(ws + uniOff + (size_t)2 * NN * G3 * 4);
  unsigned short* qkvh = (unsigned short*)(ws + uniOff);
  unsigned short* hoh  = (unsigned short*)(ws + uniOff + (size_t)T_STEPS * NN * QS * 2);
  (void)ws_size; (void)in_sizes; (void)n_in; (void)out_size;

  auto gemm = [&](const unsigned short* Ahi, const unsigned short* Alo,
                  const unsigned short* Bp, const float* bias, float* C,
                  unsigned short* Cb, int M, int N, int K, int of16) {
    int blocks = (((M >> 5) + 7) >> 3) * (N >> 7);
    gemm_mfma<<<blocks, 512, 0, stream>>>(Ahi, Alo, Bp, bias, C, Cb,
                                          M, N, K, of16);
  };

  // weights + activation split + CSR
  pack_weights<<<(BIH_PAIRS + BHH_PAIRS + WCAT_PAIRS + BCAT_N + 255) / 256, 256, 0,
                 stream>>>(W_ih, W_hh, cWq, cWk, cWv, cWs, cbq, cbk, cbv, cbs,
                           BihP, BhhP, WcatP, fbcat);
  xsplit<<<(T_STEPS * NN * IND) / 256, 256, 0, stream>>>(x_seq, xhi, xlo);
  hipMemsetAsync(iDeg, 0, (size_t)T_STEPS * NN * 4, stream);
  csr_count<<<(T_STEPS * EE) / 256, 256, 0, stream>>>(ei, iDeg);
  scan1<<<T_STEPS * NCHUNK, 256, 0, stream>>>(iDeg, iPart);
  scan2<<<1, 128, 0, stream>>>(iPart, iOffs);
  scan3<<<T_STEPS * NCHUNK, 256, 0, stream>>>(iDeg, iPart, iOffs, iCur);
  csr_fill<<<(T_STEPS * EE) / 256, 256, 0, stream>>>(ei, ea, iCur, iSE);

  // GRU over time: gi batched in pairs of t, gh sequential (t=0 skipped)
  for (int tp = 0; tp < 2; ++tp) {
    gemm(xhi + (size_t)tp * 2 * NN * IND, xlo + (size_t)tp * 2 * NN * IND,
         BihP, b_ih, fGi2, nullptr, 2 * NN, G3, IND, 0);
    for (int k = 0; k < 2; ++k) {
      const int t = tp * 2 + k;
      const unsigned short* phi = hallhi + (size_t)(t - 1) * NN * DD;  // unused t=0
      const unsigned short* plo = halllo + (size_t)(t - 1) * NN * DD;
      if (t > 0) gemm(phi, plo, BhhP, b_hh, fGh, nullptr, NN, G3, DD, 0);
      gru_gate<<<(NN * DD) / 256, 256, 0, stream>>>(
          fGi2 + (size_t)k * NN * G3, fGh, b_hh, (t == 0) ? 1 : 0,
          (t == 0) ? hallhi : phi, (t == 0) ? halllo : plo,
          hallhi + (size_t)t * NN * DD, halllo + (size_t)t * NN * DD);
    }
  }

  const int ATTN_BLOCKS = (NN / 8) * T_STEPS;   // 2500 * 4 = 10000, 1D swizzled

  // Layer 1: bf16 hi/lo A (GRU out) -> qkvh (fp16) ; attn -> hoh (fp16)
  gemm(hallhi, halllo, WcatP, fbcat, nullptr, qkvh, T_STEPS * NN, QS, DD, 1);
  attn_conv<<<ATTN_BLOCKS, 256, 0, stream>>>(qkvh, iOffs, iSE, cWe, hoh);

  // Layer 2: f16 A (hoh) x f16 hi/lo B -> qkvh ; attn -> hoh (overwrite)
  {
    int blocks = ((((T_STEPS * NN) >> 5) + 7) >> 3) * (QS >> 7);
    gemm_mfma_b1<<<blocks, 512, 0, stream>>>(
        hoh, WcatP + (size_t)131072, fbcat + QS, qkvh, T_STEPS * NN, QS, DD);
    attn_conv<<<ATTN_BLOCKS, 256, 0, stream>>>(qkvh, iOffs, iSE, cWe + DD, hoh);
  }

  // mean over T (fp16 -> fp32)
  mean_k<<<(NN * DD / 2) / 256, 256, 0, stream>>>(hoh, fH);

  // output conv (d=1) on t=3 graph
  out_proj<<<(NN * 64) / 256, 256, 0, stream>>>(
      fH, oWq, oWk, oWv, oWs, obq, obk, obv, obs, fQ1, fK1, fV1, fS1);
  out_attn<<<(NN + 255) / 256, 256, 0, stream>>>(
      fQ1, fK1, fV1, fS1, iOffs + 3 * (NN + 1), iSE + (size_t)3 * EE, oWe, out);
}

// Round 11
// 494.827 us; speedup vs baseline: 1.9031x; 1.1006x over previous
//
#include <hip/hip_runtime.h>
#include <math.h>

#define T_STEPS 4
#define NN 20000
#define EE 160000
#define IND 64
#define DD 128
#define G3 384     // 3*D (GRU gates)
#define QS 512     // q|k|v|skip fused width

typedef _Float16 f16x8 __attribute__((ext_vector_type(8)));
typedef _Float16 half2v __attribute__((ext_vector_type(2)));
typedef float floatx4 __attribute__((ext_vector_type(4)));

// ---------------------------------------------------------------------------
// fp16 helpers
// ---------------------------------------------------------------------------
__device__ inline unsigned short f2h_bits(float x) {
  union { _Float16 h; unsigned short s; } u;
  u.h = (_Float16)x;   // v_cvt_f16_f32 (RNE)
  return u.s;
}
__device__ inline float h2f(unsigned short s) {
  union { unsigned short s; _Float16 h; } u;
  u.s = s;
  return (float)u.h;
}
__device__ inline half2v shfl_xor_h2(half2v v, int m) {
  union { half2v h; int i; } u; u.h = v;
  u.i = __shfl_xor(u.i, m);
  return u.h;
}

// ---------------------------------------------------------------------------
// Unified f16 MFMA GEMM, LDS-staged B: C = A x (Bhi+Blo) + bias, fp16 out.
// A plain fp16 row-major [M][K]; weights f16 hi/lo (products exact in fp32
// accum -> weight error ~2^-22). Block = 512 thr (8 waves) sharing one
// 128-col group; B (<=64KB) staged once (r9-proven: kills per-wave L2
// latency serialization). 32-row wave tile; DO NOT enlarge (r6 spill).
// ---------------------------------------------------------------------------
__global__ __launch_bounds__(512) void gemm_f16(
    const unsigned short* __restrict__ A,
    const unsigned short* __restrict__ Bp, const float* __restrict__ bias,
    unsigned short* __restrict__ Cb, int M, int N, int K)
{
  __shared__ unsigned short Bs[32768];   // 64 KB (max ktiles=4)
  const int ngroups = N >> 7;
  const int mtiles = M >> 5;
  const int ng = blockIdx.x % ngroups;
  const int mb = blockIdx.x / ngroups;
  const int ktiles = K >> 5;
  const int tid = threadIdx.x;
  const unsigned short* Bsrc = Bp + (size_t)ng * 8 * ktiles * 1024;
  const int nchunk = ktiles * 8 * 128;   // 16B chunks
  for (int i = tid; i < nchunk; i += 512)
    *(uint4*)&Bs[i * 8] = *(const uint4*)&Bsrc[i * 8];
  __syncthreads();
  const int w = tid >> 6;
  const int lane = tid & 63;
  const int mw = mb * 8 + w;
  if (mw >= mtiles) return;
  const int r = lane & 15, quad = lane >> 4;
  const unsigned short* a0 = A + (size_t)(mw * 32 + r) * K + quad * 8;
  const unsigned short* a1 = a0 + (size_t)16 * K;
  floatx4 acc[2][8];
#pragma unroll
  for (int m = 0; m < 2; ++m)
#pragma unroll
    for (int nt = 0; nt < 8; ++nt) acc[m][nt] = (floatx4){0.f, 0.f, 0.f, 0.f};
  for (int kt = 0; kt < ktiles; ++kt) {
    f16x8 af0 = *(const f16x8*)(a0 + kt * 32);
    f16x8 af1 = *(const f16x8*)(a1 + kt * 32);
#pragma unroll
    for (int nt = 0; nt < 8; ++nt) {
      const unsigned short* bp = Bs + (nt * ktiles + kt) * 1024 + lane * 8;
      f16x8 bhi = *(const f16x8*)bp;
      f16x8 blo = *(const f16x8*)(bp + 512);
      acc[0][nt] = __builtin_amdgcn_mfma_f32_16x16x32_f16(af0, bhi, acc[0][nt], 0, 0, 0);
      acc[0][nt] = __builtin_amdgcn_mfma_f32_16x16x32_f16(af0, blo, acc[0][nt], 0, 0, 0);
      acc[1][nt] = __builtin_amdgcn_mfma_f32_16x16x32_f16(af1, bhi, acc[1][nt], 0, 0, 0);
      acc[1][nt] = __builtin_amdgcn_mfma_f32_16x16x32_f16(af1, blo, acc[1][nt], 0, 0, 0);
    }
  }
#pragma unroll
  for (int m = 0; m < 2; ++m) {
    const int crow0 = mw * 32 + m * 16 + quad * 4;
#pragma unroll
    for (int nt = 0; nt < 8; ++nt) {
      const int col = ng * 128 + nt * 16 + r;
      const float b = bias[col];
#pragma unroll
      for (int i = 0; i < 4; ++i)
        Cb[(size_t)(crow0 + i) * N + col] = f2h_bits(acc[m][nt][i] + b);
    }
  }
}

// ---------------------------------------------------------------------------
// Weight packing: ALL weights -> f16 hi/lo in MFMA fragment order + fp32 bias
// ---------------------------------------------------------------------------
#define BIH_PAIRS 24576    // (384/16)*(64/32)*512
#define BHH_PAIRS 49152    // 24*4*512
#define WCAT_PAIRS 131072  // 2*32*4*512
#define BCAT_N 1024

__device__ inline void h16split(float x, unsigned short& hi, unsigned short& lo) {
  union { _Float16 h; unsigned short s; } uh, ul;
  uh.h = (_Float16)x;
  ul.h = (_Float16)(x - (float)uh.h);
  hi = uh.s; lo = ul.s;
}

__global__ void pack_weights(
    const float* __restrict__ Wih, const float* __restrict__ Whh,
    const float* __restrict__ Wq, const float* __restrict__ Wk,
    const float* __restrict__ Wv, const float* __restrict__ Ws,
    const float* __restrict__ bq, const float* __restrict__ bk,
    const float* __restrict__ bv, const float* __restrict__ bs,
    unsigned short* __restrict__ BihP, unsigned short* __restrict__ BhhP,
    unsigned short* __restrict__ WcatP, float* __restrict__ bcat)
{
  int gid = blockIdx.x * 256 + threadIdx.x;
  if (gid < BIH_PAIRS) {  // K=64, N=384, ktiles=2
    int tile = gid >> 9, lj = gid & 511, lane = lj >> 3, j = lj & 7;
    int k_tile = tile & 1, n_tile = tile >> 1;
    int n = n_tile * 16 + (lane & 15);
    int k = k_tile * 32 + (lane >> 4) * 8 + j;
    unsigned short hi, lo;
    h16split(Wih[n * IND + k], hi, lo);   // B[k][n] = Wih^T
    BihP[tile * 1024 + lane * 8 + j] = hi;
    BihP[tile * 1024 + 512 + lane * 8 + j] = lo;
    return;
  }
  gid -= BIH_PAIRS;
  if (gid < BHH_PAIRS) {  // K=128, N=384, ktiles=4
    int tile = gid >> 9, lj = gid & 511, lane = lj >> 3, j = lj & 7;
    int k_tile = tile & 3, n_tile = tile >> 2;
    int n = n_tile * 16 + (lane & 15);
    int k = k_tile * 32 + (lane >> 4) * 8 + j;
    unsigned short hi, lo;
    h16split(Whh[n * DD + k], hi, lo);
    BhhP[tile * 1024 + lane * 8 + j] = hi;
    BhhP[tile * 1024 + 512 + lane * 8 + j] = lo;
    return;
  }
  gid -= BHH_PAIRS;
  if (gid < WCAT_PAIRS) {  // per layer: K=128, N=512, ktiles=4
    int l = gid >> 16, rem = gid & 65535;
    int tile = rem >> 9, lj = rem & 511, lane = lj >> 3, j = lj & 7;
    int k_tile = tile & 3, n_tile = tile >> 2;
    int n = n_tile * 16 + (lane & 15);
    int k = k_tile * 32 + (lane >> 4) * 8 + j;
    const float* W = (n < 128) ? Wq : (n < 256) ? Wk : (n < 384) ? Wv : Ws;
    unsigned short hi, lo;
    h16split(W[l * DD * DD + k * DD + (n & 127)], hi, lo);
    size_t base = (size_t)l * 131072 + tile * 1024;
    WcatP[base + lane * 8 + j] = hi;
    WcatP[base + 512 + lane * 8 + j] = lo;
    return;
  }
  gid -= WCAT_PAIRS;
  if (gid < BCAT_N) {
    int l = gid >> 9, n = gid & 511;
    const float* b = (n < 128) ? bq : (n < 256) ? bk : (n < 384) ? bv : bs;
    bcat[gid] = b[l * DD + (n & 127)];
  }
}

// ---------------------------------------------------------------------------
// x_seq -> fp16 single
// ---------------------------------------------------------------------------
__global__ void xcast(const float* __restrict__ x, unsigned short* __restrict__ xh)
{
  int i = blockIdx.x * 256 + threadIdx.x;   // exact T*NN*IND grid
  xh[i] = f2h_bits(x[i]);
}

// ---------------------------------------------------------------------------
// CSR build (by destination), per timestep; parallel 3-phase scan
// ---------------------------------------------------------------------------
#define SCHUNK 1024
#define NCHUNK 20          // ceil(20000/1024)

__global__ void csr_count(const int* __restrict__ ei, int* __restrict__ deg)
{
  int gid = blockIdx.x * 256 + threadIdx.x;
  if (gid >= T_STEPS * EE) return;
  int t = gid / EE, e = gid % EE;
  int dst = ei[(size_t)t * 2 * EE + EE + e];
  atomicAdd(&deg[t * NN + dst], 1);
}

__global__ void scan1(const int* __restrict__ deg, int* __restrict__ part)
{
  const int b = blockIdx.x;              // 0..T*NCHUNK-1
  const int t = b / NCHUNK, c = b % NCHUNK;
  const int tid = threadIdx.x;
  __shared__ int s[256];
  int base = c * SCHUNK + tid * 4;
  int sum = 0;
#pragma unroll
  for (int u = 0; u < 4; ++u) {
    int i = base + u;
    if (i < NN) sum += deg[t * NN + i];
  }
  s[tid] = sum;
  __syncthreads();
  for (int o = 128; o > 0; o >>= 1) {
    if (tid < o) s[tid] += s[tid + o];
    __syncthreads();
  }
  if (tid == 0) part[b] = s[0];
}

__global__ void scan2(int* __restrict__ part, int* __restrict__ offs)
{
  const int tid = threadIdx.x;
  __shared__ int s[T_STEPS * NCHUNK];
  if (tid < T_STEPS * NCHUNK) s[tid] = part[tid];
  __syncthreads();
  if (tid == 0) {
    for (int t = 0; t < T_STEPS; ++t) {
      int run = 0;
      for (int c = 0; c < NCHUNK; ++c) {
        int v = s[t * NCHUNK + c];
        s[t * NCHUNK + c] = run;
        run += v;
      }
      offs[t * (NN + 1) + NN] = run;
    }
  }
  __syncthreads();
  if (tid < T_STEPS * NCHUNK) part[tid] = s[tid];
}

__global__ void scan3(const int* __restrict__ deg, const int* __restrict__ part,
                      int* __restrict__ offs, int* __restrict__ cur)
{
  const int b = blockIdx.x;
  const int t = b / NCHUNK, c = b % NCHUNK;
  const int tid = threadIdx.x;
  __shared__ int s[256];
  int base = c * SCHUNK + tid * 4;
  int v[4]; int sum = 0;
#pragma unroll
  for (int u = 0; u < 4; ++u) {
    int i = base + u;
    v[u] = (i < NN) ? deg[t * NN + i] : 0;
    sum += v[u];
  }
  s[tid] = sum;
  __syncthreads();
  for (int o = 1; o < 256; o <<= 1) {
    int x = (tid >= o) ? s[tid - o] : 0;
    __syncthreads();
    s[tid] += x;
    __syncthreads();
  }
  int excl = part[b] + s[tid] - sum;
#pragma unroll
  for (int u = 0; u < 4; ++u) {
    int i = base + u;
    if (i < NN) {
      offs[t * (NN + 1) + i] = excl;
      cur[t * NN + i] = excl;
    }
    excl += v[u];
  }
}

// packed CSR entry: .x = src node, .y = edge_attr bits (one 8B store per edge)
__global__ void csr_fill(const int* __restrict__ ei, const float* __restrict__ ea,
                         int* __restrict__ cur, int2* __restrict__ cse)
{
  int gid = blockIdx.x * 256 + threadIdx.x;
  if (gid >= T_STEPS * EE) return;
  int t = gid / EE, e = gid % EE;
  int src = ei[(size_t)t * 2 * EE + e];
  int dst = ei[(size_t)t * 2 * EE + EE + e];
  int slot = atomicAdd(&cur[t * NN + dst], 1);
  cse[(size_t)t * EE + slot] = make_int2(src, __float_as_int(ea[(size_t)t * EE + e]));
}

// ---------------------------------------------------------------------------
// GRU gate fusion (all fp16 activations). t0: gh == b_hh exactly (h0=0).
// ---------------------------------------------------------------------------
__global__ __launch_bounds__(256) void gru_gate(
    const unsigned short* __restrict__ gi, const unsigned short* __restrict__ gh,
    const float* __restrict__ b_hh, int t0,
    const unsigned short* __restrict__ hprev, unsigned short* __restrict__ hout)
{
  int idx = blockIdx.x * 256 + threadIdx.x;   // exact NN*DD grid
  int n = idx >> 7, d = idx & 127;
  size_t gb = (size_t)n * G3 + d;
  float ir = h2f(gi[gb]), iz = h2f(gi[gb + DD]), inn = h2f(gi[gb + 2 * DD]);
  float hr, hz, hn, hp;
  if (t0) {
    hr = b_hh[d]; hz = b_hh[DD + d]; hn = b_hh[2 * DD + d]; hp = 0.f;
  } else {
    hr = h2f(gh[gb]); hz = h2f(gh[gb + DD]); hn = h2f(gh[gb + 2 * DD]);
    hp = h2f(hprev[idx]);
  }
  float r = 1.f / (1.f + __expf(-(ir + hr)));
  float z = 1.f / (1.f + __expf(-(iz + hz)));
  float nv = tanhf(inn + r * hn);
  float hnew = (1.f - z) * nv + z * hp;
  hout[idx] = f2h_bits(hnew);
}

// ---------------------------------------------------------------------------
// Fused TransformerConv (d=128), fp16 qkv, packed math (r10 proven).
// 1D grid, XCD-aware swizzle: t = (bid&7)>>1 so each XCD gathers one
// timestep's k/v. TWO nodes per wave: lane = half|es(2b)|fg(3b).
// No-max softmax + factored edge feature. fdot2 + v_pk_fma_f16.
// ---------------------------------------------------------------------------
__global__ __launch_bounds__(256) void attn_conv(
    const unsigned short* __restrict__ qkvh,  // [T][NN][512] fp16
    const int* __restrict__ offs4,    // [T][NN+1]
    const int2* __restrict__ cse4,    // [T][E]
    const float* __restrict__ We,     // [128] fp32
    unsigned short* __restrict__ hoh) // [T][NN][128] fp16 out
{
  const int bid = blockIdx.x;
  const int xc = bid & 7, jb = bid >> 3;
  const int t = xc >> 1;
  const int blk = jb * 2 + (xc & 1);          // 0..2499 within t
  const unsigned short* qk = qkvh + (size_t)t * NN * QS;
  const int* offs = offs4 + (size_t)t * (NN + 1);
  const int2* cse = cse4 + (size_t)t * EE;
  const int lane = threadIdx.x & 63;
  const int w = threadIdx.x >> 6;             // 4 waves/block
  const int hlf = lane >> 5;
  const int es = (lane >> 3) & 3;             // 4 edge slots
  const int fg = lane & 7;                    // 8 feature groups
  const int node = blk * 8 + w * 2 + hlf;     // exact 20000 per t
  const int f0 = fg * 16;
  const float scale = 0.08838834764831845f;   // 1/sqrt(128)

  union U16 { uint4 u[2]; half2v h[8]; };
  U16 q;
  {
    const uint4* p = (const uint4*)(qk + (size_t)node * QS + f0);
    q.u[0] = p[0]; q.u[1] = p[1];
  }
  half2v we2[8];
  {
    const float4* wp = (const float4*)&We[f0];
    float4 w0 = wp[0], w1 = wp[1], w2 = wp[2], w3 = wp[3];
    we2[0] = (half2v){(_Float16)w0.x, (_Float16)w0.y};
    we2[1] = (half2v){(_Float16)w0.z, (_Float16)w0.w};
    we2[2] = (half2v){(_Float16)w1.x, (_Float16)w1.y};
    we2[3] = (half2v){(_Float16)w1.z, (_Float16)w1.w};
    we2[4] = (half2v){(_Float16)w2.x, (_Float16)w2.y};
    we2[5] = (half2v){(_Float16)w2.z, (_Float16)w2.w};
    we2[6] = (half2v){(_Float16)w3.x, (_Float16)w3.y};
    we2[7] = (half2v){(_Float16)w3.z, (_Float16)w3.w};
  }
  float qwe = 0.f;
#pragma unroll
  for (int j = 0; j < 8; ++j) {
#if __has_builtin(__builtin_amdgcn_fdot2)
    qwe = __builtin_amdgcn_fdot2(q.h[j], we2[j], qwe, false);
#else
    qwe = fmaf((float)q.h[j].x, (float)we2[j].x, qwe);
    qwe = fmaf((float)q.h[j].y, (float)we2[j].y, qwe);
#endif
  }
  qwe += __shfl_xor(qwe, 1); qwe += __shfl_xor(qwe, 2); qwe += __shfl_xor(qwe, 4);

  const int e0 = offs[node], e1 = offs[node + 1];
  float l_lane = 0.f, sA_lane = 0.f;
  half2v acc2[8];
#pragma unroll
  for (int i = 0; i < 8; ++i) acc2[i] = (half2v){(_Float16)0.f, (_Float16)0.f};

  for (int base = e0; base < e1; base += 4) {
    const int eidx = base + es;
    const bool valid = eidx < e1;
    int2 se = valid ? cse[eidx] : make_int2(0, 0);
    const float a = __int_as_float(se.y);
    U16 kf;
    {
      const uint4* p = (const uint4*)(qk + (size_t)se.x * QS + 128 + f0);
      kf.u[0] = p[0]; kf.u[1] = p[1];
    }
    float p = 0.f;
#pragma unroll
    for (int j = 0; j < 8; ++j) {
#if __has_builtin(__builtin_amdgcn_fdot2)
      p = __builtin_amdgcn_fdot2(q.h[j], kf.h[j], p, false);
#else
      p = fmaf((float)q.h[j].x, (float)kf.h[j].x, p);
      p = fmaf((float)q.h[j].y, (float)kf.h[j].y, p);
#endif
    }
    p += __shfl_xor(p, 1); p += __shfl_xor(p, 2); p += __shfl_xor(p, 4);
    const float ex = valid ? __expf((p + a * qwe) * scale) : 0.f;
    l_lane += ex;
    sA_lane = fmaf(ex, a, sA_lane);
    const _Float16 exh = (_Float16)ex;
    const half2v ex2 = (half2v){exh, exh};
    U16 vf;
    {
      const uint4* p2 = (const uint4*)(qk + (size_t)se.x * QS + 256 + f0);
      vf.u[0] = p2[0]; vf.u[1] = p2[1];
    }
#pragma unroll
    for (int j = 0; j < 8; ++j)
      acc2[j] = ex2 * vf.h[j] + acc2[j];   // v_pk_fma_f16
  }
  // reductions over the 4 edge-slots (xor 8,16 stay within the 32-lane half)
  l_lane += __shfl_xor(l_lane, 8);  l_lane += __shfl_xor(l_lane, 16);
  sA_lane += __shfl_xor(sA_lane, 8); sA_lane += __shfl_xor(sA_lane, 16);
#pragma unroll
  for (int i = 0; i < 8; ++i) {
    acc2[i] = acc2[i] + shfl_xor_h2(acc2[i], 8);
    acc2[i] = acc2[i] + shfl_xor_h2(acc2[i], 16);
  }
  if (es != 0) return;
  const float inv = 1.f / (l_lane + 1e-16f);
  const float sAi = sA_lane * inv;
  U16 sk;
  {
    const uint4* p = (const uint4*)(qk + (size_t)node * QS + 384 + f0);
    sk.u[0] = p[0]; sk.u[1] = p[1];
  }
  float wf[16];
  {
    const float4* wp = (const float4*)&We[f0];
#pragma unroll
    for (int j = 0; j < 4; ++j) *(float4*)&wf[4 * j] = wp[j];
  }
  U16 outp;
#pragma unroll
  for (int j = 0; j < 8; ++j) {
    float oa = fmaf((float)acc2[j].x, inv, fmaf(sAi, wf[2 * j],     (float)sk.h[j].x));
    float ob = fmaf((float)acc2[j].y, inv, fmaf(sAi, wf[2 * j + 1], (float)sk.h[j].y));
    oa = (oa > 0.f) ? oa : 0.01f * oa;    // leaky_relu
    ob = (ob > 0.f) ? ob : 0.01f * ob;
    outp.h[j] = (half2v){(_Float16)oa, (_Float16)ob};
  }
  unsigned short* dst = hoh + ((size_t)t * NN + node) * DD + f0;
  *(uint4*)(dst + 0) = outp.u[0];
  *(uint4*)(dst + 8) = outp.u[1];
}

// ---------------------------------------------------------------------------
// mean over T from fp16; 2 elems per thread
// ---------------------------------------------------------------------------
__global__ void mean_k(const unsigned short* __restrict__ hb,
                       float* __restrict__ hm)
{
  int i = blockIdx.x * 256 + threadIdx.x;   // exact NN*DD/2 grid
  float vx = 0.f, vy = 0.f;
#pragma unroll
  for (int t = 0; t < T_STEPS; ++t) {
    union { unsigned u; half2v h; } c;
    c.u = *(const unsigned*)&hb[(size_t)t * NN * DD + 2 * i];
    vx += (float)c.h.x;
    vy += (float)c.h.y;
  }
  *(float2*)&hm[2 * i] = make_float2(0.25f * vx, 0.25f * vy);
}

// ---------------------------------------------------------------------------
__global__ __launch_bounds__(256) void out_proj(
    const float* __restrict__ h,
    const float* __restrict__ Wq, const float* __restrict__ Wk,
    const float* __restrict__ Wv, const float* __restrict__ Ws,
    const float* __restrict__ bq, const float* __restrict__ bk,
    const float* __restrict__ bv, const float* __restrict__ bs,
    float* __restrict__ q1, float* __restrict__ k1,
    float* __restrict__ v1, float* __restrict__ s1)
{
  const int wv = (blockIdx.x * 256 + threadIdx.x) >> 6;
  const int lane = threadIdx.x & 63;
  if (wv >= NN) return;
  float2 h2 = *(const float2*)&h[(size_t)wv * DD + 2 * lane];
  float pq = h2.x * Wq[2 * lane] + h2.y * Wq[2 * lane + 1];
  float pk = h2.x * Wk[2 * lane] + h2.y * Wk[2 * lane + 1];
  float pv = h2.x * Wv[2 * lane] + h2.y * Wv[2 * lane + 1];
  float ps = h2.x * Ws[2 * lane] + h2.y * Ws[2 * lane + 1];
#pragma unroll
  for (int o = 1; o < 64; o <<= 1) {
    pq += __shfl_xor(pq, o); pk += __shfl_xor(pk, o);
    pv += __shfl_xor(pv, o); ps += __shfl_xor(ps, o);
  }
  if (lane == 0) {
    q1[wv] = pq + bq[0]; k1[wv] = pk + bk[0];
    v1[wv] = pv + bv[0]; s1[wv] = ps + bs[0];
  }
}

__global__ void out_attn(
    const float* __restrict__ q1, const float* __restrict__ k1,
    const float* __restrict__ v1, const float* __restrict__ s1,
    const int* __restrict__ offs, const int2* __restrict__ cse,
    const float* __restrict__ We, float* __restrict__ out)
{
  int n = blockIdx.x * 256 + threadIdx.x;
  if (n >= NN) return;
  const float we = We[0];
  const float q = q1[n];
  const int e0 = offs[n], e1 = offs[n + 1];
  float m = -INFINITY;
  for (int e = e0; e < e1; ++e) {
    int2 se = cse[e];
    float al = q * (k1[se.x] + __int_as_float(se.y) * we);
    m = fmaxf(m, al);
  }
  float l = 0.f, acc = 0.f;
  for (int e = e0; e < e1; ++e) {
    int2 se = cse[e];
    float ca = __int_as_float(se.y);
    float al = q * (k1[se.x] + ca * we);
    float ex = __expf(al - m);
    l += ex;
    acc += ex * (v1[se.x] + ca * we);
  }
  out[n] = acc / (l + 1e-16f) + s1[n];
}

// ---------------------------------------------------------------------------
extern "C" void kernel_launch(void* const* d_in, const int* in_sizes, int n_in,
                              void* d_out, int out_size, void* d_ws, size_t ws_size,
                              hipStream_t stream)
{
  const float* x_seq = (const float*)d_in[0];
  const int*   ei    = (const int*)  d_in[1];
  const float* ea    = (const float*)d_in[2];
  const float* W_ih  = (const float*)d_in[3];
  const float* W_hh  = (const float*)d_in[4];
  const float* b_ih  = (const float*)d_in[5];
  const float* b_hh  = (const float*)d_in[6];
  const float* cWq   = (const float*)d_in[7];
  const float* cbq   = (const float*)d_in[8];
  const float* cWk   = (const float*)d_in[9];
  const float* cbk   = (const float*)d_in[10];
  const float* cWv   = (const float*)d_in[11];
  const float* cbv   = (const float*)d_in[12];
  const float* cWe   = (const float*)d_in[13];
  const float* cWs   = (const float*)d_in[14];
  const float* cbs   = (const float*)d_in[15];
  const float* oWq   = (const float*)d_in[16];
  const float* obq   = (const float*)d_in[17];
  const float* oWk   = (const float*)d_in[18];
  const float* obk   = (const float*)d_in[19];
  const float* oWv   = (const float*)d_in[20];
  const float* obv   = (const float*)d_in[21];
  const float* oWe   = (const float*)d_in[22];
  const float* oWs   = (const float*)d_in[23];
  const float* obs   = (const float*)d_in[24];
  float* out = (float*)d_out;

  char* ws = (char*)d_ws;
  size_t off = 0;
  auto alloc = [&](size_t bytes) -> char* {
    char* p = ws + off;
    off += (bytes + 255) & ~(size_t)255;
    return p;
  };
  // ---- total ~153 MB (<186 MB proven r2; r3's 289 MB aborted) ----
  unsigned short* BihP  = (unsigned short*)alloc((size_t)2 * BIH_PAIRS * 2);
  unsigned short* BhhP  = (unsigned short*)alloc((size_t)2 * BHH_PAIRS * 2);
  unsigned short* WcatP = (unsigned short*)alloc((size_t)2 * WCAT_PAIRS * 2);
  float* fbcat = (float*)alloc((size_t)BCAT_N * 4);
  unsigned short* xh    = (unsigned short*)alloc((size_t)T_STEPS * NN * IND * 2);
  unsigned short* hall  = (unsigned short*)alloc((size_t)T_STEPS * NN * DD * 2);
  float* fH    = (float*)alloc((size_t)NN * DD * 4);          // h_mean
  int*   iDeg  = (int*)  alloc((size_t)T_STEPS * NN * 4);     // zero-init
  int*   iCur  = (int*)  alloc((size_t)T_STEPS * NN * 4);
  int*   iOffs = (int*)  alloc((size_t)T_STEPS * (NN + 1) * 4);
  int*   iPart = (int*)  alloc((size_t)T_STEPS * NCHUNK * 4);
  int2*  iSE   = (int2*) alloc((size_t)T_STEPS * EE * 8);
  float* fQ1   = (float*)alloc((size_t)NN * 4);
  float* fK1   = (float*)alloc((size_t)NN * 4);
  float* fV1   = (float*)alloc((size_t)NN * 4);
  float* fS1   = (float*)alloc((size_t)NN * 4);
  // union: GRU phase gi2 [2NN*G3 fp16 = 30.7 MB] + gh [NN*G3 fp16 = 15.4 MB];
  //        conv phase qkvh [4NN*512 fp16 = 81.9 MB] + hoh [4NN*128 fp16 = 20.5 MB]
  size_t uniOff = off;
  unsigned short* gi2h = (unsigned short*)(ws + uniOff);
  unsigned short* ghh  = (unsigned short*)(ws + uniOff + (size_t)2 * NN * G3 * 2);
  unsigned short* qkvh = (unsigned short*)(ws + uniOff);
  unsigned short* hoh  = (unsigned short*)(ws + uniOff + (size_t)T_STEPS * NN * QS * 2);
  (void)ws_size; (void)in_sizes; (void)n_in; (void)out_size;

  auto gemm = [&](const unsigned short* A, const unsigned short* Bp,
                  const float* bias, unsigned short* Cb, int M, int N, int K) {
    int blocks = (((M >> 5) + 7) >> 3) * (N >> 7);
    gemm_f16<<<blocks, 512, 0, stream>>>(A, Bp, bias, Cb, M, N, K);
  };

  // weights + activation cast + CSR
  pack_weights<<<(BIH_PAIRS + BHH_PAIRS + WCAT_PAIRS + BCAT_N + 255) / 256, 256, 0,
                 stream>>>(W_ih, W_hh, cWq, cWk, cWv, cWs, cbq, cbk, cbv, cbs,
                           BihP, BhhP, WcatP, fbcat);
  xcast<<<(T_STEPS * NN * IND) / 256, 256, 0, stream>>>(x_seq, xh);
  hipMemsetAsync(iDeg, 0, (size_t)T_STEPS * NN * 4, stream);
  csr_count<<<(T_STEPS * EE) / 256, 256, 0, stream>>>(ei, iDeg);
  scan1<<<T_STEPS * NCHUNK, 256, 0, stream>>>(iDeg, iPart);
  scan2<<<1, 128, 0, stream>>>(iPart, iOffs);
  scan3<<<T_STEPS * NCHUNK, 256, 0, stream>>>(iDeg, iPart, iOffs, iCur);
  csr_fill<<<(T_STEPS * EE) / 256, 256, 0, stream>>>(ei, ea, iCur, iSE);

  // GRU over time: gi batched in pairs of t, gh sequential (t=0 skipped)
  for (int tp = 0; tp < 2; ++tp) {
    gemm(xh + (size_t)tp * 2 * NN * IND, BihP, b_ih, gi2h, 2 * NN, G3, IND);
    for (int k = 0; k < 2; ++k) {
      const int t = tp * 2 + k;
      const unsigned short* hprev = hall + (size_t)(t - 1) * NN * DD;  // unused t=0
      if (t > 0) gemm(hprev, BhhP, b_hh, ghh, NN, G3, DD);
      gru_gate<<<(NN * DD) / 256, 256, 0, stream>>>(
          gi2h + (size_t)k * NN * G3, ghh, b_hh, (t == 0) ? 1 : 0,
          (t == 0) ? hall : hprev, hall + (size_t)t * NN * DD);
    }
  }

  const int ATTN_BLOCKS = (NN / 8) * T_STEPS;   // 10000, 1D XCD-swizzled

  // Layer 1: h (fp16) -> qkvh ; attn -> hoh
  gemm(hall, WcatP, fbcat, qkvh, T_STEPS * NN, QS, DD);
  attn_conv<<<ATTN_BLOCKS, 256, 0, stream>>>(qkvh, iOffs, iSE, cWe, hoh);

  // Layer 2: hoh -> qkvh ; attn -> hoh (overwrite)
  gemm(hoh, WcatP + (size_t)131072, fbcat + QS, qkvh, T_STEPS * NN, QS, DD);
  attn_conv<<<ATTN_BLOCKS, 256, 0, stream>>>(qkvh, iOffs, iSE, cWe + DD, hoh);

  // mean over T (fp16 -> fp32)
  mean_k<<<(NN * DD / 2) / 256, 256, 0, stream>>>(hoh, fH);

  // output conv (d=1) on t=3 graph
  out_proj<<<(NN * 64) / 256, 256, 0, stream>>>(
      fH, oWq, oWk, oWv, oWs, obq, obk, obv, obs, fQ1, fK1, fV1, fS1);
  out_attn<<<(NN + 255) / 256, 256, 0, stream>>>(
      fQ1, fK1, fV1, fS1, iOffs + 3 * (NN + 1), iSE + (size_t)3 * EE, oWe, out);
}

// Round 12
// 424.707 us; speedup vs baseline: 2.2174x; 1.1651x over previous
//
#include <hip/hip_runtime.h>
#include <math.h>

#define T_STEPS 4
#define NN 20000
#define EE 160000
#define IND 64
#define DD 128
#define G3 384     // 3*D (GRU gates)
#define QS 512     // q|k|v|skip fused width
#define CAP 48     // padded-CSR capacity (max degree ~24; P(>=48) ~ 1e-25)

typedef _Float16 f16x8 __attribute__((ext_vector_type(8)));
typedef _Float16 half2v __attribute__((ext_vector_type(2)));
typedef float floatx4 __attribute__((ext_vector_type(4)));

// ---------------------------------------------------------------------------
// fp16 helpers
// ---------------------------------------------------------------------------
__device__ inline unsigned short f2h_bits(float x) {
  union { _Float16 h; unsigned short s; } u;
  u.h = (_Float16)x;   // v_cvt_f16_f32 (RNE)
  return u.s;
}
__device__ inline float h2f(unsigned short s) {
  union { unsigned short s; _Float16 h; } u;
  u.s = s;
  return (float)u.h;
}
__device__ inline half2v shfl_xor_h2(half2v v, int m) {
  union { half2v h; int i; } u; u.h = v;
  u.i = __shfl_xor(u.i, m);
  return u.h;
}

// ---------------------------------------------------------------------------
// f16 MFMA GEMM, LDS-staged single-f16 B: C = A x B + bias, fp16 out.
// B single fp16 (weight quant 2^-11 ~ activation error). Block = 512 thr
// (8 waves) sharing one 128-col group; B (<=32KB) staged once (r9-proven).
// 32-row wave tile; DO NOT enlarge (r6 spill).
// ---------------------------------------------------------------------------
__global__ __launch_bounds__(512) void gemm_f16(
    const unsigned short* __restrict__ A,
    const unsigned short* __restrict__ Bp, const float* __restrict__ bias,
    unsigned short* __restrict__ Cb, int M, int N, int K)
{
  __shared__ unsigned short Bs[16384];   // 32 KB (max ktiles=4)
  const int ngroups = N >> 7;
  const int mtiles = M >> 5;
  const int ng = blockIdx.x % ngroups;
  const int mb = blockIdx.x / ngroups;
  const int ktiles = K >> 5;
  const int tid = threadIdx.x;
  const unsigned short* Bsrc = Bp + (size_t)ng * 8 * ktiles * 512;
  const int nchunk = ktiles * 8 * 64;   // 16B chunks
  for (int i = tid; i < nchunk; i += 512)
    *(uint4*)&Bs[i * 8] = *(const uint4*)&Bsrc[i * 8];
  __syncthreads();
  const int w = tid >> 6;
  const int lane = tid & 63;
  const int mw = mb * 8 + w;
  if (mw >= mtiles) return;
  const int r = lane & 15, quad = lane >> 4;
  const unsigned short* a0 = A + (size_t)(mw * 32 + r) * K + quad * 8;
  const unsigned short* a1 = a0 + (size_t)16 * K;
  floatx4 acc[2][8];
#pragma unroll
  for (int m = 0; m < 2; ++m)
#pragma unroll
    for (int nt = 0; nt < 8; ++nt) acc[m][nt] = (floatx4){0.f, 0.f, 0.f, 0.f};
  for (int kt = 0; kt < ktiles; ++kt) {
    f16x8 af0 = *(const f16x8*)(a0 + kt * 32);
    f16x8 af1 = *(const f16x8*)(a1 + kt * 32);
#pragma unroll
    for (int nt = 0; nt < 8; ++nt) {
      f16x8 bf = *(const f16x8*)(Bs + (nt * ktiles + kt) * 512 + lane * 8);
      acc[0][nt] = __builtin_amdgcn_mfma_f32_16x16x32_f16(af0, bf, acc[0][nt], 0, 0, 0);
      acc[1][nt] = __builtin_amdgcn_mfma_f32_16x16x32_f16(af1, bf, acc[1][nt], 0, 0, 0);
    }
  }
#pragma unroll
  for (int m = 0; m < 2; ++m) {
    const int crow0 = mw * 32 + m * 16 + quad * 4;
#pragma unroll
    for (int nt = 0; nt < 8; ++nt) {
      const int col = ng * 128 + nt * 16 + r;
      const float b = bias[col];
#pragma unroll
      for (int i = 0; i < 4; ++i)
        Cb[(size_t)(crow0 + i) * N + col] = f2h_bits(acc[m][nt][i] + b);
    }
  }
}

// ---------------------------------------------------------------------------
// Weight packing: single f16 in MFMA fragment order + fp32 fused conv bias
// ---------------------------------------------------------------------------
#define BIH_N 24576    // (384/16)*(64/32)*512
#define BHH_N 49152    // 24*4*512
#define WCAT_N 131072  // 2*32*4*512
#define BCAT_N 1024

__global__ void pack_weights(
    const float* __restrict__ Wih, const float* __restrict__ Whh,
    const float* __restrict__ Wq, const float* __restrict__ Wk,
    const float* __restrict__ Wv, const float* __restrict__ Ws,
    const float* __restrict__ bq, const float* __restrict__ bk,
    const float* __restrict__ bv, const float* __restrict__ bs,
    unsigned short* __restrict__ BihP, unsigned short* __restrict__ BhhP,
    unsigned short* __restrict__ WcatP, float* __restrict__ bcat)
{
  int gid = blockIdx.x * 256 + threadIdx.x;
  if (gid < BIH_N) {  // K=64, N=384, ktiles=2
    int tile = gid >> 9, lj = gid & 511, lane = lj >> 3, j = lj & 7;
    int k_tile = tile & 1, n_tile = tile >> 1;
    int n = n_tile * 16 + (lane & 15);
    int k = k_tile * 32 + (lane >> 4) * 8 + j;
    BihP[tile * 512 + lane * 8 + j] = f2h_bits(Wih[n * IND + k]);  // B[k][n]=Wih^T
    return;
  }
  gid -= BIH_N;
  if (gid < BHH_N) {  // K=128, N=384, ktiles=4
    int tile = gid >> 9, lj = gid & 511, lane = lj >> 3, j = lj & 7;
    int k_tile = tile & 3, n_tile = tile >> 2;
    int n = n_tile * 16 + (lane & 15);
    int k = k_tile * 32 + (lane >> 4) * 8 + j;
    BhhP[tile * 512 + lane * 8 + j] = f2h_bits(Whh[n * DD + k]);
    return;
  }
  gid -= BHH_N;
  if (gid < WCAT_N) {  // per layer: K=128, N=512, ktiles=4
    int l = gid >> 16, rem = gid & 65535;
    int tile = rem >> 9, lj = rem & 511, lane = lj >> 3, j = lj & 7;
    int k_tile = tile & 3, n_tile = tile >> 2;
    int n = n_tile * 16 + (lane & 15);
    int k = k_tile * 32 + (lane >> 4) * 8 + j;
    const float* W = (n < 128) ? Wq : (n < 256) ? Wk : (n < 384) ? Wv : Ws;
    WcatP[(size_t)l * 65536 + tile * 512 + lane * 8 + j] =
        f2h_bits(W[l * DD * DD + k * DD + (n & 127)]);
    return;
  }
  gid -= WCAT_N;
  if (gid < BCAT_N) {
    int l = gid >> 9, n = gid & 511;
    const float* b = (n < 128) ? bq : (n < 256) ? bk : (n < 384) ? bv : bs;
    bcat[gid] = b[l * DD + (n & 127)];
  }
}

// ---------------------------------------------------------------------------
__global__ void xcast(const float* __restrict__ x, unsigned short* __restrict__ xh)
{
  int i = blockIdx.x * 256 + threadIdx.x;   // exact T*NN*IND grid
  xh[i] = f2h_bits(x[i]);
}

// ---------------------------------------------------------------------------
// Padded CSR build: ONE pass. slot = atomicAdd(deg[t][dst]); store into
// cse[(t*NN+dst)*CAP + slot]. Replaces count+3-phase-scan+fill (r11: ~5
// dispatches, ~50 µs). deg zero-initialized by memset.
// ---------------------------------------------------------------------------
__global__ void csr_fill(const int* __restrict__ ei, const float* __restrict__ ea,
                         int* __restrict__ deg, int2* __restrict__ cse)
{
  int gid = blockIdx.x * 256 + threadIdx.x;
  if (gid >= T_STEPS * EE) return;
  int t = gid / EE, e = gid % EE;
  int src = ei[(size_t)t * 2 * EE + e];
  int dst = ei[(size_t)t * 2 * EE + EE + e];
  int slot = atomicAdd(&deg[t * NN + dst], 1);
  cse[((size_t)t * NN + dst) * CAP + slot] =
      make_int2(src, __float_as_int(ea[(size_t)t * EE + e]));
}

// ---------------------------------------------------------------------------
// GRU gate fusion (all fp16 activations). t0: gh == b_hh exactly (h0=0).
// ---------------------------------------------------------------------------
__global__ __launch_bounds__(256) void gru_gate(
    const unsigned short* __restrict__ gi, const unsigned short* __restrict__ gh,
    const float* __restrict__ b_hh, int t0,
    const unsigned short* __restrict__ hprev, unsigned short* __restrict__ hout)
{
  int idx = blockIdx.x * 256 + threadIdx.x;   // exact NN*DD grid
  int n = idx >> 7, d = idx & 127;
  size_t gb = (size_t)n * G3 + d;
  float ir = h2f(gi[gb]), iz = h2f(gi[gb + DD]), inn = h2f(gi[gb + 2 * DD]);
  float hr, hz, hn, hp;
  if (t0) {
    hr = b_hh[d]; hz = b_hh[DD + d]; hn = b_hh[2 * DD + d]; hp = 0.f;
  } else {
    hr = h2f(gh[gb]); hz = h2f(gh[gb + DD]); hn = h2f(gh[gb + 2 * DD]);
    hp = h2f(hprev[idx]);
  }
  float r = 1.f / (1.f + __expf(-(ir + hr)));
  float z = 1.f / (1.f + __expf(-(iz + hz)));
  float nv = tanhf(inn + r * hn);
  float hnew = (1.f - z) * nv + z * hp;
  hout[idx] = f2h_bits(hnew);
}

// ---------------------------------------------------------------------------
// Fused TransformerConv (d=128), fp16 qkv, packed math, padded CSR.
// 1D grid, XCD-aware swizzle: t = (bid&7)>>1. TWO nodes per wave:
// lane = half|es(2b)|fg(3b). No-max softmax + factored edge feature
// (r7-verified). fdot2 + v_pk_fma_f16 (r10-proven).
// ---------------------------------------------------------------------------
__global__ __launch_bounds__(256) void attn_conv(
    const unsigned short* __restrict__ qkvh,  // [T][NN][512] fp16
    const int* __restrict__ deg4,     // [T][NN]
    const int2* __restrict__ cse4,    // [T][NN][CAP]
    const float* __restrict__ We,     // [128] fp32
    unsigned short* __restrict__ hoh) // [T][NN][128] fp16 out
{
  const int bid = blockIdx.x;
  const int xc = bid & 7, jb = bid >> 3;
  const int t = xc >> 1;
  const int blk = jb * 2 + (xc & 1);          // 0..2499 within t
  const unsigned short* qk = qkvh + (size_t)t * NN * QS;
  const int lane = threadIdx.x & 63;
  const int w = threadIdx.x >> 6;             // 4 waves/block
  const int hlf = lane >> 5;
  const int es = (lane >> 3) & 3;             // 4 edge slots
  const int fg = lane & 7;                    // 8 feature groups
  const int node = blk * 8 + w * 2 + hlf;     // exact 20000 per t
  const int f0 = fg * 16;
  const float scale = 0.08838834764831845f;   // 1/sqrt(128)

  union U16 { uint4 u[2]; half2v h[8]; };
  U16 q;
  {
    const uint4* p = (const uint4*)(qk + (size_t)node * QS + f0);
    q.u[0] = p[0]; q.u[1] = p[1];
  }
  half2v we2[8];
  {
    const float4* wp = (const float4*)&We[f0];
    float4 w0 = wp[0], w1 = wp[1], w2 = wp[2], w3 = wp[3];
    we2[0] = (half2v){(_Float16)w0.x, (_Float16)w0.y};
    we2[1] = (half2v){(_Float16)w0.z, (_Float16)w0.w};
    we2[2] = (half2v){(_Float16)w1.x, (_Float16)w1.y};
    we2[3] = (half2v){(_Float16)w1.z, (_Float16)w1.w};
    we2[4] = (half2v){(_Float16)w2.x, (_Float16)w2.y};
    we2[5] = (half2v){(_Float16)w2.z, (_Float16)w2.w};
    we2[6] = (half2v){(_Float16)w3.x, (_Float16)w3.y};
    we2[7] = (half2v){(_Float16)w3.z, (_Float16)w3.w};
  }
  float qwe = 0.f;
#pragma unroll
  for (int j = 0; j < 8; ++j) {
#if __has_builtin(__builtin_amdgcn_fdot2)
    qwe = __builtin_amdgcn_fdot2(q.h[j], we2[j], qwe, false);
#else
    qwe = fmaf((float)q.h[j].x, (float)we2[j].x, qwe);
    qwe = fmaf((float)q.h[j].y, (float)we2[j].y, qwe);
#endif
  }
  qwe += __shfl_xor(qwe, 1); qwe += __shfl_xor(qwe, 2); qwe += __shfl_xor(qwe, 4);

  const int dg = deg4[t * NN + node];
  const int2* cbase = cse4 + ((size_t)t * NN + node) * CAP;
  float l_lane = 0.f, sA_lane = 0.f;
  half2v acc2[8];
#pragma unroll
  for (int i = 0; i < 8; ++i) acc2[i] = (half2v){(_Float16)0.f, (_Float16)0.f};

  for (int base = 0; base < dg; base += 4) {
    const int eidx = base + es;
    const bool valid = eidx < dg;
    int2 se = valid ? cbase[eidx] : make_int2(0, 0);
    const float a = __int_as_float(se.y);
    U16 kf;
    {
      const uint4* p = (const uint4*)(qk + (size_t)se.x * QS + 128 + f0);
      kf.u[0] = p[0]; kf.u[1] = p[1];
    }
    float p = 0.f;
#pragma unroll
    for (int j = 0; j < 8; ++j) {
#if __has_builtin(__builtin_amdgcn_fdot2)
      p = __builtin_amdgcn_fdot2(q.h[j], kf.h[j], p, false);
#else
      p = fmaf((float)q.h[j].x, (float)kf.h[j].x, p);
      p = fmaf((float)q.h[j].y, (float)kf.h[j].y, p);
#endif
    }
    p += __shfl_xor(p, 1); p += __shfl_xor(p, 2); p += __shfl_xor(p, 4);
    const float ex = valid ? __expf((p + a * qwe) * scale) : 0.f;
    l_lane += ex;
    sA_lane = fmaf(ex, a, sA_lane);
    const _Float16 exh = (_Float16)ex;
    const half2v ex2 = (half2v){exh, exh};
    U16 vf;
    {
      const uint4* p2 = (const uint4*)(qk + (size_t)se.x * QS + 256 + f0);
      vf.u[0] = p2[0]; vf.u[1] = p2[1];
    }
#pragma unroll
    for (int j = 0; j < 8; ++j)
      acc2[j] = ex2 * vf.h[j] + acc2[j];   // v_pk_fma_f16
  }
  // reductions over the 4 edge-slots (xor 8,16 stay within the 32-lane half)
  l_lane += __shfl_xor(l_lane, 8);  l_lane += __shfl_xor(l_lane, 16);
  sA_lane += __shfl_xor(sA_lane, 8); sA_lane += __shfl_xor(sA_lane, 16);
#pragma unroll
  for (int i = 0; i < 8; ++i) {
    acc2[i] = acc2[i] + shfl_xor_h2(acc2[i], 8);
    acc2[i] = acc2[i] + shfl_xor_h2(acc2[i], 16);
  }
  if (es != 0) return;
  const float inv = 1.f / (l_lane + 1e-16f);
  const float sAi = sA_lane * inv;
  U16 sk;
  {
    const uint4* p = (const uint4*)(qk + (size_t)node * QS + 384 + f0);
    sk.u[0] = p[0]; sk.u[1] = p[1];
  }
  float wf[16];
  {
    const float4* wp = (const float4*)&We[f0];
#pragma unroll
    for (int j = 0; j < 4; ++j) *(float4*)&wf[4 * j] = wp[j];
  }
  U16 outp;
#pragma unroll
  for (int j = 0; j < 8; ++j) {
    float oa = fmaf((float)acc2[j].x, inv, fmaf(sAi, wf[2 * j],     (float)sk.h[j].x));
    float ob = fmaf((float)acc2[j].y, inv, fmaf(sAi, wf[2 * j + 1], (float)sk.h[j].y));
    oa = (oa > 0.f) ? oa : 0.01f * oa;    // leaky_relu
    ob = (ob > 0.f) ? ob : 0.01f * ob;
    outp.h[j] = (half2v){(_Float16)oa, (_Float16)ob};
  }
  unsigned short* dst = hoh + ((size_t)t * NN + node) * DD + f0;
  *(uint4*)(dst + 0) = outp.u[0];
  *(uint4*)(dst + 8) = outp.u[1];
}

// ---------------------------------------------------------------------------
// Output conv projections with fused mean-over-T (reads hoh fp16 directly)
// ---------------------------------------------------------------------------
__global__ __launch_bounds__(256) void out_proj(
    const unsigned short* __restrict__ hoh,   // [T][NN][128] fp16
    const float* __restrict__ Wq, const float* __restrict__ Wk,
    const float* __restrict__ Wv, const float* __restrict__ Ws,
    const float* __restrict__ bq, const float* __restrict__ bk,
    const float* __restrict__ bv, const float* __restrict__ bs,
    float* __restrict__ q1, float* __restrict__ k1,
    float* __restrict__ v1, float* __restrict__ s1)
{
  const int wv = (blockIdx.x * 256 + threadIdx.x) >> 6;
  const int lane = threadIdx.x & 63;
  if (wv >= NN) return;
  float hx = 0.f, hy = 0.f;
#pragma unroll
  for (int t = 0; t < T_STEPS; ++t) {
    union { unsigned u; half2v h; } c;
    c.u = *(const unsigned*)&hoh[((size_t)t * NN + wv) * DD + 2 * lane];
    hx += (float)c.h.x;
    hy += (float)c.h.y;
  }
  hx *= 0.25f; hy *= 0.25f;
  float pq = hx * Wq[2 * lane] + hy * Wq[2 * lane + 1];
  float pk = hx * Wk[2 * lane] + hy * Wk[2 * lane + 1];
  float pv = hx * Wv[2 * lane] + hy * Wv[2 * lane + 1];
  float ps = hx * Ws[2 * lane] + hy * Ws[2 * lane + 1];
#pragma unroll
  for (int o = 1; o < 64; o <<= 1) {
    pq += __shfl_xor(pq, o); pk += __shfl_xor(pk, o);
    pv += __shfl_xor(pv, o); ps += __shfl_xor(ps, o);
  }
  if (lane == 0) {
    q1[wv] = pq + bq[0]; k1[wv] = pk + bk[0];
    v1[wv] = pv + bv[0]; s1[wv] = ps + bs[0];
  }
}

__global__ void out_attn(
    const float* __restrict__ q1, const float* __restrict__ k1,
    const float* __restrict__ v1, const float* __restrict__ s1,
    const int* __restrict__ deg, const int2* __restrict__ cse,
    const float* __restrict__ We, float* __restrict__ out)
{
  int n = blockIdx.x * 256 + threadIdx.x;
  if (n >= NN) return;
  const float we = We[0];
  const float q = q1[n];
  const int dg = deg[n];
  const int2* cbase = cse + (size_t)n * CAP;
  float m = -INFINITY;
  for (int e = 0; e < dg; ++e) {
    int2 se = cbase[e];
    float al = q * (k1[se.x] + __int_as_float(se.y) * we);
    m = fmaxf(m, al);
  }
  float l = 0.f, acc = 0.f;
  for (int e = 0; e < dg; ++e) {
    int2 se = cbase[e];
    float ca = __int_as_float(se.y);
    float al = q * (k1[se.x] + ca * we);
    float ex = __expf(al - m);
    l += ex;
    acc += ex * (v1[se.x] + ca * we);
  }
  out[n] = acc / (l + 1e-16f) + s1[n];
}

// ---------------------------------------------------------------------------
extern "C" void kernel_launch(void* const* d_in, const int* in_sizes, int n_in,
                              void* d_out, int out_size, void* d_ws, size_t ws_size,
                              hipStream_t stream)
{
  const float* x_seq = (const float*)d_in[0];
  const int*   ei    = (const int*)  d_in[1];
  const float* ea    = (const float*)d_in[2];
  const float* W_ih  = (const float*)d_in[3];
  const float* W_hh  = (const float*)d_in[4];
  const float* b_ih  = (const float*)d_in[5];
  const float* b_hh  = (const float*)d_in[6];
  const float* cWq   = (const float*)d_in[7];
  const float* cbq   = (const float*)d_in[8];
  const float* cWk   = (const float*)d_in[9];
  const float* cbk   = (const float*)d_in[10];
  const float* cWv   = (const float*)d_in[11];
  const float* cbv   = (const float*)d_in[12];
  const float* cWe   = (const float*)d_in[13];
  const float* cWs   = (const float*)d_in[14];
  const float* cbs   = (const float*)d_in[15];
  const float* oWq   = (const float*)d_in[16];
  const float* obq   = (const float*)d_in[17];
  const float* oWk   = (const float*)d_in[18];
  const float* obk   = (const float*)d_in[19];
  const float* oWv   = (const float*)d_in[20];
  const float* obv   = (const float*)d_in[21];
  const float* oWe   = (const float*)d_in[22];
  const float* oWs   = (const float*)d_in[23];
  const float* obs   = (const float*)d_in[24];
  float* out = (float*)d_out;

  char* ws = (char*)d_ws;
  size_t off = 0;
  auto alloc = [&](size_t bytes) -> char* {
    char* p = ws + off;
    off += (bytes + 255) & ~(size_t)255;
    return p;
  };
  // ---- total ~165 MB (<186 MB proven r2; r3's 289 MB aborted) ----
  unsigned short* BihP  = (unsigned short*)alloc((size_t)BIH_N * 2);
  unsigned short* BhhP  = (unsigned short*)alloc((size_t)BHH_N * 2);
  unsigned short* WcatP = (unsigned short*)alloc((size_t)WCAT_N * 2);
  float* fbcat = (float*)alloc((size_t)BCAT_N * 4);
  unsigned short* xh    = (unsigned short*)alloc((size_t)T_STEPS * NN * IND * 2);
  unsigned short* hall  = (unsigned short*)alloc((size_t)T_STEPS * NN * DD * 2);
  int*   iDeg  = (int*)  alloc((size_t)T_STEPS * NN * 4);     // zero-init
  int2*  iSE   = (int2*) alloc((size_t)T_STEPS * NN * CAP * 8);  // padded CSR
  float* fQ1   = (float*)alloc((size_t)NN * 4);
  float* fK1   = (float*)alloc((size_t)NN * 4);
  float* fV1   = (float*)alloc((size_t)NN * 4);
  float* fS1   = (float*)alloc((size_t)NN * 4);
  // union: GRU phase gi2 [2NN*G3 fp16 = 30.7 MB] + gh [NN*G3 fp16 = 15.4 MB];
  //        conv phase qkvh [4NN*512 fp16 = 81.9 MB] + hoh [4NN*128 fp16 = 20.5 MB]
  size_t uniOff = off;
  unsigned short* gi2h = (unsigned short*)(ws + uniOff);
  unsigned short* ghh  = (unsigned short*)(ws + uniOff + (size_t)2 * NN * G3 * 2);
  unsigned short* qkvh = (unsigned short*)(ws + uniOff);
  unsigned short* hoh  = (unsigned short*)(ws + uniOff + (size_t)T_STEPS * NN * QS * 2);
  (void)ws_size; (void)in_sizes; (void)n_in; (void)out_size;

  auto gemm = [&](const unsigned short* A, const unsigned short* Bp,
                  const float* bias, unsigned short* Cb, int M, int N, int K) {
    int blocks = (((M >> 5) + 7) >> 3) * (N >> 7);
    gemm_f16<<<blocks, 512, 0, stream>>>(A, Bp, bias, Cb, M, N, K);
  };

  // weights + activation cast + padded CSR (single pass)
  pack_weights<<<(BIH_N + BHH_N + WCAT_N + BCAT_N + 255) / 256, 256, 0,
                 stream>>>(W_ih, W_hh, cWq, cWk, cWv, cWs, cbq, cbk, cbv, cbs,
                           BihP, BhhP, WcatP, fbcat);
  xcast<<<(T_STEPS * NN * IND) / 256, 256, 0, stream>>>(x_seq, xh);
  hipMemsetAsync(iDeg, 0, (size_t)T_STEPS * NN * 4, stream);
  csr_fill<<<(T_STEPS * EE) / 256, 256, 0, stream>>>(ei, ea, iDeg, iSE);

  // GRU over time: gi batched in pairs of t, gh sequential (t=0 skipped)
  for (int tp = 0; tp < 2; ++tp) {
    gemm(xh + (size_t)tp * 2 * NN * IND, BihP, b_ih, gi2h, 2 * NN, G3, IND);
    for (int k = 0; k < 2; ++k) {
      const int t = tp * 2 + k;
      const unsigned short* hprev = hall + (size_t)(t - 1) * NN * DD;  // unused t=0
      if (t > 0) gemm(hprev, BhhP, b_hh, ghh, NN, G3, DD);
      gru_gate<<<(NN * DD) / 256, 256, 0, stream>>>(
          gi2h + (size_t)k * NN * G3, ghh, b_hh, (t == 0) ? 1 : 0,
          (t == 0) ? hall : hprev, hall + (size_t)t * NN * DD);
    }
  }

  const int ATTN_BLOCKS = (NN / 8) * T_STEPS;   // 10000, 1D XCD-swizzled

  // Layer 1: h (fp16) -> qkvh ; attn -> hoh
  gemm(hall, WcatP, fbcat, qkvh, T_STEPS * NN, QS, DD);
  attn_conv<<<ATTN_BLOCKS, 256, 0, stream>>>(qkvh, iDeg, iSE, cWe, hoh);

  // Layer 2: hoh -> qkvh ; attn -> hoh (overwrite)
  gemm(hoh, WcatP + (size_t)65536, fbcat + QS, qkvh, T_STEPS * NN, QS, DD);
  attn_conv<<<ATTN_BLOCKS, 256, 0, stream>>>(qkvh, iDeg, iSE, cWe + DD, hoh);

  // output conv (d=1) on t=3 graph; mean-over-T fused into out_proj
  out_proj<<<(NN * 64) / 256, 256, 0, stream>>>(
      hoh, oWq, oWk, oWv, oWs, obq, obk, obv, obs, fQ1, fK1, fV1, fS1);
  out_attn<<<(NN + 255) / 256, 256, 0, stream>>>(
      fQ1, fK1, fV1, fS1, iDeg + 3 * NN, iSE + (size_t)3 * NN * CAP, oWe, out);
}

// Round 13
// 422.413 us; speedup vs baseline: 2.2294x; 1.0054x over previous
//
#include <hip/hip_runtime.h>
#include <math.h>

#define T_STEPS 4
#define NN 20000
#define EE 160000
#define IND 64
#define DD 128
#define G3 384     // 3*D (GRU gates)
#define QS 512     // q|k|v|skip fused width
#define CAP 48     // padded-CSR capacity (max degree ~24; P(>=48) ~ 1e-25)

typedef _Float16 f16x8 __attribute__((ext_vector_type(8)));
typedef _Float16 half2v __attribute__((ext_vector_type(2)));
typedef float floatx4 __attribute__((ext_vector_type(4)));

// ---------------------------------------------------------------------------
// fp16 helpers
// ---------------------------------------------------------------------------
__device__ inline unsigned short f2h_bits(float x) {
  union { _Float16 h; unsigned short s; } u;
  u.h = (_Float16)x;   // v_cvt_f16_f32 (RNE)
  return u.s;
}
__device__ inline float h2f(unsigned short s) {
  union { unsigned short s; _Float16 h; } u;
  u.s = s;
  return (float)u.h;
}
__device__ inline half2v shfl_xor_h2(half2v v, int m) {
  union { half2v h; int i; } u; u.h = v;
  u.i = __shfl_xor(u.i, m);
  return u.h;
}

// ---------------------------------------------------------------------------
// f16 MFMA GEMM, LDS-staged single-f16 B: C = A x B + bias, fp16 out.
// Block = 512 thr (8 waves) sharing one 128-col group; B (<=32KB) staged
// once (r9-proven). 32-row wave tile; DO NOT enlarge (r6 spill).
// ---------------------------------------------------------------------------
__global__ __launch_bounds__(512) void gemm_f16(
    const unsigned short* __restrict__ A,
    const unsigned short* __restrict__ Bp, const float* __restrict__ bias,
    unsigned short* __restrict__ Cb, int M, int N, int K)
{
  __shared__ unsigned short Bs[16384];   // 32 KB (max ktiles=4)
  const int ngroups = N >> 7;
  const int mtiles = M >> 5;
  const int ng = blockIdx.x % ngroups;
  const int mb = blockIdx.x / ngroups;
  const int ktiles = K >> 5;
  const int tid = threadIdx.x;
  const unsigned short* Bsrc = Bp + (size_t)ng * 8 * ktiles * 512;
  const int nchunk = ktiles * 8 * 64;   // 16B chunks
  for (int i = tid; i < nchunk; i += 512)
    *(uint4*)&Bs[i * 8] = *(const uint4*)&Bsrc[i * 8];
  __syncthreads();
  const int w = tid >> 6;
  const int lane = tid & 63;
  const int mw = mb * 8 + w;
  if (mw >= mtiles) return;
  const int r = lane & 15, quad = lane >> 4;
  const unsigned short* a0 = A + (size_t)(mw * 32 + r) * K + quad * 8;
  const unsigned short* a1 = a0 + (size_t)16 * K;
  floatx4 acc[2][8];
#pragma unroll
  for (int m = 0; m < 2; ++m)
#pragma unroll
    for (int nt = 0; nt < 8; ++nt) acc[m][nt] = (floatx4){0.f, 0.f, 0.f, 0.f};
  for (int kt = 0; kt < ktiles; ++kt) {
    f16x8 af0 = *(const f16x8*)(a0 + kt * 32);
    f16x8 af1 = *(const f16x8*)(a1 + kt * 32);
#pragma unroll
    for (int nt = 0; nt < 8; ++nt) {
      f16x8 bf = *(const f16x8*)(Bs + (nt * ktiles + kt) * 512 + lane * 8);
      acc[0][nt] = __builtin_amdgcn_mfma_f32_16x16x32_f16(af0, bf, acc[0][nt], 0, 0, 0);
      acc[1][nt] = __builtin_amdgcn_mfma_f32_16x16x32_f16(af1, bf, acc[1][nt], 0, 0, 0);
    }
  }
#pragma unroll
  for (int m = 0; m < 2; ++m) {
    const int crow0 = mw * 32 + m * 16 + quad * 4;
#pragma unroll
    for (int nt = 0; nt < 8; ++nt) {
      const int col = ng * 128 + nt * 16 + r;
      const float b = bias[col];
#pragma unroll
      for (int i = 0; i < 4; ++i)
        Cb[(size_t)(crow0 + i) * N + col] = f2h_bits(acc[m][nt][i] + b);
    }
  }
}

// ---------------------------------------------------------------------------
// Weight packing: single f16 in MFMA fragment order + fp32 fused conv bias
// ---------------------------------------------------------------------------
#define BIH_N 24576    // (384/16)*(64/32)*512
#define BHH_N 49152    // 24*4*512
#define WCAT_N 131072  // 2*32*4*512
#define BCAT_N 1024

__global__ void pack_weights(
    const float* __restrict__ Wih, const float* __restrict__ Whh,
    const float* __restrict__ Wq, const float* __restrict__ Wk,
    const float* __restrict__ Wv, const float* __restrict__ Ws,
    const float* __restrict__ bq, const float* __restrict__ bk,
    const float* __restrict__ bv, const float* __restrict__ bs,
    unsigned short* __restrict__ BihP, unsigned short* __restrict__ BhhP,
    unsigned short* __restrict__ WcatP, float* __restrict__ bcat)
{
  int gid = blockIdx.x * 256 + threadIdx.x;
  if (gid < BIH_N) {  // K=64, N=384, ktiles=2
    int tile = gid >> 9, lj = gid & 511, lane = lj >> 3, j = lj & 7;
    int k_tile = tile & 1, n_tile = tile >> 1;
    int n = n_tile * 16 + (lane & 15);
    int k = k_tile * 32 + (lane >> 4) * 8 + j;
    BihP[tile * 512 + lane * 8 + j] = f2h_bits(Wih[n * IND + k]);  // B[k][n]=Wih^T
    return;
  }
  gid -= BIH_N;
  if (gid < BHH_N) {  // K=128, N=384, ktiles=4
    int tile = gid >> 9, lj = gid & 511, lane = lj >> 3, j = lj & 7;
    int k_tile = tile & 3, n_tile = tile >> 2;
    int n = n_tile * 16 + (lane & 15);
    int k = k_tile * 32 + (lane >> 4) * 8 + j;
    BhhP[tile * 512 + lane * 8 + j] = f2h_bits(Whh[n * DD + k]);
    return;
  }
  gid -= BHH_N;
  if (gid < WCAT_N) {  // per layer: K=128, N=512, ktiles=4
    int l = gid >> 16, rem = gid & 65535;
    int tile = rem >> 9, lj = rem & 511, lane = lj >> 3, j = lj & 7;
    int k_tile = tile & 3, n_tile = tile >> 2;
    int n = n_tile * 16 + (lane & 15);
    int k = k_tile * 32 + (lane >> 4) * 8 + j;
    const float* W = (n < 128) ? Wq : (n < 256) ? Wk : (n < 384) ? Wv : Ws;
    WcatP[(size_t)l * 65536 + tile * 512 + lane * 8 + j] =
        f2h_bits(W[l * DD * DD + k * DD + (n & 127)]);
    return;
  }
  gid -= WCAT_N;
  if (gid < BCAT_N) {
    int l = gid >> 9, n = gid & 511;
    const float* b = (n < 128) ? bq : (n < 256) ? bk : (n < 384) ? bv : bs;
    bcat[gid] = b[l * DD + (n & 127)];
  }
}

// ---------------------------------------------------------------------------
__global__ void xcast(const float* __restrict__ x, unsigned short* __restrict__ xh)
{
  int i = blockIdx.x * 256 + threadIdx.x;   // exact T*NN*IND grid
  xh[i] = f2h_bits(x[i]);
}

// ---------------------------------------------------------------------------
// Padded CSR build: ONE pass (r12-proven).
// ---------------------------------------------------------------------------
__global__ void csr_fill(const int* __restrict__ ei, const float* __restrict__ ea,
                         int* __restrict__ deg, int2* __restrict__ cse)
{
  int gid = blockIdx.x * 256 + threadIdx.x;
  if (gid >= T_STEPS * EE) return;
  int t = gid / EE, e = gid % EE;
  int src = ei[(size_t)t * 2 * EE + e];
  int dst = ei[(size_t)t * 2 * EE + EE + e];
  int slot = atomicAdd(&deg[t * NN + dst], 1);
  cse[((size_t)t * NN + dst) * CAP + slot] =
      make_int2(src, __float_as_int(ea[(size_t)t * EE + e]));
}

// ---------------------------------------------------------------------------
// GRU gate fusion (all fp16 activations). t0: gh == b_hh exactly (h0=0).
// ---------------------------------------------------------------------------
__global__ __launch_bounds__(256) void gru_gate(
    const unsigned short* __restrict__ gi, const unsigned short* __restrict__ gh,
    const float* __restrict__ b_hh, int t0,
    const unsigned short* __restrict__ hprev, unsigned short* __restrict__ hout)
{
  int idx = blockIdx.x * 256 + threadIdx.x;   // exact NN*DD grid
  int n = idx >> 7, d = idx & 127;
  size_t gb = (size_t)n * G3 + d;
  float ir = h2f(gi[gb]), iz = h2f(gi[gb + DD]), inn = h2f(gi[gb + 2 * DD]);
  float hr, hz, hn, hp;
  if (t0) {
    hr = b_hh[d]; hz = b_hh[DD + d]; hn = b_hh[2 * DD + d]; hp = 0.f;
  } else {
    hr = h2f(gh[gb]); hz = h2f(gh[gb + DD]); hn = h2f(gh[gb + 2 * DD]);
    hp = h2f(hprev[idx]);
  }
  float r = 1.f / (1.f + __expf(-(ir + hr)));
  float z = 1.f / (1.f + __expf(-(iz + hz)));
  float nv = tanhf(inn + r * hn);
  float hnew = (1.f - z) * nv + z * hp;
  hout[idx] = f2h_bits(hnew);
}

// ---------------------------------------------------------------------------
// Fused TransformerConv (d=128), fp16 qkv, packed math, padded CSR.
// 8-EDGE-WIDE BODY: 2 edges per es lane per iteration, both masked.
// No-max softmax means no loop-carried rescale -> both k-loads issue before
// either dot (2x memory-level parallelism); deg<=8 nodes run ONE iteration.
// 1D grid, XCD-aware swizzle: t = (bid&7)>>1. TWO nodes per wave.
// ---------------------------------------------------------------------------
__global__ __launch_bounds__(256) void attn_conv(
    const unsigned short* __restrict__ qkvh,  // [T][NN][512] fp16
    const int* __restrict__ deg4,     // [T][NN]
    const int2* __restrict__ cse4,    // [T][NN][CAP]
    const float* __restrict__ We,     // [128] fp32
    unsigned short* __restrict__ hoh) // [T][NN][128] fp16 out
{
  const int bid = blockIdx.x;
  const int xc = bid & 7, jb = bid >> 3;
  const int t = xc >> 1;
  const int blk = jb * 2 + (xc & 1);          // 0..2499 within t
  const unsigned short* qk = qkvh + (size_t)t * NN * QS;
  const int lane = threadIdx.x & 63;
  const int w = threadIdx.x >> 6;             // 4 waves/block
  const int hlf = lane >> 5;
  const int es = (lane >> 3) & 3;             // 4 edge slots
  const int fg = lane & 7;                    // 8 feature groups
  const int node = blk * 8 + w * 2 + hlf;     // exact 20000 per t
  const int f0 = fg * 16;
  const float scale = 0.08838834764831845f;   // 1/sqrt(128)

  union U16 { uint4 u[2]; half2v h[8]; };
  U16 q;
  {
    const uint4* p = (const uint4*)(qk + (size_t)node * QS + f0);
    q.u[0] = p[0]; q.u[1] = p[1];
  }
  half2v we2[8];
  {
    const float4* wp = (const float4*)&We[f0];
    float4 w0 = wp[0], w1 = wp[1], w2 = wp[2], w3 = wp[3];
    we2[0] = (half2v){(_Float16)w0.x, (_Float16)w0.y};
    we2[1] = (half2v){(_Float16)w0.z, (_Float16)w0.w};
    we2[2] = (half2v){(_Float16)w1.x, (_Float16)w1.y};
    we2[3] = (half2v){(_Float16)w1.z, (_Float16)w1.w};
    we2[4] = (half2v){(_Float16)w2.x, (_Float16)w2.y};
    we2[5] = (half2v){(_Float16)w2.z, (_Float16)w2.w};
    we2[6] = (half2v){(_Float16)w3.x, (_Float16)w3.y};
    we2[7] = (half2v){(_Float16)w3.z, (_Float16)w3.w};
  }
  float qwe = 0.f;
#pragma unroll
  for (int j = 0; j < 8; ++j) {
#if __has_builtin(__builtin_amdgcn_fdot2)
    qwe = __builtin_amdgcn_fdot2(q.h[j], we2[j], qwe, false);
#else
    qwe = fmaf((float)q.h[j].x, (float)we2[j].x, qwe);
    qwe = fmaf((float)q.h[j].y, (float)we2[j].y, qwe);
#endif
  }
  qwe += __shfl_xor(qwe, 1); qwe += __shfl_xor(qwe, 2); qwe += __shfl_xor(qwe, 4);

  const int dg = deg4[t * NN + node];
  const int2* cbase = cse4 + ((size_t)t * NN + node) * CAP;
  float l_lane = 0.f, sA_lane = 0.f;
  half2v acc2[8];
#pragma unroll
  for (int i = 0; i < 8; ++i) acc2[i] = (half2v){(_Float16)0.f, (_Float16)0.f};

  for (int base = 0; base < dg; base += 8) {
    const int e0i = base + es;
    const int e1i = base + 4 + es;
    const bool ok0 = e0i < dg;
    const bool ok1 = e1i < dg;
    int2 se0 = ok0 ? cbase[e0i] : make_int2(0, 0);
    int2 se1 = ok1 ? cbase[e1i] : make_int2(0, 0);
    const float a0 = __int_as_float(se0.y);
    const float a1 = __int_as_float(se1.y);
    U16 kf0, kf1;
    {
      const uint4* p0 = (const uint4*)(qk + (size_t)se0.x * QS + 128 + f0);
      const uint4* p1 = (const uint4*)(qk + (size_t)se1.x * QS + 128 + f0);
      kf0.u[0] = p0[0]; kf0.u[1] = p0[1];
      kf1.u[0] = p1[0]; kf1.u[1] = p1[1];
    }
    float p0 = 0.f, p1 = 0.f;
#pragma unroll
    for (int j = 0; j < 8; ++j) {
#if __has_builtin(__builtin_amdgcn_fdot2)
      p0 = __builtin_amdgcn_fdot2(q.h[j], kf0.h[j], p0, false);
      p1 = __builtin_amdgcn_fdot2(q.h[j], kf1.h[j], p1, false);
#else
      p0 = fmaf((float)q.h[j].x, (float)kf0.h[j].x, p0);
      p0 = fmaf((float)q.h[j].y, (float)kf0.h[j].y, p0);
      p1 = fmaf((float)q.h[j].x, (float)kf1.h[j].x, p1);
      p1 = fmaf((float)q.h[j].y, (float)kf1.h[j].y, p1);
#endif
    }
    p0 += __shfl_xor(p0, 1); p1 += __shfl_xor(p1, 1);
    p0 += __shfl_xor(p0, 2); p1 += __shfl_xor(p1, 2);
    p0 += __shfl_xor(p0, 4); p1 += __shfl_xor(p1, 4);
    const float ex0 = ok0 ? __expf((p0 + a0 * qwe) * scale) : 0.f;
    const float ex1 = ok1 ? __expf((p1 + a1 * qwe) * scale) : 0.f;
    l_lane += ex0 + ex1;
    sA_lane = fmaf(ex0, a0, sA_lane);
    sA_lane = fmaf(ex1, a1, sA_lane);
    U16 vf0, vf1;
    {
      const uint4* p0v = (const uint4*)(qk + (size_t)se0.x * QS + 256 + f0);
      const uint4* p1v = (const uint4*)(qk + (size_t)se1.x * QS + 256 + f0);
      vf0.u[0] = p0v[0]; vf0.u[1] = p0v[1];
      vf1.u[0] = p1v[0]; vf1.u[1] = p1v[1];
    }
    const _Float16 eh0 = (_Float16)ex0, eh1 = (_Float16)ex1;
    const half2v e02 = (half2v){eh0, eh0};
    const half2v e12 = (half2v){eh1, eh1};
#pragma unroll
    for (int j = 0; j < 8; ++j) {
      acc2[j] = e02 * vf0.h[j] + acc2[j];   // v_pk_fma_f16
      acc2[j] = e12 * vf1.h[j] + acc2[j];
    }
  }
  // reductions over the 4 edge-slots (xor 8,16 stay within the 32-lane half)
  l_lane += __shfl_xor(l_lane, 8);  l_lane += __shfl_xor(l_lane, 16);
  sA_lane += __shfl_xor(sA_lane, 8); sA_lane += __shfl_xor(sA_lane, 16);
#pragma unroll
  for (int i = 0; i < 8; ++i) {
    acc2[i] = acc2[i] + shfl_xor_h2(acc2[i], 8);
    acc2[i] = acc2[i] + shfl_xor_h2(acc2[i], 16);
  }
  if (es != 0) return;
  const float inv = 1.f / (l_lane + 1e-16f);
  const float sAi = sA_lane * inv;
  U16 sk;
  {
    const uint4* p = (const uint4*)(qk + (size_t)node * QS + 384 + f0);
    sk.u[0] = p[0]; sk.u[1] = p[1];
  }
  float wf[16];
  {
    const float4* wp = (const float4*)&We[f0];
#pragma unroll
    for (int j = 0; j < 4; ++j) *(float4*)&wf[4 * j] = wp[j];
  }
  U16 outp;
#pragma unroll
  for (int j = 0; j < 8; ++j) {
    float oa = fmaf((float)acc2[j].x, inv, fmaf(sAi, wf[2 * j],     (float)sk.h[j].x));
    float ob = fmaf((float)acc2[j].y, inv, fmaf(sAi, wf[2 * j + 1], (float)sk.h[j].y));
    oa = (oa > 0.f) ? oa : 0.01f * oa;    // leaky_relu
    ob = (ob > 0.f) ? ob : 0.01f * ob;
    outp.h[j] = (half2v){(_Float16)oa, (_Float16)ob};
  }
  unsigned short* dst = hoh + ((size_t)t * NN + node) * DD + f0;
  *(uint4*)(dst + 0) = outp.u[0];
  *(uint4*)(dst + 8) = outp.u[1];
}

// ---------------------------------------------------------------------------
// Output conv projections with fused mean-over-T (reads hoh fp16 directly)
// ---------------------------------------------------------------------------
__global__ __launch_bounds__(256) void out_proj(
    const unsigned short* __restrict__ hoh,   // [T][NN][128] fp16
    const float* __restrict__ Wq, const float* __restrict__ Wk,
    const float* __restrict__ Wv, const float* __restrict__ Ws,
    const float* __restrict__ bq, const float* __restrict__ bk,
    const float* __restrict__ bv, const float* __restrict__ bs,
    float* __restrict__ q1, float* __restrict__ k1,
    float* __restrict__ v1, float* __restrict__ s1)
{
  const int wv = (blockIdx.x * 256 + threadIdx.x) >> 6;
  const int lane = threadIdx.x & 63;
  if (wv >= NN) return;
  float hx = 0.f, hy = 0.f;
#pragma unroll
  for (int t = 0; t < T_STEPS; ++t) {
    union { unsigned u; half2v h; } c;
    c.u = *(const unsigned*)&hoh[((size_t)t * NN + wv) * DD + 2 * lane];
    hx += (float)c.h.x;
    hy += (float)c.h.y;
  }
  hx *= 0.25f; hy *= 0.25f;
  float pq = hx * Wq[2 * lane] + hy * Wq[2 * lane + 1];
  float pk = hx * Wk[2 * lane] + hy * Wk[2 * lane + 1];
  float pv = hx * Wv[2 * lane] + hy * Wv[2 * lane + 1];
  float ps = hx * Ws[2 * lane] + hy * Ws[2 * lane + 1];
#pragma unroll
  for (int o = 1; o < 64; o <<= 1) {
    pq += __shfl_xor(pq, o); pk += __shfl_xor(pk, o);
    pv += __shfl_xor(pv, o); ps += __shfl_xor(ps, o);
  }
  if (lane == 0) {
    q1[wv] = pq + bq[0]; k1[wv] = pk + bk[0];
    v1[wv] = pv + bv[0]; s1[wv] = ps + bs[0];
  }
}

__global__ void out_attn(
    const float* __restrict__ q1, const float* __restrict__ k1,
    const float* __restrict__ v1, const float* __restrict__ s1,
    const int* __restrict__ deg, const int2* __restrict__ cse,
    const float* __restrict__ We, float* __restrict__ out)
{
  int n = blockIdx.x * 256 + threadIdx.x;
  if (n >= NN) return;
  const float we = We[0];
  const float q = q1[n];
  const int dg = deg[n];
  const int2* cbase = cse + (size_t)n * CAP;
  float m = -INFINITY;
  for (int e = 0; e < dg; ++e) {
    int2 se = cbase[e];
    float al = q * (k1[se.x] + __int_as_float(se.y) * we);
    m = fmaxf(m, al);
  }
  float l = 0.f, acc = 0.f;
  for (int e = 0; e < dg; ++e) {
    int2 se = cbase[e];
    float ca = __int_as_float(se.y);
    float al = q * (k1[se.x] + ca * we);
    float ex = __expf(al - m);
    l += ex;
    acc += ex * (v1[se.x] + ca * we);
  }
  out[n] = acc / (l + 1e-16f) + s1[n];
}

// ---------------------------------------------------------------------------
extern "C" void kernel_launch(void* const* d_in, const int* in_sizes, int n_in,
                              void* d_out, int out_size, void* d_ws, size_t ws_size,
                              hipStream_t stream)
{
  const float* x_seq = (const float*)d_in[0];
  const int*   ei    = (const int*)  d_in[1];
  const float* ea    = (const float*)d_in[2];
  const float* W_ih  = (const float*)d_in[3];
  const float* W_hh  = (const float*)d_in[4];
  const float* b_ih  = (const float*)d_in[5];
  const float* b_hh  = (const float*)d_in[6];
  const float* cWq   = (const float*)d_in[7];
  const float* cbq   = (const float*)d_in[8];
  const float* cWk   = (const float*)d_in[9];
  const float* cbk   = (const float*)d_in[10];
  const float* cWv   = (const float*)d_in[11];
  const float* cbv   = (const float*)d_in[12];
  const float* cWe   = (const float*)d_in[13];
  const float* cWs   = (const float*)d_in[14];
  const float* cbs   = (const float*)d_in[15];
  const float* oWq   = (const float*)d_in[16];
  const float* obq   = (const float*)d_in[17];
  const float* oWk   = (const float*)d_in[18];
  const float* obk   = (const float*)d_in[19];
  const float* oWv   = (const float*)d_in[20];
  const float* obv   = (const float*)d_in[21];
  const float* oWe   = (const float*)d_in[22];
  const float* oWs   = (const float*)d_in[23];
  const float* obs   = (const float*)d_in[24];
  float* out = (float*)d_out;

  char* ws = (char*)d_ws;
  size_t off = 0;
  auto alloc = [&](size_t bytes) -> char* {
    char* p = ws + off;
    off += (bytes + 255) & ~(size_t)255;
    return p;
  };
  // ---- total ~165 MB (<186 MB proven r2; r3's 289 MB aborted) ----
  unsigned short* BihP  = (unsigned short*)alloc((size_t)BIH_N * 2);
  unsigned short* BhhP  = (unsigned short*)alloc((size_t)BHH_N * 2);
  unsigned short* WcatP = (unsigned short*)alloc((size_t)WCAT_N * 2);
  float* fbcat = (float*)alloc((size_t)BCAT_N * 4);
  unsigned short* xh    = (unsigned short*)alloc((size_t)T_STEPS * NN * IND * 2);
  unsigned short* hall  = (unsigned short*)alloc((size_t)T_STEPS * NN * DD * 2);
  int*   iDeg  = (int*)  alloc((size_t)T_STEPS * NN * 4);     // zero-init
  int2*  iSE   = (int2*) alloc((size_t)T_STEPS * NN * CAP * 8);  // padded CSR
  float* fQ1   = (float*)alloc((size_t)NN * 4);
  float* fK1   = (float*)alloc((size_t)NN * 4);
  float* fV1   = (float*)alloc((size_t)NN * 4);
  float* fS1   = (float*)alloc((size_t)NN * 4);
  // union: GRU phase gi4 [4NN*G3 fp16 = 61.4 MB] + gh [NN*G3 fp16 = 15.4 MB];
  //        conv phase qkvh [4NN*512 fp16 = 81.9 MB] + hoh [4NN*128 fp16 = 20.5 MB]
  size_t uniOff = off;
  unsigned short* gi4h = (unsigned short*)(ws + uniOff);
  unsigned short* ghh  = (unsigned short*)(ws + uniOff + (size_t)4 * NN * G3 * 2);
  unsigned short* qkvh = (unsigned short*)(ws + uniOff);
  unsigned short* hoh  = (unsigned short*)(ws + uniOff + (size_t)T_STEPS * NN * QS * 2);
  (void)ws_size; (void)in_sizes; (void)n_in; (void)out_size;

  auto gemm = [&](const unsigned short* A, const unsigned short* Bp,
                  const float* bias, unsigned short* Cb, int M, int N, int K) {
    int blocks = (((M >> 5) + 7) >> 3) * (N >> 7);
    gemm_f16<<<blocks, 512, 0, stream>>>(A, Bp, bias, Cb, M, N, K);
  };

  // weights + activation cast + padded CSR (single pass)
  pack_weights<<<(BIH_N + BHH_N + WCAT_N + BCAT_N + 255) / 256, 256, 0,
                 stream>>>(W_ih, W_hh, cWq, cWk, cWv, cWs, cbq, cbk, cbv, cbs,
                           BihP, BhhP, WcatP, fbcat);
  xcast<<<(T_STEPS * NN * IND) / 256, 256, 0, stream>>>(x_seq, xh);
  hipMemsetAsync(iDeg, 0, (size_t)T_STEPS * NN * 4, stream);
  csr_fill<<<(T_STEPS * EE) / 256, 256, 0, stream>>>(ei, ea, iDeg, iSE);

  // GRU: gi for ALL t in one GEMM (M=80000); gh sequential (t=0 skipped)
  gemm(xh, BihP, b_ih, gi4h, T_STEPS * NN, G3, IND);
  for (int t = 0; t < T_STEPS; ++t) {
    const unsigned short* hprev = hall + (size_t)(t - 1) * NN * DD;  // unused t=0
    if (t > 0) gemm(hprev, BhhP, b_hh, ghh, NN, G3, DD);
    gru_gate<<<(NN * DD) / 256, 256, 0, stream>>>(
        gi4h + (size_t)t * NN * G3, ghh, b_hh, (t == 0) ? 1 : 0,
        (t == 0) ? hall : hprev, hall + (size_t)t * NN * DD);
  }

  const int ATTN_BLOCKS = (NN / 8) * T_STEPS;   // 10000, 1D XCD-swizzled

  // Layer 1: h (fp16) -> qkvh ; attn -> hoh
  gemm(hall, WcatP, fbcat, qkvh, T_STEPS * NN, QS, DD);
  attn_conv<<<ATTN_BLOCKS, 256, 0, stream>>>(qkvh, iDeg, iSE, cWe, hoh);

  // Layer 2: hoh -> qkvh ; attn -> hoh (overwrite)
  gemm(hoh, WcatP + (size_t)65536, fbcat + QS, qkvh, T_STEPS * NN, QS, DD);
  attn_conv<<<ATTN_BLOCKS, 256, 0, stream>>>(qkvh, iDeg, iSE, cWe + DD, hoh);

  // output conv (d=1) on t=3 graph; mean-over-T fused into out_proj
  out_proj<<<(NN * 64) / 256, 256, 0, stream>>>(
      hoh, oWq, oWk, oWv, oWs, obq, obk, obv, obs, fQ1, fK1, fV1, fS1);
  out_attn<<<(NN + 255) / 256, 256, 0, stream>>>(
      fQ1, fK1, fV1, fS1, iDeg + 3 * NN, iSE + (size_t)3 * NN * CAP, oWe, out);
}

// Round 14
// 414.949 us; speedup vs baseline: 2.2695x; 1.0180x over previous
//
#include <hip/hip_runtime.h>
#include <math.h>

#define T_STEPS 4
#define NN 20000
#define EE 160000
#define IND 64
#define DD 128
#define G3 384     // 3*D (GRU gates)
#define QS 512     // q|k|v|skip fused width
#define CAP 48     // padded-CSR capacity (max degree ~24; P(>=48) ~ 1e-25)

typedef _Float16 f16x8 __attribute__((ext_vector_type(8)));
typedef _Float16 half2v __attribute__((ext_vector_type(2)));
typedef float floatx4 __attribute__((ext_vector_type(4)));

// ---------------------------------------------------------------------------
// fp16 helpers
// ---------------------------------------------------------------------------
__device__ inline unsigned short f2h_bits(float x) {
  union { _Float16 h; unsigned short s; } u;
  u.h = (_Float16)x;   // v_cvt_f16_f32 (RNE)
  return u.s;
}
__device__ inline float h2f(unsigned short s) {
  union { unsigned short s; _Float16 h; } u;
  u.s = s;
  return (float)u.h;
}
__device__ inline half2v shfl_xor_h2(half2v v, int m) {
  union { half2v h; int i; } u; u.h = v;
  u.i = __shfl_xor(u.i, m);
  return u.h;
}

// ---------------------------------------------------------------------------
// f16 MFMA GEMM, LDS-staged single-f16 B: C = A x B + bias, fp16 out.
// Block = 512 thr (8 waves) sharing one 128-col group; B (<=32KB) staged
// once (r9-proven). 32-row wave tile; DO NOT enlarge (r6 spill).
// ---------------------------------------------------------------------------
__global__ __launch_bounds__(512) void gemm_f16(
    const unsigned short* __restrict__ A,
    const unsigned short* __restrict__ Bp, const float* __restrict__ bias,
    unsigned short* __restrict__ Cb, int M, int N, int K)
{
  __shared__ unsigned short Bs[16384];   // 32 KB (max ktiles=4)
  const int ngroups = N >> 7;
  const int mtiles = M >> 5;
  const int ng = blockIdx.x % ngroups;
  const int mb = blockIdx.x / ngroups;
  const int ktiles = K >> 5;
  const int tid = threadIdx.x;
  const unsigned short* Bsrc = Bp + (size_t)ng * 8 * ktiles * 512;
  const int nchunk = ktiles * 8 * 64;   // 16B chunks
  for (int i = tid; i < nchunk; i += 512)
    *(uint4*)&Bs[i * 8] = *(const uint4*)&Bsrc[i * 8];
  __syncthreads();
  const int w = tid >> 6;
  const int lane = tid & 63;
  const int mw = mb * 8 + w;
  if (mw >= mtiles) return;
  const int r = lane & 15, quad = lane >> 4;
  const unsigned short* a0 = A + (size_t)(mw * 32 + r) * K + quad * 8;
  const unsigned short* a1 = a0 + (size_t)16 * K;
  floatx4 acc[2][8];
#pragma unroll
  for (int m = 0; m < 2; ++m)
#pragma unroll
    for (int nt = 0; nt < 8; ++nt) acc[m][nt] = (floatx4){0.f, 0.f, 0.f, 0.f};
  for (int kt = 0; kt < ktiles; ++kt) {
    f16x8 af0 = *(const f16x8*)(a0 + kt * 32);
    f16x8 af1 = *(const f16x8*)(a1 + kt * 32);
#pragma unroll
    for (int nt = 0; nt < 8; ++nt) {
      f16x8 bf = *(const f16x8*)(Bs + (nt * ktiles + kt) * 512 + lane * 8);
      acc[0][nt] = __builtin_amdgcn_mfma_f32_16x16x32_f16(af0, bf, acc[0][nt], 0, 0, 0);
      acc[1][nt] = __builtin_amdgcn_mfma_f32_16x16x32_f16(af1, bf, acc[1][nt], 0, 0, 0);
    }
  }
#pragma unroll
  for (int m = 0; m < 2; ++m) {
    const int crow0 = mw * 32 + m * 16 + quad * 4;
#pragma unroll
    for (int nt = 0; nt < 8; ++nt) {
      const int col = ng * 128 + nt * 16 + r;
      const float b = bias[col];
#pragma unroll
      for (int i = 0; i < 4; ++i)
        Cb[(size_t)(crow0 + i) * N + col] = f2h_bits(acc[m][nt][i] + b);
    }
  }
}

// ---------------------------------------------------------------------------
// fp32-A variant (K=64 only, for gi = x @ Wih^T): reads fp32 x directly,
// converts in the A-load (fuses the old xcast kernel; saves its 30 MB of
// traffic + one dispatch). Same LDS-staged B structure.
// ---------------------------------------------------------------------------
__global__ __launch_bounds__(512) void gemm_f32a(
    const float* __restrict__ A,
    const unsigned short* __restrict__ Bp, const float* __restrict__ bias,
    unsigned short* __restrict__ Cb, int M, int N)
{
  __shared__ unsigned short Bs[8192];    // K=64 -> ktiles=2 -> 16 KB
  const int ngroups = N >> 7;
  const int mtiles = M >> 5;
  const int ng = blockIdx.x % ngroups;
  const int mb = blockIdx.x / ngroups;
  const int tid = threadIdx.x;
  const unsigned short* Bsrc = Bp + (size_t)ng * 8 * 2 * 512;
  for (int i = tid; i < 1024; i += 512)
    *(uint4*)&Bs[i * 8] = *(const uint4*)&Bsrc[i * 8];
  __syncthreads();
  const int w = tid >> 6;
  const int lane = tid & 63;
  const int mw = mb * 8 + w;
  if (mw >= mtiles) return;
  const int r = lane & 15, quad = lane >> 4;
  const float* a0 = A + (size_t)(mw * 32 + r) * IND + quad * 8;
  const float* a1 = a0 + (size_t)16 * IND;
  floatx4 acc[2][8];
#pragma unroll
  for (int m = 0; m < 2; ++m)
#pragma unroll
    for (int nt = 0; nt < 8; ++nt) acc[m][nt] = (floatx4){0.f, 0.f, 0.f, 0.f};
#pragma unroll
  for (int kt = 0; kt < 2; ++kt) {
    float4 f00 = *(const float4*)(a0 + kt * 32);
    float4 f01 = *(const float4*)(a0 + kt * 32 + 4);
    float4 f10 = *(const float4*)(a1 + kt * 32);
    float4 f11 = *(const float4*)(a1 + kt * 32 + 4);
    f16x8 af0 = (f16x8){(_Float16)f00.x, (_Float16)f00.y, (_Float16)f00.z,
                        (_Float16)f00.w, (_Float16)f01.x, (_Float16)f01.y,
                        (_Float16)f01.z, (_Float16)f01.w};
    f16x8 af1 = (f16x8){(_Float16)f10.x, (_Float16)f10.y, (_Float16)f10.z,
                        (_Float16)f10.w, (_Float16)f11.x, (_Float16)f11.y,
                        (_Float16)f11.z, (_Float16)f11.w};
#pragma unroll
    for (int nt = 0; nt < 8; ++nt) {
      f16x8 bf = *(const f16x8*)(Bs + (nt * 2 + kt) * 512 + lane * 8);
      acc[0][nt] = __builtin_amdgcn_mfma_f32_16x16x32_f16(af0, bf, acc[0][nt], 0, 0, 0);
      acc[1][nt] = __builtin_amdgcn_mfma_f32_16x16x32_f16(af1, bf, acc[1][nt], 0, 0, 0);
    }
  }
#pragma unroll
  for (int m = 0; m < 2; ++m) {
    const int crow0 = mw * 32 + m * 16 + quad * 4;
#pragma unroll
    for (int nt = 0; nt < 8; ++nt) {
      const int col = ng * 128 + nt * 16 + r;
      const float b = bias[col];
#pragma unroll
      for (int i = 0; i < 4; ++i)
        Cb[(size_t)(crow0 + i) * N + col] = f2h_bits(acc[m][nt][i] + b);
    }
  }
}

// ---------------------------------------------------------------------------
// Weight packing: single f16 in MFMA fragment order + fp32 fused conv bias
// ---------------------------------------------------------------------------
#define BIH_N 24576    // (384/16)*(64/32)*512
#define BHH_N 49152    // 24*4*512
#define WCAT_N 131072  // 2*32*4*512
#define BCAT_N 1024

__global__ void pack_weights(
    const float* __restrict__ Wih, const float* __restrict__ Whh,
    const float* __restrict__ Wq, const float* __restrict__ Wk,
    const float* __restrict__ Wv, const float* __restrict__ Ws,
    const float* __restrict__ bq, const float* __restrict__ bk,
    const float* __restrict__ bv, const float* __restrict__ bs,
    unsigned short* __restrict__ BihP, unsigned short* __restrict__ BhhP,
    unsigned short* __restrict__ WcatP, float* __restrict__ bcat)
{
  int gid = blockIdx.x * 256 + threadIdx.x;
  if (gid < BIH_N) {  // K=64, N=384, ktiles=2
    int tile = gid >> 9, lj = gid & 511, lane = lj >> 3, j = lj & 7;
    int k_tile = tile & 1, n_tile = tile >> 1;
    int n = n_tile * 16 + (lane & 15);
    int k = k_tile * 32 + (lane >> 4) * 8 + j;
    BihP[tile * 512 + lane * 8 + j] = f2h_bits(Wih[n * IND + k]);  // B[k][n]=Wih^T
    return;
  }
  gid -= BIH_N;
  if (gid < BHH_N) {  // K=128, N=384, ktiles=4
    int tile = gid >> 9, lj = gid & 511, lane = lj >> 3, j = lj & 7;
    int k_tile = tile & 3, n_tile = tile >> 2;
    int n = n_tile * 16 + (lane & 15);
    int k = k_tile * 32 + (lane >> 4) * 8 + j;
    BhhP[tile * 512 + lane * 8 + j] = f2h_bits(Whh[n * DD + k]);
    return;
  }
  gid -= BHH_N;
  if (gid < WCAT_N) {  // per layer: K=128, N=512, ktiles=4
    int l = gid >> 16, rem = gid & 65535;
    int tile = rem >> 9, lj = rem & 511, lane = lj >> 3, j = lj & 7;
    int k_tile = tile & 3, n_tile = tile >> 2;
    int n = n_tile * 16 + (lane & 15);
    int k = k_tile * 32 + (lane >> 4) * 8 + j;
    const float* W = (n < 128) ? Wq : (n < 256) ? Wk : (n < 384) ? Wv : Ws;
    WcatP[(size_t)l * 65536 + tile * 512 + lane * 8 + j] =
        f2h_bits(W[l * DD * DD + k * DD + (n & 127)]);
    return;
  }
  gid -= WCAT_N;
  if (gid < BCAT_N) {
    int l = gid >> 9, n = gid & 511;
    const float* b = (n < 128) ? bq : (n < 256) ? bk : (n < 384) ? bv : bs;
    bcat[gid] = b[l * DD + (n & 127)];
  }
}

// ---------------------------------------------------------------------------
// Padded CSR build: ONE pass (r12-proven).
// ---------------------------------------------------------------------------
__global__ void csr_fill(const int* __restrict__ ei, const float* __restrict__ ea,
                         int* __restrict__ deg, int2* __restrict__ cse)
{
  int gid = blockIdx.x * 256 + threadIdx.x;
  if (gid >= T_STEPS * EE) return;
  int t = gid / EE, e = gid % EE;
  int src = ei[(size_t)t * 2 * EE + e];
  int dst = ei[(size_t)t * 2 * EE + EE + e];
  int slot = atomicAdd(&deg[t * NN + dst], 1);
  cse[((size_t)t * NN + dst) * CAP + slot] =
      make_int2(src, __float_as_int(ea[(size_t)t * EE + e]));
}

// ---------------------------------------------------------------------------
// GRU gate fusion (all fp16 activations). t0: gh == b_hh exactly (h0=0).
// ---------------------------------------------------------------------------
__global__ __launch_bounds__(256) void gru_gate(
    const unsigned short* __restrict__ gi, const unsigned short* __restrict__ gh,
    const float* __restrict__ b_hh, int t0,
    const unsigned short* __restrict__ hprev, unsigned short* __restrict__ hout)
{
  int idx = blockIdx.x * 256 + threadIdx.x;   // exact NN*DD grid
  int n = idx >> 7, d = idx & 127;
  size_t gb = (size_t)n * G3 + d;
  float ir = h2f(gi[gb]), iz = h2f(gi[gb + DD]), inn = h2f(gi[gb + 2 * DD]);
  float hr, hz, hn, hp;
  if (t0) {
    hr = b_hh[d]; hz = b_hh[DD + d]; hn = b_hh[2 * DD + d]; hp = 0.f;
  } else {
    hr = h2f(gh[gb]); hz = h2f(gh[gb + DD]); hn = h2f(gh[gb + 2 * DD]);
    hp = h2f(hprev[idx]);
  }
  float r = 1.f / (1.f + __expf(-(ir + hr)));
  float z = 1.f / (1.f + __expf(-(iz + hz)));
  float nv = tanhf(inn + r * hn);
  float hnew = (1.f - z) * nv + z * hp;
  hout[idx] = f2h_bits(hnew);
}

// ---------------------------------------------------------------------------
// Fused TransformerConv (d=128), fp16 qkv, packed math, padded CSR.
// r12-PROVEN 4-edge body (r13's 8-wide body measured WORSE: 51.1 vs 48.8 µs
// — bound is random-gather HBM BW, not per-wave MLP).
// 1D grid, XCD-aware swizzle: t = (bid&7)>>1. TWO nodes per wave.
// ---------------------------------------------------------------------------
__global__ __launch_bounds__(256) void attn_conv(
    const unsigned short* __restrict__ qkvh,  // [T][NN][512] fp16
    const int* __restrict__ deg4,     // [T][NN]
    const int2* __restrict__ cse4,    // [T][NN][CAP]
    const float* __restrict__ We,     // [128] fp32
    unsigned short* __restrict__ hoh) // [T][NN][128] fp16 out
{
  const int bid = blockIdx.x;
  const int xc = bid & 7, jb = bid >> 3;
  const int t = xc >> 1;
  const int blk = jb * 2 + (xc & 1);          // 0..2499 within t
  const unsigned short* qk = qkvh + (size_t)t * NN * QS;
  const int lane = threadIdx.x & 63;
  const int w = threadIdx.x >> 6;             // 4 waves/block
  const int hlf = lane >> 5;
  const int es = (lane >> 3) & 3;             // 4 edge slots
  const int fg = lane & 7;                    // 8 feature groups
  const int node = blk * 8 + w * 2 + hlf;     // exact 20000 per t
  const int f0 = fg * 16;
  const float scale = 0.08838834764831845f;   // 1/sqrt(128)

  union U16 { uint4 u[2]; half2v h[8]; };
  U16 q;
  {
    const uint4* p = (const uint4*)(qk + (size_t)node * QS + f0);
    q.u[0] = p[0]; q.u[1] = p[1];
  }
  half2v we2[8];
  {
    const float4* wp = (const float4*)&We[f0];
    float4 w0 = wp[0], w1 = wp[1], w2 = wp[2], w3 = wp[3];
    we2[0] = (half2v){(_Float16)w0.x, (_Float16)w0.y};
    we2[1] = (half2v){(_Float16)w0.z, (_Float16)w0.w};
    we2[2] = (half2v){(_Float16)w1.x, (_Float16)w1.y};
    we2[3] = (half2v){(_Float16)w1.z, (_Float16)w1.w};
    we2[4] = (half2v){(_Float16)w2.x, (_Float16)w2.y};
    we2[5] = (half2v){(_Float16)w2.z, (_Float16)w2.w};
    we2[6] = (half2v){(_Float16)w3.x, (_Float16)w3.y};
    we2[7] = (half2v){(_Float16)w3.z, (_Float16)w3.w};
  }
  float qwe = 0.f;
#pragma unroll
  for (int j = 0; j < 8; ++j) {
#if __has_builtin(__builtin_amdgcn_fdot2)
    qwe = __builtin_amdgcn_fdot2(q.h[j], we2[j], qwe, false);
#else
    qwe = fmaf((float)q.h[j].x, (float)we2[j].x, qwe);
    qwe = fmaf((float)q.h[j].y, (float)we2[j].y, qwe);
#endif
  }
  qwe += __shfl_xor(qwe, 1); qwe += __shfl_xor(qwe, 2); qwe += __shfl_xor(qwe, 4);

  const int dg = deg4[t * NN + node];
  const int2* cbase = cse4 + ((size_t)t * NN + node) * CAP;
  float l_lane = 0.f, sA_lane = 0.f;
  half2v acc2[8];
#pragma unroll
  for (int i = 0; i < 8; ++i) acc2[i] = (half2v){(_Float16)0.f, (_Float16)0.f};

  for (int base = 0; base < dg; base += 4) {
    const int eidx = base + es;
    const bool valid = eidx < dg;
    int2 se = valid ? cbase[eidx] : make_int2(0, 0);
    const float a = __int_as_float(se.y);
    U16 kf;
    {
      const uint4* p = (const uint4*)(qk + (size_t)se.x * QS + 128 + f0);
      kf.u[0] = p[0]; kf.u[1] = p[1];
    }
    float p = 0.f;
#pragma unroll
    for (int j = 0; j < 8; ++j) {
#if __has_builtin(__builtin_amdgcn_fdot2)
      p = __builtin_amdgcn_fdot2(q.h[j], kf.h[j], p, false);
#else
      p = fmaf((float)q.h[j].x, (float)kf.h[j].x, p);
      p = fmaf((float)q.h[j].y, (float)kf.h[j].y, p);
#endif
    }
    p += __shfl_xor(p, 1); p += __shfl_xor(p, 2); p += __shfl_xor(p, 4);
    const float ex = valid ? __expf((p + a * qwe) * scale) : 0.f;
    l_lane += ex;
    sA_lane = fmaf(ex, a, sA_lane);
    const _Float16 exh = (_Float16)ex;
    const half2v ex2 = (half2v){exh, exh};
    U16 vf;
    {
      const uint4* p2 = (const uint4*)(qk + (size_t)se.x * QS + 256 + f0);
      vf.u[0] = p2[0]; vf.u[1] = p2[1];
    }
#pragma unroll
    for (int j = 0; j < 8; ++j)
      acc2[j] = ex2 * vf.h[j] + acc2[j];   // v_pk_fma_f16
  }
  // reductions over the 4 edge-slots (xor 8,16 stay within the 32-lane half)
  l_lane += __shfl_xor(l_lane, 8);  l_lane += __shfl_xor(l_lane, 16);
  sA_lane += __shfl_xor(sA_lane, 8); sA_lane += __shfl_xor(sA_lane, 16);
#pragma unroll
  for (int i = 0; i < 8; ++i) {
    acc2[i] = acc2[i] + shfl_xor_h2(acc2[i], 8);
    acc2[i] = acc2[i] + shfl_xor_h2(acc2[i], 16);
  }
  if (es != 0) return;
  const float inv = 1.f / (l_lane + 1e-16f);
  const float sAi = sA_lane * inv;
  U16 sk;
  {
    const uint4* p = (const uint4*)(qk + (size_t)node * QS + 384 + f0);
    sk.u[0] = p[0]; sk.u[1] = p[1];
  }
  float wf[16];
  {
    const float4* wp = (const float4*)&We[f0];
#pragma unroll
    for (int j = 0; j < 4; ++j) *(float4*)&wf[4 * j] = wp[j];
  }
  U16 outp;
#pragma unroll
  for (int j = 0; j < 8; ++j) {
    float oa = fmaf((float)acc2[j].x, inv, fmaf(sAi, wf[2 * j],     (float)sk.h[j].x));
    float ob = fmaf((float)acc2[j].y, inv, fmaf(sAi, wf[2 * j + 1], (float)sk.h[j].y));
    oa = (oa > 0.f) ? oa : 0.01f * oa;    // leaky_relu
    ob = (ob > 0.f) ? ob : 0.01f * ob;
    outp.h[j] = (half2v){(_Float16)oa, (_Float16)ob};
  }
  unsigned short* dst = hoh + ((size_t)t * NN + node) * DD + f0;
  *(uint4*)(dst + 0) = outp.u[0];
  *(uint4*)(dst + 8) = outp.u[1];
}

// ---------------------------------------------------------------------------
// Output conv projections with fused mean-over-T (reads hoh fp16 directly)
// ---------------------------------------------------------------------------
__global__ __launch_bounds__(256) void out_proj(
    const unsigned short* __restrict__ hoh,   // [T][NN][128] fp16
    const float* __restrict__ Wq, const float* __restrict__ Wk,
    const float* __restrict__ Wv, const float* __restrict__ Ws,
    const float* __restrict__ bq, const float* __restrict__ bk,
    const float* __restrict__ bv, const float* __restrict__ bs,
    float* __restrict__ q1, float* __restrict__ k1,
    float* __restrict__ v1, float* __restrict__ s1)
{
  const int wv = (blockIdx.x * 256 + threadIdx.x) >> 6;
  const int lane = threadIdx.x & 63;
  if (wv >= NN) return;
  float hx = 0.f, hy = 0.f;
#pragma unroll
  for (int t = 0; t < T_STEPS; ++t) {
    union { unsigned u; half2v h; } c;
    c.u = *(const unsigned*)&hoh[((size_t)t * NN + wv) * DD + 2 * lane];
    hx += (float)c.h.x;
    hy += (float)c.h.y;
  }
  hx *= 0.25f; hy *= 0.25f;
  float pq = hx * Wq[2 * lane] + hy * Wq[2 * lane + 1];
  float pk = hx * Wk[2 * lane] + hy * Wk[2 * lane + 1];
  float pv = hx * Wv[2 * lane] + hy * Wv[2 * lane + 1];
  float ps = hx * Ws[2 * lane] + hy * Ws[2 * lane + 1];
#pragma unroll
  for (int o = 1; o < 64; o <<= 1) {
    pq += __shfl_xor(pq, o); pk += __shfl_xor(pk, o);
    pv += __shfl_xor(pv, o); ps += __shfl_xor(ps, o);
  }
  if (lane == 0) {
    q1[wv] = pq + bq[0]; k1[wv] = pk + bk[0];
    v1[wv] = pv + bv[0]; s1[wv] = ps + bs[0];
  }
}

__global__ void out_attn(
    const float* __restrict__ q1, const float* __restrict__ k1,
    const float* __restrict__ v1, const float* __restrict__ s1,
    const int* __restrict__ deg, const int2* __restrict__ cse,
    const float* __restrict__ We, float* __restrict__ out)
{
  int n = blockIdx.x * 256 + threadIdx.x;
  if (n >= NN) return;
  const float we = We[0];
  const float q = q1[n];
  const int dg = deg[n];
  const int2* cbase = cse + (size_t)n * CAP;
  float m = -INFINITY;
  for (int e = 0; e < dg; ++e) {
    int2 se = cbase[e];
    float al = q * (k1[se.x] + __int_as_float(se.y) * we);
    m = fmaxf(m, al);
  }
  float l = 0.f, acc = 0.f;
  for (int e = 0; e < dg; ++e) {
    int2 se = cbase[e];
    float ca = __int_as_float(se.y);
    float al = q * (k1[se.x] + ca * we);
    float ex = __expf(al - m);
    l += ex;
    acc += ex * (v1[se.x] + ca * we);
  }
  out[n] = acc / (l + 1e-16f) + s1[n];
}

// ---------------------------------------------------------------------------
extern "C" void kernel_launch(void* const* d_in, const int* in_sizes, int n_in,
                              void* d_out, int out_size, void* d_ws, size_t ws_size,
                              hipStream_t stream)
{
  const float* x_seq = (const float*)d_in[0];
  const int*   ei    = (const int*)  d_in[1];
  const float* ea    = (const float*)d_in[2];
  const float* W_ih  = (const float*)d_in[3];
  const float* W_hh  = (const float*)d_in[4];
  const float* b_ih  = (const float*)d_in[5];
  const float* b_hh  = (const float*)d_in[6];
  const float* cWq   = (const float*)d_in[7];
  const float* cbq   = (const float*)d_in[8];
  const float* cWk   = (const float*)d_in[9];
  const float* cbk   = (const float*)d_in[10];
  const float* cWv   = (const float*)d_in[11];
  const float* cbv   = (const float*)d_in[12];
  const float* cWe   = (const float*)d_in[13];
  const float* cWs   = (const float*)d_in[14];
  const float* cbs   = (const float*)d_in[15];
  const float* oWq   = (const float*)d_in[16];
  const float* obq   = (const float*)d_in[17];
  const float* oWk   = (const float*)d_in[18];
  const float* obk   = (const float*)d_in[19];
  const float* oWv   = (const float*)d_in[20];
  const float* obv   = (const float*)d_in[21];
  const float* oWe   = (const float*)d_in[22];
  const float* oWs   = (const float*)d_in[23];
  const float* obs   = (const float*)d_in[24];
  float* out = (float*)d_out;

  char* ws = (char*)d_ws;
  size_t off = 0;
  auto alloc = [&](size_t bytes) -> char* {
    char* p = ws + off;
    off += (bytes + 255) & ~(size_t)255;
    return p;
  };
  // ---- total ~145 MB (<186 MB proven r2; r3's 289 MB aborted) ----
  unsigned short* BihP  = (unsigned short*)alloc((size_t)BIH_N * 2);
  unsigned short* BhhP  = (unsigned short*)alloc((size_t)BHH_N * 2);
  unsigned short* WcatP = (unsigned short*)alloc((size_t)WCAT_N * 2);
  float* fbcat = (float*)alloc((size_t)BCAT_N * 4);
  unsigned short* hall  = (unsigned short*)alloc((size_t)T_STEPS * NN * DD * 2);
  int*   iDeg  = (int*)  alloc((size_t)T_STEPS * NN * 4);     // zero-init
  int2*  iSE   = (int2*) alloc((size_t)T_STEPS * NN * CAP * 8);  // padded CSR
  float* fQ1   = (float*)alloc((size_t)NN * 4);
  float* fK1   = (float*)alloc((size_t)NN * 4);
  float* fV1   = (float*)alloc((size_t)NN * 4);
  float* fS1   = (float*)alloc((size_t)NN * 4);
  // union: GRU phase gi4 [4NN*G3 fp16 = 61.4 MB] + gh [NN*G3 fp16 = 15.4 MB];
  //        conv phase qkvh [4NN*512 fp16 = 81.9 MB] + hoh [4NN*128 fp16 = 20.5 MB]
  size_t uniOff = off;
  unsigned short* gi4h = (unsigned short*)(ws + uniOff);
  unsigned short* ghh  = (unsigned short*)(ws + uniOff + (size_t)4 * NN * G3 * 2);
  unsigned short* qkvh = (unsigned short*)(ws + uniOff);
  unsigned short* hoh  = (unsigned short*)(ws + uniOff + (size_t)T_STEPS * NN * QS * 2);
  (void)ws_size; (void)in_sizes; (void)n_in; (void)out_size;

  auto gemm = [&](const unsigned short* A, const unsigned short* Bp,
                  const float* bias, unsigned short* Cb, int M, int N, int K) {
    int blocks = (((M >> 5) + 7) >> 3) * (N >> 7);
    gemm_f16<<<blocks, 512, 0, stream>>>(A, Bp, bias, Cb, M, N, K);
  };

  // weights + padded CSR (single pass)
  pack_weights<<<(BIH_N + BHH_N + WCAT_N + BCAT_N + 255) / 256, 256, 0,
                 stream>>>(W_ih, W_hh, cWq, cWk, cWv, cWs, cbq, cbk, cbv, cbs,
                           BihP, BhhP, WcatP, fbcat);
  hipMemsetAsync(iDeg, 0, (size_t)T_STEPS * NN * 4, stream);
  csr_fill<<<(T_STEPS * EE) / 256, 256, 0, stream>>>(ei, ea, iDeg, iSE);

  // GRU: gi for ALL t in one fp32-A GEMM (xcast fused); gh sequential
  {
    int blocks = ((((T_STEPS * NN) >> 5) + 7) >> 3) * (G3 >> 7);
    gemm_f32a<<<blocks, 512, 0, stream>>>(x_seq, BihP, b_ih, gi4h,
                                          T_STEPS * NN, G3);
  }
  for (int t = 0; t < T_STEPS; ++t) {
    const unsigned short* hprev = hall + (size_t)(t - 1) * NN * DD;  // unused t=0
    if (t > 0) gemm(hprev, BhhP, b_hh, ghh, NN, G3, DD);
    gru_gate<<<(NN * DD) / 256, 256, 0, stream>>>(
        gi4h + (size_t)t * NN * G3, ghh, b_hh, (t == 0) ? 1 : 0,
        (t == 0) ? hall : hprev, hall + (size_t)t * NN * DD);
  }

  const int ATTN_BLOCKS = (NN / 8) * T_STEPS;   // 10000, 1D XCD-swizzled

  // Layer 1: h (fp16) -> qkvh ; attn -> hoh
  gemm(hall, WcatP, fbcat, qkvh, T_STEPS * NN, QS, DD);
  attn_conv<<<ATTN_BLOCKS, 256, 0, stream>>>(qkvh, iDeg, iSE, cWe, hoh);

  // Layer 2: hoh -> qkvh ; attn -> hoh (overwrite)
  gemm(hoh, WcatP + (size_t)65536, fbcat + QS, qkvh, T_STEPS * NN, QS, DD);
  attn_conv<<<ATTN_BLOCKS, 256, 0, stream>>>(qkvh, iDeg, iSE, cWe + DD, hoh);

  // output conv (d=1) on t=3 graph; mean-over-T fused into out_proj
  out_proj<<<(NN * 64) / 256, 256, 0, stream>>>(
      hoh, oWq, oWk, oWv, oWs, obq, obk, obv, obs, fQ1, fK1, fV1, fS1);
  out_attn<<<(NN + 255) / 256, 256, 0, stream>>>(
      fQ1, fK1, fV1, fS1, iDeg + 3 * NN, iSE + (size_t)3 * NN * CAP, oWe, out);
}